// Round 1
// baseline (1072.003 us; speedup 1.0000x reference)
//
#include <hip/hip_runtime.h>

#define N_NODES 50000
#define N_EDGES 800000
#define IN_DIM  128
#define HID     256
#define NGRAPH  256
#define LN_EPS  1e-5f

// ---------------- workspace layout (32-bit word offsets) ----------------
#define W_DEG      0
#define W_CURSOR   (W_DEG + N_NODES)
#define W_CNT      (W_CURSOR + N_NODES)
#define W_FLAG     (W_CNT + NGRAPH)
#define W_POOL     (W_FLAG + 16)
#define ZERO_WORDS (W_POOL + NGRAPH * HID)
#define W_OFFS     ZERO_WORDS
#define W_DIS      (W_OFFS + N_NODES + 1)
#define W_SRC32    (W_DIS + N_NODES)
#define W_DST32    (W_SRC32 + N_EDGES)
#define W_BATCH32  (W_DST32 + N_EDGES)
#define W_CSRS     (W_BATCH32 + N_NODES)
#define W_CSRW     (W_CSRS + N_EDGES)
#define W_ALIGN    (((W_CSRW + N_EDGES) + 3) & ~3)
#define W_H        W_ALIGN
#define W_Z        (W_H + N_NODES * HID)

// ---------------- small utility kernels ----------------
__global__ __launch_bounds__(256) void zero_kernel(unsigned int* __restrict__ p, int n) {
    int i = blockIdx.x * 256 + threadIdx.x;
    int stride = gridDim.x * 256;
    for (; i < n; i += stride) p[i] = 0u;
}

// flag=1  <=>  integer inputs are int32 (odd 32-bit words of edge_index are node ids, nonzero w.h.p.)
// flag=0  <=>  int64 (odd words are the all-zero high halves)
__global__ __launch_bounds__(256) void detect_kernel(const unsigned int* __restrict__ ei,
                                                     int* __restrict__ flag) {
    int e = blockIdx.x * 256 + threadIdx.x;
    if (e >= N_EDGES) return;
    if (ei[2 * e + 1] != 0u) *flag = 1;
}

__global__ __launch_bounds__(256) void convert_edges(const void* __restrict__ ei,
                                                     const int* __restrict__ flag,
                                                     int* __restrict__ src32,
                                                     int* __restrict__ dst32) {
    int e = blockIdx.x * 256 + threadIdx.x;
    if (e >= N_EDGES) return;
    if (*flag) {
        const int* p = (const int*)ei;
        src32[e] = p[e];
        dst32[e] = p[N_EDGES + e];
    } else {
        const long long* p = (const long long*)ei;
        src32[e] = (int)p[e];
        dst32[e] = (int)p[N_EDGES + e];
    }
}

__global__ __launch_bounds__(256) void convert_batch(const void* __restrict__ b,
                                                     const int* __restrict__ flag,
                                                     int* __restrict__ batch32) {
    int v = blockIdx.x * 256 + threadIdx.x;
    if (v >= N_NODES) return;
    if (*flag) batch32[v] = ((const int*)b)[v];
    else       batch32[v] = (int)((const long long*)b)[v];
}

__global__ __launch_bounds__(256) void deg_kernel(const int* __restrict__ dst32,
                                                  int* __restrict__ deg) {
    int e = blockIdx.x * 256 + threadIdx.x;
    if (e >= N_EDGES) return;
    atomicAdd(&deg[dst32[e]], 1);
}

__global__ __launch_bounds__(256) void cnt_kernel(const int* __restrict__ batch32,
                                                  int* __restrict__ cnt) {
    int v = blockIdx.x * 256 + threadIdx.x;
    if (v >= N_NODES) return;
    atomicAdd(&cnt[batch32[v]], 1);
}

__global__ __launch_bounds__(256) void dis_kernel(const int* __restrict__ deg,
                                                  float* __restrict__ dis) {
    int v = blockIdx.x * 256 + threadIdx.x;
    if (v >= N_NODES) return;
    dis[v] = rsqrtf((float)deg[v] + 1.0f);
}

// single-block exclusive scan over deg[0..N_NODES) -> offs, offs[N]=total
__global__ __launch_bounds__(256) void scan_kernel(const int* __restrict__ deg,
                                                   int* __restrict__ offs) {
    const int CH = (N_NODES + 255) / 256;  // 196
    int t = threadIdx.x;
    int s0 = t * CH;
    int s1 = min(s0 + CH, N_NODES);
    int sum = 0;
    for (int i = s0; i < s1; ++i) sum += deg[i];
    int lane = t & 63, wid = t >> 6;
    int inc = sum;
    #pragma unroll
    for (int o = 1; o < 64; o <<= 1) {
        int u = __shfl_up(inc, o, 64);
        if (lane >= o) inc += u;
    }
    __shared__ int wsums[4];
    if (lane == 63) wsums[wid] = inc;
    __syncthreads();
    int base = 0;
    for (int w = 0; w < wid; ++w) base += wsums[w];
    int run = base + inc - sum;  // exclusive prefix at s0
    for (int i = s0; i < s1; ++i) { offs[i] = run; run += deg[i]; }
    if (t == 255) offs[N_NODES] = run;
}

__global__ __launch_bounds__(256) void scatter_kernel(const int* __restrict__ src32,
                                                      const int* __restrict__ dst32,
                                                      const int* __restrict__ offs,
                                                      int* __restrict__ cursor,
                                                      const float* __restrict__ dis,
                                                      int* __restrict__ csr_s,
                                                      float* __restrict__ csr_w) {
    int e = blockIdx.x * 256 + threadIdx.x;
    if (e >= N_EDGES) return;
    int s = src32[e], d = dst32[e];
    int pos = atomicAdd(&cursor[d], 1);
    int idx = offs[d] + pos;
    csr_s[idx] = s;
    csr_w[idx] = dis[s] * dis[d];
}

// ---------------- f32 tiled GEMM:  C[M x 256] = A[M x K] @ W[K x 256] ----------------
#define BM 64
#define BN 64
#define BK 16
__global__ __launch_bounds__(256) void gemm_f32(const float* __restrict__ A,
                                                const float* __restrict__ W,
                                                float* __restrict__ C,
                                                int M, int K) {
    __shared__ float As[BK][BM + 4];  // transposed A tile
    __shared__ float Ws[BK][BN + 4];
    int bm = blockIdx.x * BM;
    int bn = blockIdx.y * BN;
    int tid = threadIdx.x;
    int la_r = tid >> 2;           // 0..63
    int la_k = (tid & 3) << 2;     // 0,4,8,12
    int lw_k = tid >> 4;           // 0..15
    int lw_c = (tid & 15) << 2;    // 0..60
    int tm = (tid >> 4) << 2;      // 0..60
    int tn = (tid & 15) << 2;      // 0..60
    float acc[4][4] = {};
    int arow = bm + la_r;
    for (int k0 = 0; k0 < K; k0 += BK) {
        float4 av = make_float4(0.f, 0.f, 0.f, 0.f);
        if (arow < M) av = *(const float4*)&A[(size_t)arow * K + k0 + la_k];
        As[la_k + 0][la_r] = av.x;
        As[la_k + 1][la_r] = av.y;
        As[la_k + 2][la_r] = av.z;
        As[la_k + 3][la_r] = av.w;
        *(float4*)&Ws[lw_k][lw_c] = *(const float4*)&W[(size_t)(k0 + lw_k) * HID + bn + lw_c];
        __syncthreads();
        #pragma unroll
        for (int k = 0; k < BK; ++k) {
            float4 a4 = *(const float4*)&As[k][tm];
            float4 w4 = *(const float4*)&Ws[k][tn];
            float a[4] = {a4.x, a4.y, a4.z, a4.w};
            float w[4] = {w4.x, w4.y, w4.z, w4.w};
            #pragma unroll
            for (int i = 0; i < 4; ++i)
                #pragma unroll
                for (int j = 0; j < 4; ++j)
                    acc[i][j] = fmaf(a[i], w[j], acc[i][j]);
        }
        __syncthreads();
    }
    #pragma unroll
    for (int i = 0; i < 4; ++i) {
        int row = bm + tm + i;
        if (row < M) {
            float4 o = make_float4(acc[i][0], acc[i][1], acc[i][2], acc[i][3]);
            *(float4*)&C[(size_t)row * HID + bn + tn] = o;
        }
    }
}

// ---------------- fused CSR aggregation + bias + ReLU + LayerNorm ----------------
__global__ __launch_bounds__(256) void aggln_kernel(const float* __restrict__ H,
                                                    const float* __restrict__ dis,
                                                    const int* __restrict__ offs,
                                                    const int* __restrict__ csr_s,
                                                    const float* __restrict__ csr_w,
                                                    const float* __restrict__ bias,
                                                    const float* __restrict__ gamma,
                                                    const float* __restrict__ beta,
                                                    float* __restrict__ Z) {
    int v = blockIdx.x;
    int t = threadIdx.x;
    float dv = dis[v];
    float acc = H[v * HID + t] * (dv * dv);
    int i0 = offs[v], i1 = offs[v + 1];
    for (int i = i0; i < i1; ++i) {
        int s = csr_s[i];
        float w = csr_w[i];
        acc = fmaf(H[s * HID + t], w, acc);
    }
    acc += bias[t];
    float rv = fmaxf(acc, 0.f);
    // LayerNorm over 256 features
    __shared__ float lds[8];
    int lane = t & 63, wid = t >> 6;
    float ssum = rv;
    #pragma unroll
    for (int o = 32; o >= 1; o >>= 1) ssum += __shfl_down(ssum, o, 64);
    if (lane == 0) lds[wid] = ssum;
    __syncthreads();
    float mu = (lds[0] + lds[1] + lds[2] + lds[3]) * (1.0f / HID);
    float d = rv - mu;
    float vsum = d * d;
    #pragma unroll
    for (int o = 32; o >= 1; o >>= 1) vsum += __shfl_down(vsum, o, 64);
    if (lane == 0) lds[4 + wid] = vsum;
    __syncthreads();
    float var = (lds[4] + lds[5] + lds[6] + lds[7]) * (1.0f / HID);
    Z[v * HID + t] = d * rsqrtf(var + LN_EPS) * gamma[t] + beta[t];
}

// ---------------- layer-3 aggregation + bias + pooled atomics ----------------
__global__ __launch_bounds__(256) void aggpool_kernel(const float* __restrict__ H,
                                                      const float* __restrict__ dis,
                                                      const int* __restrict__ offs,
                                                      const int* __restrict__ csr_s,
                                                      const float* __restrict__ csr_w,
                                                      const float* __restrict__ bias,
                                                      const int* __restrict__ batch32,
                                                      float* __restrict__ pool) {
    int v = blockIdx.x;
    int t = threadIdx.x;
    float dv = dis[v];
    float acc = H[v * HID + t] * (dv * dv);
    int i0 = offs[v], i1 = offs[v + 1];
    for (int i = i0; i < i1; ++i) {
        int s = csr_s[i];
        float w = csr_w[i];
        acc = fmaf(H[s * HID + t], w, acc);
    }
    acc += bias[t];
    atomicAdd(&pool[batch32[v] * HID + t], acc);
}

__global__ __launch_bounds__(256) void final_kernel(const float* __restrict__ pool,
                                                    const int* __restrict__ cnt,
                                                    float* __restrict__ out) {
    int g = blockIdx.x;
    int t = threadIdx.x;
    out[g * HID + t] = pool[g * HID + t] / (float)cnt[g];
}

// ---------------- launch ----------------
extern "C" void kernel_launch(void* const* d_in, const int* in_sizes, int n_in,
                              void* d_out, int out_size, void* d_ws, size_t ws_size,
                              hipStream_t stream) {
    const float* x   = (const float*)d_in[0];
    const float* W1  = (const float*)d_in[1];
    const float* b1  = (const float*)d_in[2];
    const float* g1  = (const float*)d_in[3];
    const float* be1 = (const float*)d_in[4];
    const float* W2  = (const float*)d_in[5];
    const float* b2  = (const float*)d_in[6];
    const float* g2  = (const float*)d_in[7];
    const float* be2 = (const float*)d_in[8];
    const float* W3  = (const float*)d_in[9];
    const float* b3  = (const float*)d_in[10];
    const void*  ei  = d_in[11];
    const void*  bt  = d_in[12];
    float* out = (float*)d_out;

    unsigned int* ws = (unsigned int*)d_ws;
    int*   deg    = (int*)(ws + W_DEG);
    int*   cursor = (int*)(ws + W_CURSOR);
    int*   cnt    = (int*)(ws + W_CNT);
    int*   flag   = (int*)(ws + W_FLAG);
    float* pool   = (float*)(ws + W_POOL);
    int*   offs   = (int*)(ws + W_OFFS);
    float* dis    = (float*)(ws + W_DIS);
    int*   src32  = (int*)(ws + W_SRC32);
    int*   dst32  = (int*)(ws + W_DST32);
    int*   batch32= (int*)(ws + W_BATCH32);
    int*   csr_s  = (int*)(ws + W_CSRS);
    float* csr_w  = (float*)(ws + W_CSRW);
    float* Hbuf   = (float*)(ws + W_H);
    float* Zbuf   = (float*)(ws + W_Z);

    const int EB = (N_EDGES + 255) / 256;   // 3125
    const int NB = (N_NODES + 255) / 256;   // 196

    zero_kernel<<<512, 256, 0, stream>>>(ws, ZERO_WORDS);
    detect_kernel<<<EB, 256, 0, stream>>>((const unsigned int*)ei, flag);
    convert_edges<<<EB, 256, 0, stream>>>(ei, flag, src32, dst32);
    convert_batch<<<NB, 256, 0, stream>>>(bt, flag, batch32);
    deg_kernel<<<EB, 256, 0, stream>>>(dst32, deg);
    cnt_kernel<<<NB, 256, 0, stream>>>(batch32, cnt);
    dis_kernel<<<NB, 256, 0, stream>>>(deg, dis);
    scan_kernel<<<1, 256, 0, stream>>>(deg, offs);
    scatter_kernel<<<EB, 256, 0, stream>>>(src32, dst32, offs, cursor, dis, csr_s, csr_w);

    dim3 gg((N_NODES + BM - 1) / BM, HID / BN);

    // layer 1
    gemm_f32<<<gg, 256, 0, stream>>>(x, W1, Hbuf, N_NODES, IN_DIM);
    aggln_kernel<<<N_NODES, 256, 0, stream>>>(Hbuf, dis, offs, csr_s, csr_w, b1, g1, be1, Zbuf);
    // layer 2
    gemm_f32<<<gg, 256, 0, stream>>>(Zbuf, W2, Hbuf, N_NODES, HID);
    aggln_kernel<<<N_NODES, 256, 0, stream>>>(Hbuf, dis, offs, csr_s, csr_w, b2, g2, be2, Zbuf);
    // layer 3
    gemm_f32<<<gg, 256, 0, stream>>>(Zbuf, W3, Hbuf, N_NODES, HID);
    aggpool_kernel<<<N_NODES, 256, 0, stream>>>(Hbuf, dis, offs, csr_s, csr_w, b3, batch32, pool);
    final_kernel<<<NGRAPH, 256, 0, stream>>>(pool, cnt, out);
}

// Round 2
// 966.095 us; speedup vs baseline: 1.1096x; 1.1096x over previous
//
#include <hip/hip_runtime.h>

#define N_NODES 50000
#define N_EDGES 800000
#define IN_DIM  128
#define HID     256
#define NGRAPH  256
#define LN_EPS  1e-5f

typedef __attribute__((ext_vector_type(8))) short bf16x8;
typedef __attribute__((ext_vector_type(4))) float f32x4;
typedef __attribute__((ext_vector_type(4))) unsigned int u32x4;

// ---------------- workspace layout (32-bit word offsets) ----------------
#define W_DEG      0
#define W_CURSOR   (W_DEG + N_NODES)                 // 50000
#define W_CNT      (W_CURSOR + N_NODES)              // 100000
#define W_FLAG     (W_CNT + NGRAPH)                  // 100256
#define W_POOL     (W_FLAG + 16)                     // 100272
#define ZERO_WORDS (W_POOL + NGRAPH * HID)           // 165808
#define W_OFFS     ZERO_WORDS
#define W_DIS      (W_OFFS + N_NODES + 4)            // keep alignment slack
#define W_SRC32    (((W_DIS + N_NODES) + 3) & ~3)
#define W_DST32    (W_SRC32 + N_EDGES)
#define W_BATCH32  (W_DST32 + N_EDGES)
#define W_CSRSW    (((W_BATCH32 + N_NODES) + 3) & ~3)   // int2 per edge
#define W_WT       (W_CSRSW + 2 * N_EDGES)           // 327680 ushort = 163840 words
#define W_ZH       (((W_WT + 163840) + 3) & ~3)      // 50000*256 bf16 (xh overlays)
#define W_ZL       (W_ZH + (N_NODES * HID / 2))      // 50000*256 bf16 (xl overlays)
#define W_H        (W_ZL + (N_NODES * HID / 2))      // 50000*256 f32

// Wt sub-offsets in ushorts within W_WT
#define WT1H 0
#define WT1L 32768
#define WT2H 65536
#define WT2L 131072
#define WT3H 196608
#define WT3L 262144

__device__ __forceinline__ unsigned short f2b(float f) {
    unsigned int u = __float_as_uint(f);
    unsigned int r = (u + 0x7FFFu + ((u >> 16) & 1u)) >> 16;
    return (unsigned short)r;
}
__device__ __forceinline__ float b2f(unsigned short h) {
    return __uint_as_float(((unsigned int)h) << 16);
}

// ---------------- prep kernels ----------------
__global__ __launch_bounds__(256) void zero_kernel(unsigned int* __restrict__ p, int n) {
    int i = blockIdx.x * 256 + threadIdx.x;
    if (i < n) p[i] = 0u;
}

__global__ __launch_bounds__(256) void detect_kernel(const unsigned int* __restrict__ ei,
                                                     int* __restrict__ flag) {
    int e = blockIdx.x * 256 + threadIdx.x;
    if (e >= N_EDGES) return;
    if (ei[2 * e + 1] != 0u) *flag = 1;
}

__global__ __launch_bounds__(256) void convert_all(const void* __restrict__ ei,
                                                   const void* __restrict__ bt,
                                                   const int* __restrict__ flag,
                                                   int* __restrict__ src32,
                                                   int* __restrict__ dst32,
                                                   int* __restrict__ batch32) {
    int idx = blockIdx.x * 256 + threadIdx.x;
    bool is32 = (*flag != 0);
    if (idx < N_EDGES) {
        if (is32) {
            const int* p = (const int*)ei;
            src32[idx] = p[idx];
            dst32[idx] = p[N_EDGES + idx];
        } else {
            const long long* p = (const long long*)ei;
            src32[idx] = (int)p[idx];
            dst32[idx] = (int)p[N_EDGES + idx];
        }
    } else {
        int v = idx - N_EDGES;
        if (v < N_NODES) {
            batch32[v] = is32 ? ((const int*)bt)[v] : (int)((const long long*)bt)[v];
        }
    }
}

__global__ __launch_bounds__(256) void degcnt_kernel(const int* __restrict__ dst32,
                                                     const int* __restrict__ batch32,
                                                     int* __restrict__ deg,
                                                     int* __restrict__ cnt) {
    int idx = blockIdx.x * 256 + threadIdx.x;
    if (idx < N_EDGES) {
        atomicAdd(&deg[dst32[idx]], 1);
    } else {
        int v = idx - N_EDGES;
        if (v < N_NODES) atomicAdd(&cnt[batch32[v]], 1);
    }
}

// single-block exclusive scan over deg -> offs; also dis = rsqrt(deg+1)
__global__ __launch_bounds__(256) void scan_kernel(const int* __restrict__ deg,
                                                   int* __restrict__ offs,
                                                   float* __restrict__ dis) {
    const int CH = (N_NODES + 255) / 256;  // 196
    int t = threadIdx.x;
    int s0 = t * CH;
    int s1 = min(s0 + CH, N_NODES);
    int sum = 0;
    for (int i = s0; i < s1; ++i) sum += deg[i];
    int lane = t & 63, wid = t >> 6;
    int inc = sum;
    #pragma unroll
    for (int o = 1; o < 64; o <<= 1) {
        int u = __shfl_up(inc, o, 64);
        if (lane >= o) inc += u;
    }
    __shared__ int wsums[4];
    if (lane == 63) wsums[wid] = inc;
    __syncthreads();
    int base = 0;
    for (int w = 0; w < wid; ++w) base += wsums[w];
    int run = base + inc - sum;
    for (int i = s0; i < s1; ++i) {
        offs[i] = run;
        run += deg[i];
        dis[i] = rsqrtf((float)deg[i] + 1.0f);
    }
    if (t == 255) offs[N_NODES] = run;
}

__global__ __launch_bounds__(256) void scatter_kernel(const int* __restrict__ src32,
                                                      const int* __restrict__ dst32,
                                                      const int* __restrict__ offs,
                                                      int* __restrict__ cursor,
                                                      const float* __restrict__ dis,
                                                      int2* __restrict__ csr) {
    int e = blockIdx.x * 256 + threadIdx.x;
    if (e >= N_EDGES) return;
    int s = src32[e], d = dst32[e];
    int pos = atomicAdd(&cursor[d], 1);
    int idx = offs[d] + pos;
    int2 rec;
    rec.x = s;
    rec.y = __float_as_int(dis[s] * dis[d]);
    csr[idx] = rec;
}

// split x into bf16 hi/lo + transpose/split W1,W2,W3 into [N][K] bf16 pairs
#define XSPLIT_BLOCKS 6250   // 50000*128/4 float4 / 256
__global__ __launch_bounds__(256) void prep_w(const float* __restrict__ x,
                                              const float* __restrict__ W1,
                                              const float* __restrict__ W2,
                                              const float* __restrict__ W3,
                                              unsigned short* __restrict__ xh,
                                              unsigned short* __restrict__ xl,
                                              unsigned short* __restrict__ wt) {
    int b = blockIdx.x;
    int t = threadIdx.x;
    if (b < XSPLIT_BLOCKS) {
        int i = b * 256 + t;  // float4 index
        float4 v = ((const float4*)x)[i];
        ushort4 h, lo;
        h.x = f2b(v.x); lo.x = f2b(v.x - b2f(h.x));
        h.y = f2b(v.y); lo.y = f2b(v.y - b2f(h.y));
        h.z = f2b(v.z); lo.z = f2b(v.z - b2f(h.z));
        h.w = f2b(v.w); lo.w = f2b(v.w - b2f(h.w));
        ((ushort4*)xh)[i] = h;
        ((ushort4*)xl)[i] = lo;
    } else {
        int wb = b - XSPLIT_BLOCKS;  // 0..639 : one k-row of one W
        const float* W; int K, k, bh, bl;
        if (wb < 128)      { W = W1; K = 128; k = wb;       bh = WT1H; bl = WT1L; }
        else if (wb < 384) { W = W2; K = 256; k = wb - 128; bh = WT2H; bl = WT2L; }
        else               { W = W3; K = 256; k = wb - 384; bh = WT3H; bl = WT3L; }
        int n = t;  // 0..255
        float val = W[k * HID + n];
        unsigned short hv = f2b(val);
        unsigned short lv = f2b(val - b2f(hv));
        wt[bh + n * K + k] = hv;
        wt[bl + n * K + k] = lv;
    }
}

// ---------------- bf16x2-split MFMA GEMM: C[M x 256] = (Ah+Al) @ (Bh+Bl)^T-stored ----------------
// A: [M][K] bf16 pairs; B given transposed: [256][K] bf16 pairs. C f32 [M][256].
__global__ __launch_bounds__(256) void gemm_bf16x2(const unsigned short* __restrict__ Ah,
                                                   const unsigned short* __restrict__ Al,
                                                   const unsigned short* __restrict__ Bh,
                                                   const unsigned short* __restrict__ Bl,
                                                   float* __restrict__ C,
                                                   int M, int K) {
    // LDS: 4 tiles (Ah,Al,Bh,Bl) of 128 rows x 32 bf16, rows padded to 80B
    __shared__ char lds[4 * 128 * 80];
    int tid = threadIdx.x;
    int bm = blockIdx.x * 128;
    int bn = blockIdx.y * 128;
    int lane = tid & 63, wid = tid >> 6;
    int wm = wid >> 1, wn = wid & 1;
    int lr = lane & 15, lc = lane >> 4;
    f32x4 acc[4][4];
    #pragma unroll
    for (int i = 0; i < 4; ++i)
        #pragma unroll
        for (int j = 0; j < 4; ++j)
            acc[i][j] = (f32x4){0.f, 0.f, 0.f, 0.f};

    const unsigned short* gA[2] = {Ah, Al};
    const unsigned short* gB[2] = {Bh, Bl};

    for (int k0 = 0; k0 < K; k0 += 32) {
        // stage 4 tiles: 2048 16B-chunks, 8 per thread
        #pragma unroll
        for (int c8 = 0; c8 < 8; ++c8) {
            int c = tid + c8 * 256;
            int tile = c >> 9;
            int rr = (c >> 2) & 127;
            int q = c & 3;
            u32x4 v = {0u, 0u, 0u, 0u};
            if (tile < 2) {
                int row = bm + rr;
                if (row < M) v = *(const u32x4*)(gA[tile] + (size_t)row * K + k0 + q * 8);
            } else {
                int row = bn + rr;
                v = *(const u32x4*)(gB[tile - 2] + (size_t)row * K + k0 + q * 8);
            }
            *(u32x4*)(lds + tile * 10240 + rr * 80 + q * 16) = v;
        }
        __syncthreads();
        bf16x8 af[2][4], bfr[2][4];
        #pragma unroll
        for (int p = 0; p < 2; ++p) {
            #pragma unroll
            for (int f = 0; f < 4; ++f) {
                af[p][f]  = *(const bf16x8*)(lds + p * 10240       + (wm * 64 + f * 16 + lr) * 80 + lc * 16);
                bfr[p][f] = *(const bf16x8*)(lds + (2 + p) * 10240 + (wn * 64 + f * 16 + lr) * 80 + lc * 16);
            }
        }
        #pragma unroll
        for (int fi = 0; fi < 4; ++fi) {
            #pragma unroll
            for (int fj = 0; fj < 4; ++fj) {
                acc[fi][fj] = __builtin_amdgcn_mfma_f32_16x16x32_bf16(af[0][fi], bfr[0][fj], acc[fi][fj], 0, 0, 0);
                acc[fi][fj] = __builtin_amdgcn_mfma_f32_16x16x32_bf16(af[0][fi], bfr[1][fj], acc[fi][fj], 0, 0, 0);
                acc[fi][fj] = __builtin_amdgcn_mfma_f32_16x16x32_bf16(af[1][fi], bfr[0][fj], acc[fi][fj], 0, 0, 0);
            }
        }
        __syncthreads();
    }
    // epilogue: D col = lane&15, row = (lane>>4)*4 + reg
    #pragma unroll
    for (int fi = 0; fi < 4; ++fi) {
        int rbase = bm + wm * 64 + fi * 16 + lc * 4;
        #pragma unroll
        for (int fj = 0; fj < 4; ++fj) {
            int col = bn + wn * 64 + fj * 16 + lr;
            #pragma unroll
            for (int r = 0; r < 4; ++r) {
                int row = rbase + r;
                if (row < M) C[(size_t)row * HID + col] = acc[fi][fj][r];
            }
        }
    }
}

// ---------------- fused CSR aggregation + bias + ReLU + LayerNorm (wave per node) ----------------
__global__ __launch_bounds__(256) void aggln_kernel(const float* __restrict__ H,
                                                    const float* __restrict__ dis,
                                                    const int* __restrict__ offs,
                                                    const int2* __restrict__ csr,
                                                    const float* __restrict__ bias,
                                                    const float* __restrict__ gamma,
                                                    const float* __restrict__ beta,
                                                    unsigned short* __restrict__ Zh,
                                                    unsigned short* __restrict__ Zl) {
    int v = blockIdx.x * 4 + (threadIdx.x >> 6);
    int l = threadIdx.x & 63;
    float dv = dis[v];
    float sw = dv * dv;
    float4 a = ((const float4*)(H + (size_t)v * HID))[l];
    float4 acc;
    acc.x = a.x * sw; acc.y = a.y * sw; acc.z = a.z * sw; acc.w = a.w * sw;
    int i0 = offs[v], i1 = offs[v + 1];
    int i = i0;
    for (; i + 4 <= i1; i += 4) {
        int2 e0 = csr[i], e1 = csr[i + 1], e2 = csr[i + 2], e3 = csr[i + 3];
        float4 h0 = ((const float4*)(H + (size_t)e0.x * HID))[l];
        float4 h1 = ((const float4*)(H + (size_t)e1.x * HID))[l];
        float4 h2 = ((const float4*)(H + (size_t)e2.x * HID))[l];
        float4 h3 = ((const float4*)(H + (size_t)e3.x * HID))[l];
        float w0 = __int_as_float(e0.y), w1 = __int_as_float(e1.y);
        float w2 = __int_as_float(e2.y), w3 = __int_as_float(e3.y);
        acc.x = fmaf(h0.x, w0, acc.x); acc.y = fmaf(h0.y, w0, acc.y);
        acc.z = fmaf(h0.z, w0, acc.z); acc.w = fmaf(h0.w, w0, acc.w);
        acc.x = fmaf(h1.x, w1, acc.x); acc.y = fmaf(h1.y, w1, acc.y);
        acc.z = fmaf(h1.z, w1, acc.z); acc.w = fmaf(h1.w, w1, acc.w);
        acc.x = fmaf(h2.x, w2, acc.x); acc.y = fmaf(h2.y, w2, acc.y);
        acc.z = fmaf(h2.z, w2, acc.z); acc.w = fmaf(h2.w, w2, acc.w);
        acc.x = fmaf(h3.x, w3, acc.x); acc.y = fmaf(h3.y, w3, acc.y);
        acc.z = fmaf(h3.z, w3, acc.z); acc.w = fmaf(h3.w, w3, acc.w);
    }
    for (; i < i1; ++i) {
        int2 e = csr[i];
        float4 h = ((const float4*)(H + (size_t)e.x * HID))[l];
        float w = __int_as_float(e.y);
        acc.x = fmaf(h.x, w, acc.x); acc.y = fmaf(h.y, w, acc.y);
        acc.z = fmaf(h.z, w, acc.z); acc.w = fmaf(h.w, w, acc.w);
    }
    float4 b4 = ((const float4*)bias)[l];
    acc.x = fmaxf(acc.x + b4.x, 0.f);
    acc.y = fmaxf(acc.y + b4.y, 0.f);
    acc.z = fmaxf(acc.z + b4.z, 0.f);
    acc.w = fmaxf(acc.w + b4.w, 0.f);
    // LayerNorm across 256 features (64 lanes x 4)
    float s = acc.x + acc.y + acc.z + acc.w;
    #pragma unroll
    for (int o = 32; o >= 1; o >>= 1) s += __shfl_xor(s, o, 64);
    float mu = s * (1.0f / HID);
    float4 d;
    d.x = acc.x - mu; d.y = acc.y - mu; d.z = acc.z - mu; d.w = acc.w - mu;
    float vs = d.x * d.x + d.y * d.y + d.z * d.z + d.w * d.w;
    #pragma unroll
    for (int o = 32; o >= 1; o >>= 1) vs += __shfl_xor(vs, o, 64);
    float inv = rsqrtf(vs * (1.0f / HID) + LN_EPS);
    float4 g4 = ((const float4*)gamma)[l];
    float4 be4 = ((const float4*)beta)[l];
    float z0 = d.x * inv * g4.x + be4.x;
    float z1 = d.y * inv * g4.y + be4.y;
    float z2 = d.z * inv * g4.z + be4.z;
    float z3 = d.w * inv * g4.w + be4.w;
    ushort4 zh, zl;
    zh.x = f2b(z0); zl.x = f2b(z0 - b2f(zh.x));
    zh.y = f2b(z1); zl.y = f2b(z1 - b2f(zh.y));
    zh.z = f2b(z2); zl.z = f2b(z2 - b2f(zh.z));
    zh.w = f2b(z3); zl.w = f2b(z3 - b2f(zh.w));
    *(ushort4*)(Zh + (size_t)v * HID + l * 4) = zh;
    *(ushort4*)(Zl + (size_t)v * HID + l * 4) = zl;
}

// ---------------- layer-3 aggregation + bias + pooled atomics (wave per node) ----------------
__global__ __launch_bounds__(256) void aggpool_kernel(const float* __restrict__ H,
                                                      const float* __restrict__ dis,
                                                      const int* __restrict__ offs,
                                                      const int2* __restrict__ csr,
                                                      const float* __restrict__ bias,
                                                      const int* __restrict__ batch32,
                                                      float* __restrict__ pool) {
    int v = blockIdx.x * 4 + (threadIdx.x >> 6);
    int l = threadIdx.x & 63;
    float dv = dis[v];
    float sw = dv * dv;
    float4 a = ((const float4*)(H + (size_t)v * HID))[l];
    float4 acc;
    acc.x = a.x * sw; acc.y = a.y * sw; acc.z = a.z * sw; acc.w = a.w * sw;
    int i0 = offs[v], i1 = offs[v + 1];
    int i = i0;
    for (; i + 4 <= i1; i += 4) {
        int2 e0 = csr[i], e1 = csr[i + 1], e2 = csr[i + 2], e3 = csr[i + 3];
        float4 h0 = ((const float4*)(H + (size_t)e0.x * HID))[l];
        float4 h1 = ((const float4*)(H + (size_t)e1.x * HID))[l];
        float4 h2 = ((const float4*)(H + (size_t)e2.x * HID))[l];
        float4 h3 = ((const float4*)(H + (size_t)e3.x * HID))[l];
        float w0 = __int_as_float(e0.y), w1 = __int_as_float(e1.y);
        float w2 = __int_as_float(e2.y), w3 = __int_as_float(e3.y);
        acc.x = fmaf(h0.x, w0, acc.x); acc.y = fmaf(h0.y, w0, acc.y);
        acc.z = fmaf(h0.z, w0, acc.z); acc.w = fmaf(h0.w, w0, acc.w);
        acc.x = fmaf(h1.x, w1, acc.x); acc.y = fmaf(h1.y, w1, acc.y);
        acc.z = fmaf(h1.z, w1, acc.z); acc.w = fmaf(h1.w, w1, acc.w);
        acc.x = fmaf(h2.x, w2, acc.x); acc.y = fmaf(h2.y, w2, acc.y);
        acc.z = fmaf(h2.z, w2, acc.z); acc.w = fmaf(h2.w, w2, acc.w);
        acc.x = fmaf(h3.x, w3, acc.x); acc.y = fmaf(h3.y, w3, acc.y);
        acc.z = fmaf(h3.z, w3, acc.z); acc.w = fmaf(h3.w, w3, acc.w);
    }
    for (; i < i1; ++i) {
        int2 e = csr[i];
        float4 h = ((const float4*)(H + (size_t)e.x * HID))[l];
        float w = __int_as_float(e.y);
        acc.x = fmaf(h.x, w, acc.x); acc.y = fmaf(h.y, w, acc.y);
        acc.z = fmaf(h.z, w, acc.z); acc.w = fmaf(h.w, w, acc.w);
    }
    float4 b4 = ((const float4*)bias)[l];
    acc.x += b4.x; acc.y += b4.y; acc.z += b4.z; acc.w += b4.w;
    float* p = pool + (size_t)batch32[v] * HID + l * 4;
    atomicAdd(p + 0, acc.x);
    atomicAdd(p + 1, acc.y);
    atomicAdd(p + 2, acc.z);
    atomicAdd(p + 3, acc.w);
}

__global__ __launch_bounds__(256) void final_kernel(const float* __restrict__ pool,
                                                    const int* __restrict__ cnt,
                                                    float* __restrict__ out) {
    int g = blockIdx.x;
    int t = threadIdx.x;
    out[g * HID + t] = pool[g * HID + t] / (float)cnt[g];
}

// ---------------- launch ----------------
extern "C" void kernel_launch(void* const* d_in, const int* in_sizes, int n_in,
                              void* d_out, int out_size, void* d_ws, size_t ws_size,
                              hipStream_t stream) {
    const float* x   = (const float*)d_in[0];
    const float* W1  = (const float*)d_in[1];
    const float* b1  = (const float*)d_in[2];
    const float* g1  = (const float*)d_in[3];
    const float* be1 = (const float*)d_in[4];
    const float* W2  = (const float*)d_in[5];
    const float* b2  = (const float*)d_in[6];
    const float* g2  = (const float*)d_in[7];
    const float* be2 = (const float*)d_in[8];
    const float* W3  = (const float*)d_in[9];
    const float* b3  = (const float*)d_in[10];
    const void*  ei  = d_in[11];
    const void*  bt  = d_in[12];
    float* out = (float*)d_out;

    unsigned int* ws = (unsigned int*)d_ws;
    int*   deg    = (int*)(ws + W_DEG);
    int*   cursor = (int*)(ws + W_CURSOR);
    int*   cnt    = (int*)(ws + W_CNT);
    int*   flag   = (int*)(ws + W_FLAG);
    float* pool   = (float*)(ws + W_POOL);
    int*   offs   = (int*)(ws + W_OFFS);
    float* dis    = (float*)(ws + W_DIS);
    int*   src32  = (int*)(ws + W_SRC32);
    int*   dst32  = (int*)(ws + W_DST32);
    int*   batch32= (int*)(ws + W_BATCH32);
    int2*  csr    = (int2*)(ws + W_CSRSW);
    unsigned short* wt = (unsigned short*)(ws + W_WT);
    unsigned short* Zh = (unsigned short*)(ws + W_ZH);
    unsigned short* Zl = (unsigned short*)(ws + W_ZL);
    unsigned short* xh = Zh;   // overlay: x-split dead after gemm1
    unsigned short* xl = Zl;
    float* Hbuf   = (float*)(ws + W_H);

    const int EB = (N_EDGES + 255) / 256;
    const int CE = (N_EDGES + N_NODES + 255) / 256;
    const int ZB = (ZERO_WORDS + 255) / 256;

    zero_kernel<<<ZB, 256, 0, stream>>>(ws, ZERO_WORDS);
    detect_kernel<<<EB, 256, 0, stream>>>((const unsigned int*)ei, flag);
    convert_all<<<CE, 256, 0, stream>>>(ei, bt, flag, src32, dst32, batch32);
    degcnt_kernel<<<CE, 256, 0, stream>>>(dst32, batch32, deg, cnt);
    scan_kernel<<<1, 256, 0, stream>>>(deg, offs, dis);
    scatter_kernel<<<EB, 256, 0, stream>>>(src32, dst32, offs, cursor, dis, csr);
    prep_w<<<XSPLIT_BLOCKS + 640, 256, 0, stream>>>(x, W1, W2, W3, xh, xl, wt);

    dim3 gg((N_NODES + 127) / 128, HID / 128);  // (391, 2)
    const int AB = N_NODES / 4;                  // 12500

    // layer 1
    gemm_bf16x2<<<gg, 256, 0, stream>>>(xh, xl, wt + WT1H, wt + WT1L, Hbuf, N_NODES, IN_DIM);
    aggln_kernel<<<AB, 256, 0, stream>>>(Hbuf, dis, offs, csr, b1, g1, be1, Zh, Zl);
    // layer 2
    gemm_bf16x2<<<gg, 256, 0, stream>>>(Zh, Zl, wt + WT2H, wt + WT2L, Hbuf, N_NODES, HID);
    aggln_kernel<<<AB, 256, 0, stream>>>(Hbuf, dis, offs, csr, b2, g2, be2, Zh, Zl);
    // layer 3
    gemm_bf16x2<<<gg, 256, 0, stream>>>(Zh, Zl, wt + WT3H, wt + WT3L, Hbuf, N_NODES, HID);
    aggpool_kernel<<<AB, 256, 0, stream>>>(Hbuf, dis, offs, csr, b3, batch32, pool);
    final_kernel<<<NGRAPH, 256, 0, stream>>>(pool, cnt, out);
}

// Round 3
// 686.910 us; speedup vs baseline: 1.5606x; 1.4064x over previous
//
#include <hip/hip_runtime.h>

#define N_NODES 50000
#define N_EDGES 800000
#define IN_DIM  128
#define HID     256
#define NGRAPH  256
#define LN_EPS  1e-5f

typedef __attribute__((ext_vector_type(8))) short bf16x8;
typedef __attribute__((ext_vector_type(4))) float f32x4;
typedef __attribute__((ext_vector_type(4))) unsigned int u32x4;

// padded CSR capacity (pad each node's edge list to a multiple of 8; max +7/node)
#define PAD_E (N_EDGES + 7 * N_NODES)

// ---------------- workspace layout (32-bit word offsets) ----------------
#define W_DEG      0
#define W_CURSOR   (W_DEG + N_NODES)
#define W_CNT      (W_CURSOR + N_NODES)
#define W_FLAG     (W_CNT + NGRAPH)
#define ZERO_WORDS (W_FLAG + 16)
#define W_BSUM     ZERO_WORDS
#define W_BPRE     (W_BSUM + 256)
#define W_GOFF     (W_BPRE + 256)
#define W_OFFS     (W_GOFF + NGRAPH + 8)
#define W_DIS      (W_OFFS + N_NODES + 8)
#define W_CSR      (((W_DIS + N_NODES) + 3) & ~3)
#define W_WT       (W_CSR + 2 * PAD_E)
#define W_ZH       (((W_WT + 163840) + 3) & ~3)
#define W_ZL       (W_ZH + (N_NODES * HID / 2))
#define W_H        (W_ZL + (N_NODES * HID / 2))

// Wt sub-offsets in ushorts within W_WT
#define WT1H 0
#define WT1L 32768
#define WT2H 65536
#define WT2L 131072
#define WT3H 196608
#define WT3L 262144

__device__ __forceinline__ unsigned short f2b(float f) {
    unsigned int u = __float_as_uint(f);
    unsigned int r = (u + 0x7FFFu + ((u >> 16) & 1u)) >> 16;
    return (unsigned short)r;
}
__device__ __forceinline__ float b2f(unsigned short h) {
    return __uint_as_float(((unsigned int)h) << 16);
}

// ---------------- prep kernels ----------------
__global__ __launch_bounds__(256) void zero_kernel(unsigned int* __restrict__ p, int n) {
    int i = blockIdx.x * 256 + threadIdx.x;
    if (i < n) p[i] = 0u;
}

__global__ __launch_bounds__(256) void detect_kernel(const unsigned int* __restrict__ ei,
                                                     int* __restrict__ flag) {
    int e = blockIdx.x * 256 + threadIdx.x;
    if (e >= N_EDGES) return;
    if (ei[2 * e + 1] != 0u) *flag = 1;
}

__global__ __launch_bounds__(256) void degcnt_kernel(const void* __restrict__ ei,
                                                     const void* __restrict__ bt,
                                                     const int* __restrict__ flag,
                                                     int* __restrict__ deg,
                                                     int* __restrict__ cnt) {
    int idx = blockIdx.x * 256 + threadIdx.x;
    bool is32 = (*flag != 0);
    if (idx < N_EDGES) {
        int d = is32 ? ((const int*)ei)[N_EDGES + idx]
                     : (int)((const long long*)ei)[N_EDGES + idx];
        atomicAdd(&deg[d], 1);
    } else {
        int v = idx - N_EDGES;
        if (v < N_NODES) {
            int b = is32 ? ((const int*)bt)[v] : (int)((const long long*)bt)[v];
            atomicAdd(&cnt[b], 1);
        }
    }
}

// per-block sums of padded degrees
__global__ __launch_bounds__(256) void blocksum_kernel(const int* __restrict__ deg,
                                                       int* __restrict__ bsum) {
    int b = blockIdx.x, t = threadIdx.x;
    int i = b * 256 + t;
    int pd = (i < N_NODES) ? ((deg[i] + 7) & ~7) : 0;
    int lane = t & 63, w = t >> 6;
    int s = pd;
    #pragma unroll
    for (int o = 32; o >= 1; o >>= 1) s += __shfl_xor(s, o, 64);
    __shared__ int ws[4];
    if (lane == 0) ws[w] = s;
    __syncthreads();
    if (t == 0) bsum[b] = ws[0] + ws[1] + ws[2] + ws[3];
}

// single tiny block: exclusive scan bsum(196) -> bpre; exclusive scan cnt(256) -> goffs
__global__ __launch_bounds__(256) void scan_small(const int* __restrict__ bsum,
                                                  int* __restrict__ bpre,
                                                  const int* __restrict__ cnt,
                                                  int* __restrict__ goffs) {
    int t = threadIdx.x;
    int lane = t & 63, w = t >> 6;
    {
        int x = (t < 196) ? bsum[t] : 0;
        int inc = x;
        #pragma unroll
        for (int o = 1; o < 64; o <<= 1) {
            int u = __shfl_up(inc, o, 64);
            if (lane >= o) inc += u;
        }
        __shared__ int wsA[4];
        if (lane == 63) wsA[w] = inc;
        __syncthreads();
        int base = 0;
        for (int k = 0; k < w; ++k) base += wsA[k];
        bpre[t] = base + inc - x;
        __syncthreads();
    }
    {
        int y = cnt[t];
        int inc = y;
        #pragma unroll
        for (int o = 1; o < 64; o <<= 1) {
            int u = __shfl_up(inc, o, 64);
            if (lane >= o) inc += u;
        }
        __shared__ int wsB[4];
        if (lane == 63) wsB[w] = inc;
        __syncthreads();
        int base = 0;
        for (int k = 0; k < w; ++k) base += wsB[k];
        goffs[t] = base + inc - y;
        if (t == 255) goffs[256] = base + inc;
    }
}

// per-node padded offsets + dis
__global__ __launch_bounds__(256) void finalize_kernel(const int* __restrict__ deg,
                                                       const int* __restrict__ bpre,
                                                       int* __restrict__ offs,
                                                       float* __restrict__ dis) {
    int b = blockIdx.x, t = threadIdx.x;
    int i = b * 256 + t;
    int d = (i < N_NODES) ? deg[i] : 0;
    int pd = (d + 7) & ~7;
    int lane = t & 63, w = t >> 6;
    int inc = pd;
    #pragma unroll
    for (int o = 1; o < 64; o <<= 1) {
        int u = __shfl_up(inc, o, 64);
        if (lane >= o) inc += u;
    }
    __shared__ int ws[4];
    if (lane == 63) ws[w] = inc;
    __syncthreads();
    int base = 0;
    for (int k = 0; k < w; ++k) base += ws[k];
    int pre = base + inc - pd;
    if (i < N_NODES) {
        offs[i] = bpre[b] + pre;
        dis[i] = rsqrtf((float)d + 1.0f);
    }
    if (i == N_NODES - 1) offs[N_NODES] = bpre[b] + pre + pd;
}

__global__ __launch_bounds__(256) void scatter_kernel(const void* __restrict__ ei,
                                                      const int* __restrict__ flag,
                                                      const int* __restrict__ offs,
                                                      int* __restrict__ cursor,
                                                      const float* __restrict__ dis,
                                                      int2* __restrict__ csr) {
    int e = blockIdx.x * 256 + threadIdx.x;
    if (e >= N_EDGES) return;
    bool is32 = (*flag != 0);
    int s, d;
    if (is32) {
        const int* p = (const int*)ei;
        s = p[e]; d = p[N_EDGES + e];
    } else {
        const long long* p = (const long long*)ei;
        s = (int)p[e]; d = (int)p[N_EDGES + e];
    }
    int pos = atomicAdd(&cursor[d], 1);
    int idx = offs[d] + pos;
    int2 rec;
    rec.x = s;
    rec.y = __float_as_int(dis[s] * dis[d]);
    csr[idx] = rec;
}

// split x into bf16 hi/lo + transpose/split W1,W2,W3 into [N][K] bf16 pairs
#define XSPLIT_BLOCKS 6250
__global__ __launch_bounds__(256) void prep_w(const float* __restrict__ x,
                                              const float* __restrict__ W1,
                                              const float* __restrict__ W2,
                                              const float* __restrict__ W3,
                                              unsigned short* __restrict__ xh,
                                              unsigned short* __restrict__ xl,
                                              unsigned short* __restrict__ wt) {
    int b = blockIdx.x;
    int t = threadIdx.x;
    if (b < XSPLIT_BLOCKS) {
        int i = b * 256 + t;
        float4 v = ((const float4*)x)[i];
        ushort4 h, lo;
        h.x = f2b(v.x); lo.x = f2b(v.x - b2f(h.x));
        h.y = f2b(v.y); lo.y = f2b(v.y - b2f(h.y));
        h.z = f2b(v.z); lo.z = f2b(v.z - b2f(h.z));
        h.w = f2b(v.w); lo.w = f2b(v.w - b2f(h.w));
        ((ushort4*)xh)[i] = h;
        ((ushort4*)xl)[i] = lo;
    } else {
        int wb = b - XSPLIT_BLOCKS;
        const float* W; int K, k, bh, bl;
        if (wb < 128)      { W = W1; K = 128; k = wb;       bh = WT1H; bl = WT1L; }
        else if (wb < 384) { W = W2; K = 256; k = wb - 128; bh = WT2H; bl = WT2L; }
        else               { W = W3; K = 256; k = wb - 384; bh = WT3H; bl = WT3L; }
        int n = t;
        float val = W[k * HID + n];
        unsigned short hv = f2b(val);
        unsigned short lv = f2b(val - b2f(hv));
        wt[bh + n * K + k] = hv;
        wt[bl + n * K + k] = lv;
    }
}

// ---------------- bf16x2-split MFMA GEMM (unchanged from R2) ----------------
__global__ __launch_bounds__(256) void gemm_bf16x2(const unsigned short* __restrict__ Ah,
                                                   const unsigned short* __restrict__ Al,
                                                   const unsigned short* __restrict__ Bh,
                                                   const unsigned short* __restrict__ Bl,
                                                   float* __restrict__ C,
                                                   int M, int K) {
    __shared__ char lds[4 * 128 * 80];
    int tid = threadIdx.x;
    int bm = blockIdx.x * 128;
    int bn = blockIdx.y * 128;
    int lane = tid & 63, wid = tid >> 6;
    int wm = wid >> 1, wn = wid & 1;
    int lr = lane & 15, lc = lane >> 4;
    f32x4 acc[4][4];
    #pragma unroll
    for (int i = 0; i < 4; ++i)
        #pragma unroll
        for (int j = 0; j < 4; ++j)
            acc[i][j] = (f32x4){0.f, 0.f, 0.f, 0.f};

    const unsigned short* gA[2] = {Ah, Al};
    const unsigned short* gB[2] = {Bh, Bl};

    for (int k0 = 0; k0 < K; k0 += 32) {
        #pragma unroll
        for (int c8 = 0; c8 < 8; ++c8) {
            int c = tid + c8 * 256;
            int tile = c >> 9;
            int rr = (c >> 2) & 127;
            int q = c & 3;
            u32x4 v = {0u, 0u, 0u, 0u};
            if (tile < 2) {
                int row = bm + rr;
                if (row < M) v = *(const u32x4*)(gA[tile] + (size_t)row * K + k0 + q * 8);
            } else {
                int row = bn + rr;
                v = *(const u32x4*)(gB[tile - 2] + (size_t)row * K + k0 + q * 8);
            }
            *(u32x4*)(lds + tile * 10240 + rr * 80 + q * 16) = v;
        }
        __syncthreads();
        bf16x8 af[2][4], bfr[2][4];
        #pragma unroll
        for (int p = 0; p < 2; ++p) {
            #pragma unroll
            for (int f = 0; f < 4; ++f) {
                af[p][f]  = *(const bf16x8*)(lds + p * 10240       + (wm * 64 + f * 16 + lr) * 80 + lc * 16);
                bfr[p][f] = *(const bf16x8*)(lds + (2 + p) * 10240 + (wn * 64 + f * 16 + lr) * 80 + lc * 16);
            }
        }
        #pragma unroll
        for (int fi = 0; fi < 4; ++fi) {
            #pragma unroll
            for (int fj = 0; fj < 4; ++fj) {
                acc[fi][fj] = __builtin_amdgcn_mfma_f32_16x16x32_bf16(af[0][fi], bfr[0][fj], acc[fi][fj], 0, 0, 0);
                acc[fi][fj] = __builtin_amdgcn_mfma_f32_16x16x32_bf16(af[0][fi], bfr[1][fj], acc[fi][fj], 0, 0, 0);
                acc[fi][fj] = __builtin_amdgcn_mfma_f32_16x16x32_bf16(af[1][fi], bfr[0][fj], acc[fi][fj], 0, 0, 0);
            }
        }
        __syncthreads();
    }
    #pragma unroll
    for (int fi = 0; fi < 4; ++fi) {
        int rbase = bm + wm * 64 + fi * 16 + lc * 4;
        #pragma unroll
        for (int fj = 0; fj < 4; ++fj) {
            int col = bn + wn * 64 + fj * 16 + lr;
            #pragma unroll
            for (int r = 0; r < 4; ++r) {
                int row = rbase + r;
                if (row < M) C[(size_t)row * HID + col] = acc[fi][fj][r];
            }
        }
    }
}

// ---------------- fused aggregation: 2 nodes/wave, 8-edge chunks ----------------
#define DECL_CH(P) int4 P##c0, P##c1, P##c2, P##c3; \
                   float4 P##h0, P##h1, P##h2, P##h3, P##h4, P##h5, P##h6, P##h7;

#define LOAD8(P, idx) do { \
    const int4* _q = (const int4*)(csr + (idx)); \
    P##c0 = _q[0]; P##c1 = _q[1]; P##c2 = _q[2]; P##c3 = _q[3]; \
    P##h0 = ((const float4*)(H + (size_t)P##c0.x * HID))[l]; \
    P##h1 = ((const float4*)(H + (size_t)P##c0.z * HID))[l]; \
    P##h2 = ((const float4*)(H + (size_t)P##c1.x * HID))[l]; \
    P##h3 = ((const float4*)(H + (size_t)P##c1.z * HID))[l]; \
    P##h4 = ((const float4*)(H + (size_t)P##c2.x * HID))[l]; \
    P##h5 = ((const float4*)(H + (size_t)P##c2.z * HID))[l]; \
    P##h6 = ((const float4*)(H + (size_t)P##c3.x * HID))[l]; \
    P##h7 = ((const float4*)(H + (size_t)P##c3.z * HID))[l]; \
} while (0)

#define FMA4(hv, wv, a) do { float _w = (wv); \
    a.x = fmaf(hv.x, _w, a.x); a.y = fmaf(hv.y, _w, a.y); \
    a.z = fmaf(hv.z, _w, a.z); a.w = fmaf(hv.w, _w, a.w); } while (0)

#define CONS8(P, a) do { \
    FMA4(P##h0, __int_as_float(P##c0.y), a); \
    FMA4(P##h1, __int_as_float(P##c0.w), a); \
    FMA4(P##h2, __int_as_float(P##c1.y), a); \
    FMA4(P##h3, __int_as_float(P##c1.w), a); \
    FMA4(P##h4, __int_as_float(P##c2.y), a); \
    FMA4(P##h5, __int_as_float(P##c2.w), a); \
    FMA4(P##h6, __int_as_float(P##c3.y), a); \
    FMA4(P##h7, __int_as_float(P##c3.w), a); \
} while (0)

// MODE 0: +bias, ReLU, LayerNorm, write bf16 hi/lo.  MODE 1: +bias, write f32 rows.
template <int MODE>
__global__ __launch_bounds__(256) void agg_kernel(const float* __restrict__ H,
                                                  const float* __restrict__ dis,
                                                  const int* __restrict__ offs,
                                                  const int2* __restrict__ csr,
                                                  const float* __restrict__ bias,
                                                  const float* __restrict__ gamma,
                                                  const float* __restrict__ beta,
                                                  unsigned short* __restrict__ Zh,
                                                  unsigned short* __restrict__ Zl,
                                                  float* __restrict__ O) {
    int wg = blockIdx.x * 4 + (threadIdx.x >> 6);
    int l = threadIdx.x & 63;
    int v0 = wg * 2, v1 = wg * 2 + 1;

    float dv0 = dis[v0], dv1 = dis[v1];
    float4 a0 = ((const float4*)(H + (size_t)v0 * HID))[l];
    float4 a1 = ((const float4*)(H + (size_t)v1 * HID))[l];
    float sl0 = dv0 * dv0, sl1 = dv1 * dv1;
    float4 acc0, acc1;
    acc0.x = a0.x * sl0; acc0.y = a0.y * sl0; acc0.z = a0.z * sl0; acc0.w = a0.w * sl0;
    acc1.x = a1.x * sl1; acc1.y = a1.y * sl1; acc1.z = a1.z * sl1; acc1.w = a1.w * sl1;

    int ia = offs[v0], ea = offs[v0 + 1];
    int ib = offs[v1], eb = offs[v1 + 1];
    DECL_CH(A)
    DECL_CH(B)
    while (ia < ea && ib < eb) {
        LOAD8(A, ia);
        LOAD8(B, ib);
        CONS8(A, acc0);
        CONS8(B, acc1);
        ia += 8; ib += 8;
    }
    while (ia < ea) { LOAD8(A, ia); CONS8(A, acc0); ia += 8; }
    while (ib < eb) { LOAD8(B, ib); CONS8(B, acc1); ib += 8; }

    float4 b4 = ((const float4*)bias)[l];
    if (MODE == 0) {
        acc0.x = fmaxf(acc0.x + b4.x, 0.f); acc0.y = fmaxf(acc0.y + b4.y, 0.f);
        acc0.z = fmaxf(acc0.z + b4.z, 0.f); acc0.w = fmaxf(acc0.w + b4.w, 0.f);
        acc1.x = fmaxf(acc1.x + b4.x, 0.f); acc1.y = fmaxf(acc1.y + b4.y, 0.f);
        acc1.z = fmaxf(acc1.z + b4.z, 0.f); acc1.w = fmaxf(acc1.w + b4.w, 0.f);
        float s0 = acc0.x + acc0.y + acc0.z + acc0.w;
        float s1 = acc1.x + acc1.y + acc1.z + acc1.w;
        #pragma unroll
        for (int o = 32; o >= 1; o >>= 1) {
            s0 += __shfl_xor(s0, o, 64);
            s1 += __shfl_xor(s1, o, 64);
        }
        float mu0 = s0 * (1.0f / HID), mu1 = s1 * (1.0f / HID);
        float4 d0, d1;
        d0.x = acc0.x - mu0; d0.y = acc0.y - mu0; d0.z = acc0.z - mu0; d0.w = acc0.w - mu0;
        d1.x = acc1.x - mu1; d1.y = acc1.y - mu1; d1.z = acc1.z - mu1; d1.w = acc1.w - mu1;
        float vs0 = d0.x * d0.x + d0.y * d0.y + d0.z * d0.z + d0.w * d0.w;
        float vs1 = d1.x * d1.x + d1.y * d1.y + d1.z * d1.z + d1.w * d1.w;
        #pragma unroll
        for (int o = 32; o >= 1; o >>= 1) {
            vs0 += __shfl_xor(vs0, o, 64);
            vs1 += __shfl_xor(vs1, o, 64);
        }
        float inv0 = rsqrtf(vs0 * (1.0f / HID) + LN_EPS);
        float inv1 = rsqrtf(vs1 * (1.0f / HID) + LN_EPS);
        float4 g4 = ((const float4*)gamma)[l];
        float4 be4 = ((const float4*)beta)[l];
        float z0 = d0.x * inv0 * g4.x + be4.x;
        float z1 = d0.y * inv0 * g4.y + be4.y;
        float z2 = d0.z * inv0 * g4.z + be4.z;
        float z3 = d0.w * inv0 * g4.w + be4.w;
        ushort4 zh, zl;
        zh.x = f2b(z0); zl.x = f2b(z0 - b2f(zh.x));
        zh.y = f2b(z1); zl.y = f2b(z1 - b2f(zh.y));
        zh.z = f2b(z2); zl.z = f2b(z2 - b2f(zh.z));
        zh.w = f2b(z3); zl.w = f2b(z3 - b2f(zh.w));
        *(ushort4*)(Zh + (size_t)v0 * HID + l * 4) = zh;
        *(ushort4*)(Zl + (size_t)v0 * HID + l * 4) = zl;
        z0 = d1.x * inv1 * g4.x + be4.x;
        z1 = d1.y * inv1 * g4.y + be4.y;
        z2 = d1.z * inv1 * g4.z + be4.z;
        z3 = d1.w * inv1 * g4.w + be4.w;
        zh.x = f2b(z0); zl.x = f2b(z0 - b2f(zh.x));
        zh.y = f2b(z1); zl.y = f2b(z1 - b2f(zh.y));
        zh.z = f2b(z2); zl.z = f2b(z2 - b2f(zh.z));
        zh.w = f2b(z3); zl.w = f2b(z3 - b2f(zh.w));
        *(ushort4*)(Zh + (size_t)v1 * HID + l * 4) = zh;
        *(ushort4*)(Zl + (size_t)v1 * HID + l * 4) = zl;
    } else {
        float4 o0, o1;
        o0.x = acc0.x + b4.x; o0.y = acc0.y + b4.y; o0.z = acc0.z + b4.z; o0.w = acc0.w + b4.w;
        o1.x = acc1.x + b4.x; o1.y = acc1.y + b4.y; o1.z = acc1.z + b4.z; o1.w = acc1.w + b4.w;
        ((float4*)(O + (size_t)v0 * HID))[l] = o0;
        ((float4*)(O + (size_t)v1 * HID))[l] = o1;
    }
}

// ---------------- per-graph segment-mean pool (batch is sorted) ----------------
__global__ __launch_bounds__(256) void pool_kernel(const float* __restrict__ O,
                                                   const int* __restrict__ goffs,
                                                   float* __restrict__ out) {
    int g = blockIdx.x, t = threadIdx.x;
    int l = t & 63, w = t >> 6;
    int s = goffs[g], e = goffs[g + 1];
    float4 acc = make_float4(0.f, 0.f, 0.f, 0.f);
    for (int v = s + w; v < e; v += 4) {
        float4 r = ((const float4*)(O + (size_t)v * HID))[l];
        acc.x += r.x; acc.y += r.y; acc.z += r.z; acc.w += r.w;
    }
    __shared__ float4 red[4][64];
    red[w][l] = acc;
    __syncthreads();
    if (w == 0) {
        float4 r0 = red[0][l], r1 = red[1][l], r2 = red[2][l], r3 = red[3][l];
        float inv = 1.0f / (float)(e - s);
        float4 o;
        o.x = (r0.x + r1.x + r2.x + r3.x) * inv;
        o.y = (r0.y + r1.y + r2.y + r3.y) * inv;
        o.z = (r0.z + r1.z + r2.z + r3.z) * inv;
        o.w = (r0.w + r1.w + r2.w + r3.w) * inv;
        ((float4*)(out + (size_t)g * HID))[l] = o;
    }
}

// ---------------- launch ----------------
extern "C" void kernel_launch(void* const* d_in, const int* in_sizes, int n_in,
                              void* d_out, int out_size, void* d_ws, size_t ws_size,
                              hipStream_t stream) {
    const float* x   = (const float*)d_in[0];
    const float* W1  = (const float*)d_in[1];
    const float* b1  = (const float*)d_in[2];
    const float* g1  = (const float*)d_in[3];
    const float* be1 = (const float*)d_in[4];
    const float* W2  = (const float*)d_in[5];
    const float* b2  = (const float*)d_in[6];
    const float* g2  = (const float*)d_in[7];
    const float* be2 = (const float*)d_in[8];
    const float* W3  = (const float*)d_in[9];
    const float* b3  = (const float*)d_in[10];
    const void*  ei  = d_in[11];
    const void*  bt  = d_in[12];
    float* out = (float*)d_out;

    unsigned int* ws = (unsigned int*)d_ws;
    int*   deg    = (int*)(ws + W_DEG);
    int*   cursor = (int*)(ws + W_CURSOR);
    int*   cnt    = (int*)(ws + W_CNT);
    int*   flag   = (int*)(ws + W_FLAG);
    int*   bsum   = (int*)(ws + W_BSUM);
    int*   bpre   = (int*)(ws + W_BPRE);
    int*   goffs  = (int*)(ws + W_GOFF);
    int*   offs   = (int*)(ws + W_OFFS);
    float* dis    = (float*)(ws + W_DIS);
    int2*  csr    = (int2*)(ws + W_CSR);
    unsigned short* wt = (unsigned short*)(ws + W_WT);
    unsigned short* Zh = (unsigned short*)(ws + W_ZH);
    unsigned short* Zl = (unsigned short*)(ws + W_ZL);
    unsigned short* xh = Zh;            // overlay: x-split dead after gemm1
    unsigned short* xl = Zl;
    float* Hbuf = (float*)(ws + W_H);
    float* Obuf = (float*)(ws + W_ZH);  // overlay: Zh/Zl dead after gemm3

    const int EB = (N_EDGES + 255) / 256;
    const int CE = (N_EDGES + N_NODES + 255) / 256;
    const int NB = (N_NODES + 255) / 256;  // 196

    zero_kernel<<<(ZERO_WORDS + 255) / 256, 256, 0, stream>>>(ws, ZERO_WORDS);
    zero_kernel<<<(2 * PAD_E + 255) / 256, 256, 0, stream>>>(ws + W_CSR, 2 * PAD_E);
    detect_kernel<<<EB, 256, 0, stream>>>((const unsigned int*)ei, flag);
    degcnt_kernel<<<CE, 256, 0, stream>>>(ei, bt, flag, deg, cnt);
    blocksum_kernel<<<NB, 256, 0, stream>>>(deg, bsum);
    scan_small<<<1, 256, 0, stream>>>(bsum, bpre, cnt, goffs);
    finalize_kernel<<<NB, 256, 0, stream>>>(deg, bpre, offs, dis);
    scatter_kernel<<<EB, 256, 0, stream>>>(ei, flag, offs, cursor, dis, csr);
    prep_w<<<XSPLIT_BLOCKS + 640, 256, 0, stream>>>(x, W1, W2, W3, xh, xl, wt);

    dim3 gg((N_NODES + 127) / 128, HID / 128);
    const int AB = N_NODES / 8;  // 6250 blocks = 25000 waves = 2 nodes/wave

    gemm_bf16x2<<<gg, 256, 0, stream>>>(xh, xl, wt + WT1H, wt + WT1L, Hbuf, N_NODES, IN_DIM);
    agg_kernel<0><<<AB, 256, 0, stream>>>(Hbuf, dis, offs, csr, b1, g1, be1, Zh, Zl, nullptr);
    gemm_bf16x2<<<gg, 256, 0, stream>>>(Zh, Zl, wt + WT2H, wt + WT2L, Hbuf, N_NODES, HID);
    agg_kernel<0><<<AB, 256, 0, stream>>>(Hbuf, dis, offs, csr, b2, g2, be2, Zh, Zl, nullptr);
    gemm_bf16x2<<<gg, 256, 0, stream>>>(Zh, Zl, wt + WT3H, wt + WT3L, Hbuf, N_NODES, HID);
    agg_kernel<1><<<AB, 256, 0, stream>>>(Hbuf, dis, offs, csr, b3, nullptr, nullptr, nullptr, nullptr, Obuf);
    pool_kernel<<<NGRAPH, 256, 0, stream>>>(Obuf, goffs, out);
}

// Round 4
// 673.722 us; speedup vs baseline: 1.5912x; 1.0196x over previous
//
#include <hip/hip_runtime.h>

#define N_NODES 50000
#define N_EDGES 800000
#define IN_DIM  128
#define HID     256
#define NGRAPH  256
#define LN_EPS  1e-5f

typedef __attribute__((ext_vector_type(8))) short bf16x8;
typedef __attribute__((ext_vector_type(4))) float f32x4;
typedef __attribute__((ext_vector_type(4))) unsigned int u32x4;

// padded CSR capacity (pad each node's edge list to a multiple of 8; max +7/node)
#define PAD_E (N_EDGES + 7 * N_NODES)

// ---------------- workspace layout (32-bit word offsets) ----------------
#define W_DEG      0
#define W_CURSOR   (W_DEG + N_NODES)
#define W_CNT      (W_CURSOR + N_NODES)
#define W_FLAG     (W_CNT + NGRAPH)
#define ZERO_WORDS (W_FLAG + 16)
#define W_BSUM     ZERO_WORDS
#define W_BPRE     (W_BSUM + 256)
#define W_GOFF     (W_BPRE + 256)
#define W_OFFS     (W_GOFF + NGRAPH + 8)
#define W_DIS      (W_OFFS + N_NODES + 8)
#define W_CSR      (((W_DIS + N_NODES) + 3) & ~3)
#define W_WT       (W_CSR + 2 * PAD_E)
#define W_ZH       (((W_WT + 163840) + 3) & ~3)
#define W_ZL       (W_ZH + (N_NODES * HID / 2))
#define W_H        (W_ZL + (N_NODES * HID / 2))

// Wt sub-offsets in ushorts within W_WT
#define WT1H 0
#define WT1L 32768
#define WT2H 65536
#define WT2L 131072
#define WT3H 196608
#define WT3L 262144

__device__ __forceinline__ unsigned short f2b(float f) {
    unsigned int u = __float_as_uint(f);
    unsigned int r = (u + 0x7FFFu + ((u >> 16) & 1u)) >> 16;
    return (unsigned short)r;
}
__device__ __forceinline__ float b2f(unsigned short h) {
    return __uint_as_float(((unsigned int)h) << 16);
}

// ---------------- prep kernels ----------------
__global__ __launch_bounds__(256) void zero_kernel(unsigned int* __restrict__ p, int n) {
    int i = blockIdx.x * 256 + threadIdx.x;
    if (i < n) p[i] = 0u;
}

__global__ __launch_bounds__(256) void detect_kernel(const unsigned int* __restrict__ ei,
                                                     int* __restrict__ flag) {
    int e = blockIdx.x * 256 + threadIdx.x;
    if (e >= N_EDGES) return;
    if (ei[2 * e + 1] != 0u) *flag = 1;
}

__global__ __launch_bounds__(256) void degcnt_kernel(const void* __restrict__ ei,
                                                     const void* __restrict__ bt,
                                                     const int* __restrict__ flag,
                                                     int* __restrict__ deg,
                                                     int* __restrict__ cnt) {
    int idx = blockIdx.x * 256 + threadIdx.x;
    bool is32 = (*flag != 0);
    if (idx < N_EDGES) {
        int d = is32 ? ((const int*)ei)[N_EDGES + idx]
                     : (int)((const long long*)ei)[N_EDGES + idx];
        atomicAdd(&deg[d], 1);
    } else {
        int v = idx - N_EDGES;
        if (v < N_NODES) {
            int b = is32 ? ((const int*)bt)[v] : (int)((const long long*)bt)[v];
            atomicAdd(&cnt[b], 1);
        }
    }
}

// per-block sums of padded degrees
__global__ __launch_bounds__(256) void blocksum_kernel(const int* __restrict__ deg,
                                                       int* __restrict__ bsum) {
    int b = blockIdx.x, t = threadIdx.x;
    int i = b * 256 + t;
    int pd = (i < N_NODES) ? ((deg[i] + 7) & ~7) : 0;
    int lane = t & 63, w = t >> 6;
    int s = pd;
    #pragma unroll
    for (int o = 32; o >= 1; o >>= 1) s += __shfl_xor(s, o, 64);
    __shared__ int ws[4];
    if (lane == 0) ws[w] = s;
    __syncthreads();
    if (t == 0) bsum[b] = ws[0] + ws[1] + ws[2] + ws[3];
}

// single tiny block: exclusive scan bsum(196) -> bpre; exclusive scan cnt(256) -> goffs
__global__ __launch_bounds__(256) void scan_small(const int* __restrict__ bsum,
                                                  int* __restrict__ bpre,
                                                  const int* __restrict__ cnt,
                                                  int* __restrict__ goffs) {
    int t = threadIdx.x;
    int lane = t & 63, w = t >> 6;
    {
        int x = (t < 196) ? bsum[t] : 0;
        int inc = x;
        #pragma unroll
        for (int o = 1; o < 64; o <<= 1) {
            int u = __shfl_up(inc, o, 64);
            if (lane >= o) inc += u;
        }
        __shared__ int wsA[4];
        if (lane == 63) wsA[w] = inc;
        __syncthreads();
        int base = 0;
        for (int k = 0; k < w; ++k) base += wsA[k];
        bpre[t] = base + inc - x;
        __syncthreads();
    }
    {
        int y = cnt[t];
        int inc = y;
        #pragma unroll
        for (int o = 1; o < 64; o <<= 1) {
            int u = __shfl_up(inc, o, 64);
            if (lane >= o) inc += u;
        }
        __shared__ int wsB[4];
        if (lane == 63) wsB[w] = inc;
        __syncthreads();
        int base = 0;
        for (int k = 0; k < w; ++k) base += wsB[k];
        goffs[t] = base + inc - y;
        if (t == 255) goffs[256] = base + inc;
    }
}

// per-node padded offsets + dis
__global__ __launch_bounds__(256) void finalize_kernel(const int* __restrict__ deg,
                                                       const int* __restrict__ bpre,
                                                       int* __restrict__ offs,
                                                       float* __restrict__ dis) {
    int b = blockIdx.x, t = threadIdx.x;
    int i = b * 256 + t;
    int d = (i < N_NODES) ? deg[i] : 0;
    int pd = (d + 7) & ~7;
    int lane = t & 63, w = t >> 6;
    int inc = pd;
    #pragma unroll
    for (int o = 1; o < 64; o <<= 1) {
        int u = __shfl_up(inc, o, 64);
        if (lane >= o) inc += u;
    }
    __shared__ int ws[4];
    if (lane == 63) ws[w] = inc;
    __syncthreads();
    int base = 0;
    for (int k = 0; k < w; ++k) base += ws[k];
    int pre = base + inc - pd;
    if (i < N_NODES) {
        offs[i] = bpre[b] + pre;
        dis[i] = rsqrtf((float)d + 1.0f);
    }
    if (i == N_NODES - 1) offs[N_NODES] = bpre[b] + pre + pd;
}

__global__ __launch_bounds__(256) void scatter_kernel(const void* __restrict__ ei,
                                                      const int* __restrict__ flag,
                                                      const int* __restrict__ offs,
                                                      int* __restrict__ cursor,
                                                      const float* __restrict__ dis,
                                                      int2* __restrict__ csr) {
    int e = blockIdx.x * 256 + threadIdx.x;
    if (e >= N_EDGES) return;
    bool is32 = (*flag != 0);
    int s, d;
    if (is32) {
        const int* p = (const int*)ei;
        s = p[e]; d = p[N_EDGES + e];
    } else {
        const long long* p = (const long long*)ei;
        s = (int)p[e]; d = (int)p[N_EDGES + e];
    }
    int pos = atomicAdd(&cursor[d], 1);
    int idx = offs[d] + pos;
    int2 rec;
    rec.x = s;
    rec.y = __float_as_int(dis[s] * dis[d]);
    csr[idx] = rec;
}

// split x into bf16 hi/lo + transpose/split W1,W2,W3 into [N][K] bf16 pairs
#define XSPLIT_BLOCKS 6250
__global__ __launch_bounds__(256) void prep_w(const float* __restrict__ x,
                                              const float* __restrict__ W1,
                                              const float* __restrict__ W2,
                                              const float* __restrict__ W3,
                                              unsigned short* __restrict__ xh,
                                              unsigned short* __restrict__ xl,
                                              unsigned short* __restrict__ wt) {
    int b = blockIdx.x;
    int t = threadIdx.x;
    if (b < XSPLIT_BLOCKS) {
        int i = b * 256 + t;
        float4 v = ((const float4*)x)[i];
        ushort4 h, lo;
        h.x = f2b(v.x); lo.x = f2b(v.x - b2f(h.x));
        h.y = f2b(v.y); lo.y = f2b(v.y - b2f(h.y));
        h.z = f2b(v.z); lo.z = f2b(v.z - b2f(h.z));
        h.w = f2b(v.w); lo.w = f2b(v.w - b2f(h.w));
        ((ushort4*)xh)[i] = h;
        ((ushort4*)xl)[i] = lo;
    } else {
        int wb = b - XSPLIT_BLOCKS;
        const float* W; int K, k, bh, bl;
        if (wb < 128)      { W = W1; K = 128; k = wb;       bh = WT1H; bl = WT1L; }
        else if (wb < 384) { W = W2; K = 256; k = wb - 128; bh = WT2H; bl = WT2L; }
        else               { W = W3; K = 256; k = wb - 384; bh = WT3H; bl = WT3L; }
        int n = t;
        float val = W[k * HID + n];
        unsigned short hv = f2b(val);
        unsigned short lv = f2b(val - b2f(hv));
        wt[bh + n * K + k] = hv;
        wt[bl + n * K + k] = lv;
    }
}

// ---------------- bf16x2-split MFMA GEMM (unchanged) ----------------
__global__ __launch_bounds__(256) void gemm_bf16x2(const unsigned short* __restrict__ Ah,
                                                   const unsigned short* __restrict__ Al,
                                                   const unsigned short* __restrict__ Bh,
                                                   const unsigned short* __restrict__ Bl,
                                                   float* __restrict__ C,
                                                   int M, int K) {
    __shared__ char lds[4 * 128 * 80];
    int tid = threadIdx.x;
    int bm = blockIdx.x * 128;
    int bn = blockIdx.y * 128;
    int lane = tid & 63, wid = tid >> 6;
    int wm = wid >> 1, wn = wid & 1;
    int lr = lane & 15, lc = lane >> 4;
    f32x4 acc[4][4];
    #pragma unroll
    for (int i = 0; i < 4; ++i)
        #pragma unroll
        for (int j = 0; j < 4; ++j)
            acc[i][j] = (f32x4){0.f, 0.f, 0.f, 0.f};

    const unsigned short* gA[2] = {Ah, Al};
    const unsigned short* gB[2] = {Bh, Bl};

    for (int k0 = 0; k0 < K; k0 += 32) {
        #pragma unroll
        for (int c8 = 0; c8 < 8; ++c8) {
            int c = tid + c8 * 256;
            int tile = c >> 9;
            int rr = (c >> 2) & 127;
            int q = c & 3;
            u32x4 v = {0u, 0u, 0u, 0u};
            if (tile < 2) {
                int row = bm + rr;
                if (row < M) v = *(const u32x4*)(gA[tile] + (size_t)row * K + k0 + q * 8);
            } else {
                int row = bn + rr;
                v = *(const u32x4*)(gB[tile - 2] + (size_t)row * K + k0 + q * 8);
            }
            *(u32x4*)(lds + tile * 10240 + rr * 80 + q * 16) = v;
        }
        __syncthreads();
        bf16x8 af[2][4], bfr[2][4];
        #pragma unroll
        for (int p = 0; p < 2; ++p) {
            #pragma unroll
            for (int f = 0; f < 4; ++f) {
                af[p][f]  = *(const bf16x8*)(lds + p * 10240       + (wm * 64 + f * 16 + lr) * 80 + lc * 16);
                bfr[p][f] = *(const bf16x8*)(lds + (2 + p) * 10240 + (wn * 64 + f * 16 + lr) * 80 + lc * 16);
            }
        }
        #pragma unroll
        for (int fi = 0; fi < 4; ++fi) {
            #pragma unroll
            for (int fj = 0; fj < 4; ++fj) {
                acc[fi][fj] = __builtin_amdgcn_mfma_f32_16x16x32_bf16(af[0][fi], bfr[0][fj], acc[fi][fj], 0, 0, 0);
                acc[fi][fj] = __builtin_amdgcn_mfma_f32_16x16x32_bf16(af[0][fi], bfr[1][fj], acc[fi][fj], 0, 0, 0);
                acc[fi][fj] = __builtin_amdgcn_mfma_f32_16x16x32_bf16(af[1][fi], bfr[0][fj], acc[fi][fj], 0, 0, 0);
            }
        }
        __syncthreads();
    }
    #pragma unroll
    for (int fi = 0; fi < 4; ++fi) {
        int rbase = bm + wm * 64 + fi * 16 + lc * 4;
        #pragma unroll
        for (int fj = 0; fj < 4; ++fj) {
            int col = bn + wn * 64 + fj * 16 + lr;
            #pragma unroll
            for (int r = 0; r < 4; ++r) {
                int row = rbase + r;
                if (row < M) C[(size_t)row * HID + col] = acc[fi][fj][r];
            }
        }
    }
}

// ---------------- fused aggregation: 1 node/wave, 8-edge chunks, 2-deep pipeline ----------------
#define DECL_CH(P) int4 P##c0, P##c1, P##c2, P##c3; \
                   float4 P##h0, P##h1, P##h2, P##h3, P##h4, P##h5, P##h6, P##h7;

#define LOAD8(P, idx) do { \
    const int4* _q = (const int4*)(csr + (idx)); \
    P##c0 = _q[0]; P##c1 = _q[1]; P##c2 = _q[2]; P##c3 = _q[3]; \
    P##h0 = ((const float4*)(H + (size_t)P##c0.x * HID))[l]; \
    P##h1 = ((const float4*)(H + (size_t)P##c0.z * HID))[l]; \
    P##h2 = ((const float4*)(H + (size_t)P##c1.x * HID))[l]; \
    P##h3 = ((const float4*)(H + (size_t)P##c1.z * HID))[l]; \
    P##h4 = ((const float4*)(H + (size_t)P##c2.x * HID))[l]; \
    P##h5 = ((const float4*)(H + (size_t)P##c2.z * HID))[l]; \
    P##h6 = ((const float4*)(H + (size_t)P##c3.x * HID))[l]; \
    P##h7 = ((const float4*)(H + (size_t)P##c3.z * HID))[l]; \
} while (0)

#define FMA4(hv, wv, a) do { float _w = (wv); \
    a.x = fmaf(hv.x, _w, a.x); a.y = fmaf(hv.y, _w, a.y); \
    a.z = fmaf(hv.z, _w, a.z); a.w = fmaf(hv.w, _w, a.w); } while (0)

#define CONS8(P, a) do { \
    FMA4(P##h0, __int_as_float(P##c0.y), a); \
    FMA4(P##h1, __int_as_float(P##c0.w), a); \
    FMA4(P##h2, __int_as_float(P##c1.y), a); \
    FMA4(P##h3, __int_as_float(P##c1.w), a); \
    FMA4(P##h4, __int_as_float(P##c2.y), a); \
    FMA4(P##h5, __int_as_float(P##c2.w), a); \
    FMA4(P##h6, __int_as_float(P##c3.y), a); \
    FMA4(P##h7, __int_as_float(P##c3.w), a); \
} while (0)

// MODE 0: +bias, ReLU, LayerNorm, write bf16 hi/lo.  MODE 1: +bias, write f32 rows.
template <int MODE>
__global__ __launch_bounds__(256) void agg_kernel(const float* __restrict__ H,
                                                  const float* __restrict__ dis,
                                                  const int* __restrict__ offs,
                                                  const int2* __restrict__ csr,
                                                  const float* __restrict__ bias,
                                                  const float* __restrict__ gamma,
                                                  const float* __restrict__ beta,
                                                  unsigned short* __restrict__ Zh,
                                                  unsigned short* __restrict__ Zl,
                                                  float* __restrict__ O) {
    int v = blockIdx.x * 4 + (threadIdx.x >> 6);
    int l = threadIdx.x & 63;

    float dv = dis[v];
    float4 a0 = ((const float4*)(H + (size_t)v * HID))[l];
    float sl = dv * dv;
    float4 acc;
    acc.x = a0.x * sl; acc.y = a0.y * sl; acc.z = a0.z * sl; acc.w = a0.w * sl;

    int i = offs[v];
    int n = (offs[v + 1] - i) >> 3;   // padded chunk count
    DECL_CH(A)
    DECL_CH(B)
    if (n > 0) LOAD8(A, i);
    if (n > 1) LOAD8(B, i + 8);
    int c = 0;
    // steady state: consume chunk c, prefetch chunk c+2 into the freed buffer
    while (c + 2 < n) {
        if ((c & 1) == 0) { CONS8(A, acc); LOAD8(A, i + 16); }
        else              { CONS8(B, acc); LOAD8(B, i + 16); }
        i += 8; ++c;
    }
    // tail: at most 2 preloaded chunks remain
    if (c < n) {
        if ((c & 1) == 0) CONS8(A, acc); else CONS8(B, acc);
        ++c;
    }
    if (c < n) {
        if ((c & 1) == 0) CONS8(A, acc); else CONS8(B, acc);
    }

    float4 b4 = ((const float4*)bias)[l];
    if (MODE == 0) {
        acc.x = fmaxf(acc.x + b4.x, 0.f); acc.y = fmaxf(acc.y + b4.y, 0.f);
        acc.z = fmaxf(acc.z + b4.z, 0.f); acc.w = fmaxf(acc.w + b4.w, 0.f);
        float s = acc.x + acc.y + acc.z + acc.w;
        #pragma unroll
        for (int o = 32; o >= 1; o >>= 1) s += __shfl_xor(s, o, 64);
        float mu = s * (1.0f / HID);
        float4 d;
        d.x = acc.x - mu; d.y = acc.y - mu; d.z = acc.z - mu; d.w = acc.w - mu;
        float vs = d.x * d.x + d.y * d.y + d.z * d.z + d.w * d.w;
        #pragma unroll
        for (int o = 32; o >= 1; o >>= 1) vs += __shfl_xor(vs, o, 64);
        float inv = rsqrtf(vs * (1.0f / HID) + LN_EPS);
        float4 g4 = ((const float4*)gamma)[l];
        float4 be4 = ((const float4*)beta)[l];
        float z0 = d.x * inv * g4.x + be4.x;
        float z1 = d.y * inv * g4.y + be4.y;
        float z2 = d.z * inv * g4.z + be4.z;
        float z3 = d.w * inv * g4.w + be4.w;
        ushort4 zh, zl;
        zh.x = f2b(z0); zl.x = f2b(z0 - b2f(zh.x));
        zh.y = f2b(z1); zl.y = f2b(z1 - b2f(zh.y));
        zh.z = f2b(z2); zl.z = f2b(z2 - b2f(zh.z));
        zh.w = f2b(z3); zl.w = f2b(z3 - b2f(zh.w));
        *(ushort4*)(Zh + (size_t)v * HID + l * 4) = zh;
        *(ushort4*)(Zl + (size_t)v * HID + l * 4) = zl;
    } else {
        float4 o0;
        o0.x = acc.x + b4.x; o0.y = acc.y + b4.y;
        o0.z = acc.z + b4.z; o0.w = acc.w + b4.w;
        ((float4*)(O + (size_t)v * HID))[l] = o0;
    }
}

// ---------------- per-graph segment-mean pool (batch is sorted) ----------------
__global__ __launch_bounds__(256) void pool_kernel(const float* __restrict__ O,
                                                   const int* __restrict__ goffs,
                                                   float* __restrict__ out) {
    int g = blockIdx.x, t = threadIdx.x;
    int l = t & 63, w = t >> 6;
    int s = goffs[g], e = goffs[g + 1];
    float4 acc = make_float4(0.f, 0.f, 0.f, 0.f);
    for (int v = s + w; v < e; v += 4) {
        float4 r = ((const float4*)(O + (size_t)v * HID))[l];
        acc.x += r.x; acc.y += r.y; acc.z += r.z; acc.w += r.w;
    }
    __shared__ float4 red[4][64];
    red[w][l] = acc;
    __syncthreads();
    if (w == 0) {
        float4 r0 = red[0][l], r1 = red[1][l], r2 = red[2][l], r3 = red[3][l];
        float inv = 1.0f / (float)(e - s);
        float4 o;
        o.x = (r0.x + r1.x + r2.x + r3.x) * inv;
        o.y = (r0.y + r1.y + r2.y + r3.y) * inv;
        o.z = (r0.z + r1.z + r2.z + r3.z) * inv;
        o.w = (r0.w + r1.w + r2.w + r3.w) * inv;
        ((float4*)(out + (size_t)g * HID))[l] = o;
    }
}

// ---------------- launch ----------------
extern "C" void kernel_launch(void* const* d_in, const int* in_sizes, int n_in,
                              void* d_out, int out_size, void* d_ws, size_t ws_size,
                              hipStream_t stream) {
    const float* x   = (const float*)d_in[0];
    const float* W1  = (const float*)d_in[1];
    const float* b1  = (const float*)d_in[2];
    const float* g1  = (const float*)d_in[3];
    const float* be1 = (const float*)d_in[4];
    const float* W2  = (const float*)d_in[5];
    const float* b2  = (const float*)d_in[6];
    const float* g2  = (const float*)d_in[7];
    const float* be2 = (const float*)d_in[8];
    const float* W3  = (const float*)d_in[9];
    const float* b3  = (const float*)d_in[10];
    const void*  ei  = d_in[11];
    const void*  bt  = d_in[12];
    float* out = (float*)d_out;

    unsigned int* ws = (unsigned int*)d_ws;
    int*   deg    = (int*)(ws + W_DEG);
    int*   cursor = (int*)(ws + W_CURSOR);
    int*   cnt    = (int*)(ws + W_CNT);
    int*   flag   = (int*)(ws + W_FLAG);
    int*   bsum   = (int*)(ws + W_BSUM);
    int*   bpre   = (int*)(ws + W_BPRE);
    int*   goffs  = (int*)(ws + W_GOFF);
    int*   offs   = (int*)(ws + W_OFFS);
    float* dis    = (float*)(ws + W_DIS);
    int2*  csr    = (int2*)(ws + W_CSR);
    unsigned short* wt = (unsigned short*)(ws + W_WT);
    unsigned short* Zh = (unsigned short*)(ws + W_ZH);
    unsigned short* Zl = (unsigned short*)(ws + W_ZL);
    unsigned short* xh = Zh;            // overlay: x-split dead after gemm1
    unsigned short* xl = Zl;
    float* Hbuf = (float*)(ws + W_H);
    float* Obuf = (float*)(ws + W_ZH);  // overlay: Zh/Zl dead after gemm3

    const int EB = (N_EDGES + 255) / 256;
    const int CE = (N_EDGES + N_NODES + 255) / 256;
    const int NB = (N_NODES + 255) / 256;  // 196

    zero_kernel<<<(ZERO_WORDS + 255) / 256, 256, 0, stream>>>(ws, ZERO_WORDS);
    zero_kernel<<<(2 * PAD_E + 255) / 256, 256, 0, stream>>>(ws + W_CSR, 2 * PAD_E);
    detect_kernel<<<EB, 256, 0, stream>>>((const unsigned int*)ei, flag);
    degcnt_kernel<<<CE, 256, 0, stream>>>(ei, bt, flag, deg, cnt);
    blocksum_kernel<<<NB, 256, 0, stream>>>(deg, bsum);
    scan_small<<<1, 256, 0, stream>>>(bsum, bpre, cnt, goffs);
    finalize_kernel<<<NB, 256, 0, stream>>>(deg, bpre, offs, dis);
    scatter_kernel<<<EB, 256, 0, stream>>>(ei, flag, offs, cursor, dis, csr);
    prep_w<<<XSPLIT_BLOCKS + 640, 256, 0, stream>>>(x, W1, W2, W3, xh, xl, wt);

    dim3 gg((N_NODES + 127) / 128, HID / 128);
    const int AB = N_NODES / 4;  // 12500 blocks = 50000 waves = 1 node/wave

    gemm_bf16x2<<<gg, 256, 0, stream>>>(xh, xl, wt + WT1H, wt + WT1L, Hbuf, N_NODES, IN_DIM);
    agg_kernel<0><<<AB, 256, 0, stream>>>(Hbuf, dis, offs, csr, b1, g1, be1, Zh, Zl, nullptr);
    gemm_bf16x2<<<gg, 256, 0, stream>>>(Zh, Zl, wt + WT2H, wt + WT2L, Hbuf, N_NODES, HID);
    agg_kernel<0><<<AB, 256, 0, stream>>>(Hbuf, dis, offs, csr, b2, g2, be2, Zh, Zl, nullptr);
    gemm_bf16x2<<<gg, 256, 0, stream>>>(Zh, Zl, wt + WT3H, wt + WT3L, Hbuf, N_NODES, HID);
    agg_kernel<1><<<AB, 256, 0, stream>>>(Hbuf, dis, offs, csr, b3, nullptr, nullptr, nullptr, nullptr, Obuf);
    pool_kernel<<<NGRAPH, 256, 0, stream>>>(Obuf, goffs, out);
}

// Round 5
// 554.691 us; speedup vs baseline: 1.9326x; 1.2146x over previous
//
#include <hip/hip_runtime.h>

#define N_NODES 50000
#define N_EDGES 800000
#define IN_DIM  128
#define HID     256
#define NGRAPH  256
#define LN_EPS  1e-5f

typedef __attribute__((ext_vector_type(8))) short bf16x8;
typedef __attribute__((ext_vector_type(4))) float f32x4;
typedef __attribute__((ext_vector_type(4))) unsigned int u32x4;

// padded CSR capacity (pad each node's edge list to a multiple of 8; max +7/node)
#define PAD_E (N_EDGES + 7 * N_NODES)

// ---------------- workspace layout (32-bit word offsets) ----------------
#define W_DEG      0
#define W_CURSOR   (W_DEG + N_NODES)
#define W_CNT      (W_CURSOR + N_NODES)
#define W_FLAG     (W_CNT + NGRAPH)
#define ZERO_WORDS (W_FLAG + 16)
#define W_BSUM     ZERO_WORDS
#define W_BPRE     (W_BSUM + 256)
#define W_GOFF     (W_BPRE + 256)
#define W_OFFS     (W_GOFF + NGRAPH + 8)
#define W_DIS      (W_OFFS + N_NODES + 8)
#define W_CSR      (((W_DIS + N_NODES) + 3) & ~3)
#define W_WT       (W_CSR + 2 * PAD_E)
#define W_ZH       (((W_WT + 163840) + 3) & ~3)
#define W_ZL       (W_ZH + (N_NODES * HID / 2))
#define W_H        (W_ZL + (N_NODES * HID / 2))   // bf16 H: 50000*256 ushort

// Wt sub-offsets in ushorts within W_WT
#define WT1H 0
#define WT1L 32768
#define WT2H 65536
#define WT2L 131072
#define WT3H 196608
#define WT3L 262144

__device__ __forceinline__ unsigned short f2b(float f) {
    unsigned int u = __float_as_uint(f);
    unsigned int r = (u + 0x7FFFu + ((u >> 16) & 1u)) >> 16;
    return (unsigned short)r;
}
__device__ __forceinline__ float b2f(unsigned short h) {
    return __uint_as_float(((unsigned int)h) << 16);
}

// ---------------- prep kernels ----------------
__global__ __launch_bounds__(256) void zero_kernel(unsigned int* __restrict__ p, int n) {
    int i = blockIdx.x * 256 + threadIdx.x;
    if (i < n) p[i] = 0u;
}

__global__ __launch_bounds__(256) void detect_kernel(const unsigned int* __restrict__ ei,
                                                     int* __restrict__ flag) {
    int e = blockIdx.x * 256 + threadIdx.x;
    if (e >= N_EDGES) return;
    if (ei[2 * e + 1] != 0u) *flag = 1;
}

__global__ __launch_bounds__(256) void degcnt_kernel(const void* __restrict__ ei,
                                                     const void* __restrict__ bt,
                                                     const int* __restrict__ flag,
                                                     int* __restrict__ deg,
                                                     int* __restrict__ cnt) {
    int idx = blockIdx.x * 256 + threadIdx.x;
    bool is32 = (*flag != 0);
    if (idx < N_EDGES) {
        int d = is32 ? ((const int*)ei)[N_EDGES + idx]
                     : (int)((const long long*)ei)[N_EDGES + idx];
        atomicAdd(&deg[d], 1);
    } else {
        int v = idx - N_EDGES;
        if (v < N_NODES) {
            int b = is32 ? ((const int*)bt)[v] : (int)((const long long*)bt)[v];
            atomicAdd(&cnt[b], 1);
        }
    }
}

// per-block sums of padded degrees
__global__ __launch_bounds__(256) void blocksum_kernel(const int* __restrict__ deg,
                                                       int* __restrict__ bsum) {
    int b = blockIdx.x, t = threadIdx.x;
    int i = b * 256 + t;
    int pd = (i < N_NODES) ? ((deg[i] + 7) & ~7) : 0;
    int lane = t & 63, w = t >> 6;
    int s = pd;
    #pragma unroll
    for (int o = 32; o >= 1; o >>= 1) s += __shfl_xor(s, o, 64);
    __shared__ int ws[4];
    if (lane == 0) ws[w] = s;
    __syncthreads();
    if (t == 0) bsum[b] = ws[0] + ws[1] + ws[2] + ws[3];
}

// single tiny block: exclusive scan bsum(196) -> bpre; exclusive scan cnt(256) -> goffs
__global__ __launch_bounds__(256) void scan_small(const int* __restrict__ bsum,
                                                  int* __restrict__ bpre,
                                                  const int* __restrict__ cnt,
                                                  int* __restrict__ goffs) {
    int t = threadIdx.x;
    int lane = t & 63, w = t >> 6;
    {
        int x = (t < 196) ? bsum[t] : 0;
        int inc = x;
        #pragma unroll
        for (int o = 1; o < 64; o <<= 1) {
            int u = __shfl_up(inc, o, 64);
            if (lane >= o) inc += u;
        }
        __shared__ int wsA[4];
        if (lane == 63) wsA[w] = inc;
        __syncthreads();
        int base = 0;
        for (int k = 0; k < w; ++k) base += wsA[k];
        bpre[t] = base + inc - x;
        __syncthreads();
    }
    {
        int y = cnt[t];
        int inc = y;
        #pragma unroll
        for (int o = 1; o < 64; o <<= 1) {
            int u = __shfl_up(inc, o, 64);
            if (lane >= o) inc += u;
        }
        __shared__ int wsB[4];
        if (lane == 63) wsB[w] = inc;
        __syncthreads();
        int base = 0;
        for (int k = 0; k < w; ++k) base += wsB[k];
        goffs[t] = base + inc - y;
        if (t == 255) goffs[256] = base + inc;
    }
}

// per-node padded offsets + dis
__global__ __launch_bounds__(256) void finalize_kernel(const int* __restrict__ deg,
                                                       const int* __restrict__ bpre,
                                                       int* __restrict__ offs,
                                                       float* __restrict__ dis) {
    int b = blockIdx.x, t = threadIdx.x;
    int i = b * 256 + t;
    int d = (i < N_NODES) ? deg[i] : 0;
    int pd = (d + 7) & ~7;
    int lane = t & 63, w = t >> 6;
    int inc = pd;
    #pragma unroll
    for (int o = 1; o < 64; o <<= 1) {
        int u = __shfl_up(inc, o, 64);
        if (lane >= o) inc += u;
    }
    __shared__ int ws[4];
    if (lane == 63) ws[w] = inc;
    __syncthreads();
    int base = 0;
    for (int k = 0; k < w; ++k) base += ws[k];
    int pre = base + inc - pd;
    if (i < N_NODES) {
        offs[i] = bpre[b] + pre;
        dis[i] = rsqrtf((float)d + 1.0f);
    }
    if (i == N_NODES - 1) offs[N_NODES] = bpre[b] + pre + pd;
}

__global__ __launch_bounds__(256) void scatter_kernel(const void* __restrict__ ei,
                                                      const int* __restrict__ flag,
                                                      const int* __restrict__ offs,
                                                      int* __restrict__ cursor,
                                                      const float* __restrict__ dis,
                                                      int2* __restrict__ csr) {
    int e = blockIdx.x * 256 + threadIdx.x;
    if (e >= N_EDGES) return;
    bool is32 = (*flag != 0);
    int s, d;
    if (is32) {
        const int* p = (const int*)ei;
        s = p[e]; d = p[N_EDGES + e];
    } else {
        const long long* p = (const long long*)ei;
        s = (int)p[e]; d = (int)p[N_EDGES + e];
    }
    int pos = atomicAdd(&cursor[d], 1);
    int idx = offs[d] + pos;
    int2 rec;
    rec.x = s;
    rec.y = __float_as_int(dis[s] * dis[d]);
    csr[idx] = rec;
}

// split x into bf16 hi/lo + transpose/split W1,W2,W3 into [N][K] bf16 pairs
#define XSPLIT_BLOCKS 6250
__global__ __launch_bounds__(256) void prep_w(const float* __restrict__ x,
                                              const float* __restrict__ W1,
                                              const float* __restrict__ W2,
                                              const float* __restrict__ W3,
                                              unsigned short* __restrict__ xh,
                                              unsigned short* __restrict__ xl,
                                              unsigned short* __restrict__ wt) {
    int b = blockIdx.x;
    int t = threadIdx.x;
    if (b < XSPLIT_BLOCKS) {
        int i = b * 256 + t;
        float4 v = ((const float4*)x)[i];
        ushort4 h, lo;
        h.x = f2b(v.x); lo.x = f2b(v.x - b2f(h.x));
        h.y = f2b(v.y); lo.y = f2b(v.y - b2f(h.y));
        h.z = f2b(v.z); lo.z = f2b(v.z - b2f(h.z));
        h.w = f2b(v.w); lo.w = f2b(v.w - b2f(h.w));
        ((ushort4*)xh)[i] = h;
        ((ushort4*)xl)[i] = lo;
    } else {
        int wb = b - XSPLIT_BLOCKS;
        const float* W; int K, k, bh, bl;
        if (wb < 128)      { W = W1; K = 128; k = wb;       bh = WT1H; bl = WT1L; }
        else if (wb < 384) { W = W2; K = 256; k = wb - 128; bh = WT2H; bl = WT2L; }
        else               { W = W3; K = 256; k = wb - 384; bh = WT3H; bl = WT3L; }
        int n = t;
        float val = W[k * HID + n];
        unsigned short hv = f2b(val);
        unsigned short lv = f2b(val - b2f(hv));
        wt[bh + n * K + k] = hv;
        wt[bl + n * K + k] = lv;
    }
}

// ---------------- bf16x2-split MFMA GEMM; C written as bf16 ----------------
__global__ __launch_bounds__(256) void gemm_bf16x2(const unsigned short* __restrict__ Ah,
                                                   const unsigned short* __restrict__ Al,
                                                   const unsigned short* __restrict__ Bh,
                                                   const unsigned short* __restrict__ Bl,
                                                   unsigned short* __restrict__ C,
                                                   int M, int K) {
    __shared__ char lds[4 * 128 * 80];
    int tid = threadIdx.x;
    int bm = blockIdx.x * 128;
    int bn = blockIdx.y * 128;
    int lane = tid & 63, wid = tid >> 6;
    int wm = wid >> 1, wn = wid & 1;
    int lr = lane & 15, lc = lane >> 4;
    f32x4 acc[4][4];
    #pragma unroll
    for (int i = 0; i < 4; ++i)
        #pragma unroll
        for (int j = 0; j < 4; ++j)
            acc[i][j] = (f32x4){0.f, 0.f, 0.f, 0.f};

    const unsigned short* gA[2] = {Ah, Al};
    const unsigned short* gB[2] = {Bh, Bl};

    for (int k0 = 0; k0 < K; k0 += 32) {
        #pragma unroll
        for (int c8 = 0; c8 < 8; ++c8) {
            int c = tid + c8 * 256;
            int tile = c >> 9;
            int rr = (c >> 2) & 127;
            int q = c & 3;
            u32x4 v = {0u, 0u, 0u, 0u};
            if (tile < 2) {
                int row = bm + rr;
                if (row < M) v = *(const u32x4*)(gA[tile] + (size_t)row * K + k0 + q * 8);
            } else {
                int row = bn + rr;
                v = *(const u32x4*)(gB[tile - 2] + (size_t)row * K + k0 + q * 8);
            }
            *(u32x4*)(lds + tile * 10240 + rr * 80 + q * 16) = v;
        }
        __syncthreads();
        bf16x8 af[2][4], bfr[2][4];
        #pragma unroll
        for (int p = 0; p < 2; ++p) {
            #pragma unroll
            for (int f = 0; f < 4; ++f) {
                af[p][f]  = *(const bf16x8*)(lds + p * 10240       + (wm * 64 + f * 16 + lr) * 80 + lc * 16);
                bfr[p][f] = *(const bf16x8*)(lds + (2 + p) * 10240 + (wn * 64 + f * 16 + lr) * 80 + lc * 16);
            }
        }
        #pragma unroll
        for (int fi = 0; fi < 4; ++fi) {
            #pragma unroll
            for (int fj = 0; fj < 4; ++fj) {
                acc[fi][fj] = __builtin_amdgcn_mfma_f32_16x16x32_bf16(af[0][fi], bfr[0][fj], acc[fi][fj], 0, 0, 0);
                acc[fi][fj] = __builtin_amdgcn_mfma_f32_16x16x32_bf16(af[0][fi], bfr[1][fj], acc[fi][fj], 0, 0, 0);
                acc[fi][fj] = __builtin_amdgcn_mfma_f32_16x16x32_bf16(af[1][fi], bfr[0][fj], acc[fi][fj], 0, 0, 0);
            }
        }
        __syncthreads();
    }
    #pragma unroll
    for (int fi = 0; fi < 4; ++fi) {
        int rbase = bm + wm * 64 + fi * 16 + lc * 4;
        #pragma unroll
        for (int fj = 0; fj < 4; ++fj) {
            int col = bn + wn * 64 + fj * 16 + lr;
            #pragma unroll
            for (int r = 0; r < 4; ++r) {
                int row = rbase + r;
                if (row < M) C[(size_t)row * HID + col] = f2b(acc[fi][fj][r]);
            }
        }
    }
}

// ---------------- fused aggregation: bf16 H gather, 1 node/wave, 8-edge chunks, 2-deep pipeline ----
#define DECL_CH(P) int4 P##c0, P##c1, P##c2, P##c3; \
                   ushort4 P##h0, P##h1, P##h2, P##h3, P##h4, P##h5, P##h6, P##h7;

#define LOAD8(P, idx) do { \
    const int4* _q = (const int4*)(csr + (idx)); \
    P##c0 = _q[0]; P##c1 = _q[1]; P##c2 = _q[2]; P##c3 = _q[3]; \
    P##h0 = ((const ushort4*)(H + (size_t)P##c0.x * HID))[l]; \
    P##h1 = ((const ushort4*)(H + (size_t)P##c0.z * HID))[l]; \
    P##h2 = ((const ushort4*)(H + (size_t)P##c1.x * HID))[l]; \
    P##h3 = ((const ushort4*)(H + (size_t)P##c1.z * HID))[l]; \
    P##h4 = ((const ushort4*)(H + (size_t)P##c2.x * HID))[l]; \
    P##h5 = ((const ushort4*)(H + (size_t)P##c2.z * HID))[l]; \
    P##h6 = ((const ushort4*)(H + (size_t)P##c3.x * HID))[l]; \
    P##h7 = ((const ushort4*)(H + (size_t)P##c3.z * HID))[l]; \
} while (0)

#define FMA4U(hv, wv, a) do { float _w = (wv); \
    a.x = fmaf(b2f(hv.x), _w, a.x); a.y = fmaf(b2f(hv.y), _w, a.y); \
    a.z = fmaf(b2f(hv.z), _w, a.z); a.w = fmaf(b2f(hv.w), _w, a.w); } while (0)

#define CONS8(P, a) do { \
    FMA4U(P##h0, __int_as_float(P##c0.y), a); \
    FMA4U(P##h1, __int_as_float(P##c0.w), a); \
    FMA4U(P##h2, __int_as_float(P##c1.y), a); \
    FMA4U(P##h3, __int_as_float(P##c1.w), a); \
    FMA4U(P##h4, __int_as_float(P##c2.y), a); \
    FMA4U(P##h5, __int_as_float(P##c2.w), a); \
    FMA4U(P##h6, __int_as_float(P##c3.y), a); \
    FMA4U(P##h7, __int_as_float(P##c3.w), a); \
} while (0)

// MODE 0: +bias, ReLU, LayerNorm, write bf16 hi/lo.  MODE 1: +bias, write f32 rows.
template <int MODE>
__global__ __launch_bounds__(256) void agg_kernel(const unsigned short* __restrict__ H,
                                                  const float* __restrict__ dis,
                                                  const int* __restrict__ offs,
                                                  const int2* __restrict__ csr,
                                                  const float* __restrict__ bias,
                                                  const float* __restrict__ gamma,
                                                  const float* __restrict__ beta,
                                                  unsigned short* __restrict__ Zh,
                                                  unsigned short* __restrict__ Zl,
                                                  float* __restrict__ O) {
    int v = blockIdx.x * 4 + (threadIdx.x >> 6);
    int l = threadIdx.x & 63;

    float dv = dis[v];
    ushort4 a0u = ((const ushort4*)(H + (size_t)v * HID))[l];
    float sl = dv * dv;
    float4 acc;
    acc.x = b2f(a0u.x) * sl; acc.y = b2f(a0u.y) * sl;
    acc.z = b2f(a0u.z) * sl; acc.w = b2f(a0u.w) * sl;

    int i = offs[v];
    int n = (offs[v + 1] - i) >> 3;   // padded chunk count
    DECL_CH(A)
    DECL_CH(B)
    if (n > 0) LOAD8(A, i);
    if (n > 1) LOAD8(B, i + 8);
    int c = 0;
    // steady state: consume chunk c, prefetch chunk c+2 into the freed register set
    while (c + 2 < n) {
        if ((c & 1) == 0) { CONS8(A, acc); LOAD8(A, i + 16); }
        else              { CONS8(B, acc); LOAD8(B, i + 16); }
        i += 8; ++c;
    }
    if (c < n) {
        if ((c & 1) == 0) CONS8(A, acc); else CONS8(B, acc);
        ++c;
    }
    if (c < n) {
        if ((c & 1) == 0) CONS8(A, acc); else CONS8(B, acc);
    }

    float4 b4 = ((const float4*)bias)[l];
    if (MODE == 0) {
        acc.x = fmaxf(acc.x + b4.x, 0.f); acc.y = fmaxf(acc.y + b4.y, 0.f);
        acc.z = fmaxf(acc.z + b4.z, 0.f); acc.w = fmaxf(acc.w + b4.w, 0.f);
        float s = acc.x + acc.y + acc.z + acc.w;
        #pragma unroll
        for (int o = 32; o >= 1; o >>= 1) s += __shfl_xor(s, o, 64);
        float mu = s * (1.0f / HID);
        float4 d;
        d.x = acc.x - mu; d.y = acc.y - mu; d.z = acc.z - mu; d.w = acc.w - mu;
        float vs = d.x * d.x + d.y * d.y + d.z * d.z + d.w * d.w;
        #pragma unroll
        for (int o = 32; o >= 1; o >>= 1) vs += __shfl_xor(vs, o, 64);
        float inv = rsqrtf(vs * (1.0f / HID) + LN_EPS);
        float4 g4 = ((const float4*)gamma)[l];
        float4 be4 = ((const float4*)beta)[l];
        float z0 = d.x * inv * g4.x + be4.x;
        float z1 = d.y * inv * g4.y + be4.y;
        float z2 = d.z * inv * g4.z + be4.z;
        float z3 = d.w * inv * g4.w + be4.w;
        ushort4 zh, zl;
        zh.x = f2b(z0); zl.x = f2b(z0 - b2f(zh.x));
        zh.y = f2b(z1); zl.y = f2b(z1 - b2f(zh.y));
        zh.z = f2b(z2); zl.z = f2b(z2 - b2f(zh.z));
        zh.w = f2b(z3); zl.w = f2b(z3 - b2f(zh.w));
        *(ushort4*)(Zh + (size_t)v * HID + l * 4) = zh;
        *(ushort4*)(Zl + (size_t)v * HID + l * 4) = zl;
    } else {
        float4 o0;
        o0.x = acc.x + b4.x; o0.y = acc.y + b4.y;
        o0.z = acc.z + b4.z; o0.w = acc.w + b4.w;
        ((float4*)(O + (size_t)v * HID))[l] = o0;
    }
}

// ---------------- per-graph segment-mean pool (batch is sorted) ----------------
__global__ __launch_bounds__(256) void pool_kernel(const float* __restrict__ O,
                                                   const int* __restrict__ goffs,
                                                   float* __restrict__ out) {
    int g = blockIdx.x, t = threadIdx.x;
    int l = t & 63, w = t >> 6;
    int s = goffs[g], e = goffs[g + 1];
    float4 acc = make_float4(0.f, 0.f, 0.f, 0.f);
    for (int v = s + w; v < e; v += 4) {
        float4 r = ((const float4*)(O + (size_t)v * HID))[l];
        acc.x += r.x; acc.y += r.y; acc.z += r.z; acc.w += r.w;
    }
    __shared__ float4 red[4][64];
    red[w][l] = acc;
    __syncthreads();
    if (w == 0) {
        float4 r0 = red[0][l], r1 = red[1][l], r2 = red[2][l], r3 = red[3][l];
        float inv = 1.0f / (float)(e - s);
        float4 o;
        o.x = (r0.x + r1.x + r2.x + r3.x) * inv;
        o.y = (r0.y + r1.y + r2.y + r3.y) * inv;
        o.z = (r0.z + r1.z + r2.z + r3.z) * inv;
        o.w = (r0.w + r1.w + r2.w + r3.w) * inv;
        ((float4*)(out + (size_t)g * HID))[l] = o;
    }
}

// ---------------- launch ----------------
extern "C" void kernel_launch(void* const* d_in, const int* in_sizes, int n_in,
                              void* d_out, int out_size, void* d_ws, size_t ws_size,
                              hipStream_t stream) {
    const float* x   = (const float*)d_in[0];
    const float* W1  = (const float*)d_in[1];
    const float* b1  = (const float*)d_in[2];
    const float* g1  = (const float*)d_in[3];
    const float* be1 = (const float*)d_in[4];
    const float* W2  = (const float*)d_in[5];
    const float* b2  = (const float*)d_in[6];
    const float* g2  = (const float*)d_in[7];
    const float* be2 = (const float*)d_in[8];
    const float* W3  = (const float*)d_in[9];
    const float* b3  = (const float*)d_in[10];
    const void*  ei  = d_in[11];
    const void*  bt  = d_in[12];
    float* out = (float*)d_out;

    unsigned int* ws = (unsigned int*)d_ws;
    int*   deg    = (int*)(ws + W_DEG);
    int*   cursor = (int*)(ws + W_CURSOR);
    int*   cnt    = (int*)(ws + W_CNT);
    int*   flag   = (int*)(ws + W_FLAG);
    int*   bsum   = (int*)(ws + W_BSUM);
    int*   bpre   = (int*)(ws + W_BPRE);
    int*   goffs  = (int*)(ws + W_GOFF);
    int*   offs   = (int*)(ws + W_OFFS);
    float* dis    = (float*)(ws + W_DIS);
    int2*  csr    = (int2*)(ws + W_CSR);
    unsigned short* wt = (unsigned short*)(ws + W_WT);
    unsigned short* Zh = (unsigned short*)(ws + W_ZH);
    unsigned short* Zl = (unsigned short*)(ws + W_ZL);
    unsigned short* xh = Zh;            // overlay: x-split dead after gemm1
    unsigned short* xl = Zl;
    unsigned short* Hbuf = (unsigned short*)(ws + W_H);   // bf16 H
    float* Obuf = (float*)(ws + W_ZH);  // overlay: Zh/Zl dead after gemm3

    const int EB = (N_EDGES + 255) / 256;
    const int CE = (N_EDGES + N_NODES + 255) / 256;
    const int NB = (N_NODES + 255) / 256;  // 196

    zero_kernel<<<(ZERO_WORDS + 255) / 256, 256, 0, stream>>>(ws, ZERO_WORDS);
    zero_kernel<<<(2 * PAD_E + 255) / 256, 256, 0, stream>>>(ws + W_CSR, 2 * PAD_E);
    detect_kernel<<<EB, 256, 0, stream>>>((const unsigned int*)ei, flag);
    degcnt_kernel<<<CE, 256, 0, stream>>>(ei, bt, flag, deg, cnt);
    blocksum_kernel<<<NB, 256, 0, stream>>>(deg, bsum);
    scan_small<<<1, 256, 0, stream>>>(bsum, bpre, cnt, goffs);
    finalize_kernel<<<NB, 256, 0, stream>>>(deg, bpre, offs, dis);
    scatter_kernel<<<EB, 256, 0, stream>>>(ei, flag, offs, cursor, dis, csr);
    prep_w<<<XSPLIT_BLOCKS + 640, 256, 0, stream>>>(x, W1, W2, W3, xh, xl, wt);

    dim3 gg((N_NODES + 127) / 128, HID / 128);
    const int AB = N_NODES / 4;  // 12500 blocks = 50000 waves = 1 node/wave

    gemm_bf16x2<<<gg, 256, 0, stream>>>(xh, xl, wt + WT1H, wt + WT1L, Hbuf, N_NODES, IN_DIM);
    agg_kernel<0><<<AB, 256, 0, stream>>>(Hbuf, dis, offs, csr, b1, g1, be1, Zh, Zl, nullptr);
    gemm_bf16x2<<<gg, 256, 0, stream>>>(Zh, Zl, wt + WT2H, wt + WT2L, Hbuf, N_NODES, HID);
    agg_kernel<0><<<AB, 256, 0, stream>>>(Hbuf, dis, offs, csr, b2, g2, be2, Zh, Zl, nullptr);
    gemm_bf16x2<<<gg, 256, 0, stream>>>(Zh, Zl, wt + WT3H, wt + WT3L, Hbuf, N_NODES, HID);
    agg_kernel<1><<<AB, 256, 0, stream>>>(Hbuf, dis, offs, csr, b3, nullptr, nullptr, nullptr, nullptr, Obuf);
    pool_kernel<<<NGRAPH, 256, 0, stream>>>(Obuf, goffs, out);
}

// Round 6
// 494.840 us; speedup vs baseline: 2.1664x; 1.1210x over previous
//
#include <hip/hip_runtime.h>

#define N_NODES 50000
#define N_EDGES 800000
#define IN_DIM  128
#define HID     256
#define NGRAPH  256
#define LN_EPS  1e-5f

typedef __attribute__((ext_vector_type(8))) short bf16x8;
typedef __attribute__((ext_vector_type(4))) float f32x4;
typedef __attribute__((ext_vector_type(4))) unsigned int u32x4;

// counting-sort geometry: 256 chunks x 3125 edges; bins split in 2 halves of 25000
#define NCHUNK  256
#define CHUNK   3125
#define HWORDS  12500   // packed u32 words per half (2 bins/word)

// padded CSR capacity (pad each node's edge list to a multiple of 8; max +7/node)
#define PAD_E (N_EDGES + 7 * N_NODES)

// ---------------- workspace layout (32-bit word offsets) ----------------
#define W_DEG      0
#define W_FLAG     (W_DEG + N_NODES)
#define W_BSUM     (W_FLAG + 16)
#define W_BPRE     (W_BSUM + 256)
#define W_GOFF     (W_BPRE + 256)
#define W_OFFS     (W_GOFF + NGRAPH + 8)
#define W_DIS      (W_OFFS + N_NODES + 8)
#define W_CSR      (((W_DIS + N_NODES) + 3) & ~3)
#define W_WT       (W_CSR + 2 * PAD_E)
#define W_ZH       (((W_WT + 163840) + 3) & ~3)
#define W_ZL       (W_ZH + (N_NODES * HID / 2))
#define W_H        (W_ZL + (N_NODES * HID / 2))   // bf16 H (overlaid by sort partials pre-gemm1)

// Wt sub-offsets in ushorts within W_WT
#define WT1H 0
#define WT1L 32768
#define WT2H 65536
#define WT2L 131072
#define WT3H 196608
#define WT3L 262144

__device__ __forceinline__ unsigned short f2b(float f) {
    unsigned int u = __float_as_uint(f);
    unsigned int r = (u + 0x7FFFu + ((u >> 16) & 1u)) >> 16;
    return (unsigned short)r;
}
__device__ __forceinline__ float b2f(unsigned short h) {
    return __uint_as_float(((unsigned int)h) << 16);
}

// ---------------- prep kernels ----------------
__global__ __launch_bounds__(256) void zero_kernel(unsigned int* __restrict__ p, int n) {
    int i = blockIdx.x * 256 + threadIdx.x;
    if (i < n) p[i] = 0u;
}

__global__ __launch_bounds__(256) void detect_kernel(const unsigned int* __restrict__ ei,
                                                     int* __restrict__ flag) {
    int e = blockIdx.x * 256 + threadIdx.x;
    if (e >= N_EDGES) return;
    if (ei[2 * e + 1] != 0u) *flag = 1;
}

// pass 1: per-(chunk,half) LDS histogram, packed 2x16-bit counts per word
__global__ __launch_bounds__(256) void hist_kernel(const void* __restrict__ ei,
                                                   const int* __restrict__ flag,
                                                   unsigned int* __restrict__ partial) {
    __shared__ unsigned int h[HWORDS];
    int c = blockIdx.x >> 1, hf = blockIdx.x & 1;
    int t = threadIdx.x;
    for (int i = t; i < HWORDS; i += 256) h[i] = 0u;
    __syncthreads();
    bool is32 = (*flag != 0);
    int e0 = c * CHUNK;
    for (int k = 0; k < 13; ++k) {
        int e = e0 + t + k * 256;
        if (e < e0 + CHUNK) {
            int d = is32 ? ((const int*)ei)[N_EDGES + e]
                         : (int)((const long long*)ei)[N_EDGES + e];
            if (((d >= 25000) ? 1 : 0) == hf) {
                int w = (d - hf * 25000) >> 1;
                atomicAdd(&h[w], (d & 1) ? 0x10000u : 1u);
            }
        }
    }
    __syncthreads();
    unsigned int* dst = partial + (size_t)blockIdx.x * HWORDS;
    for (int i = t; i < HWORDS; i += 256) dst[i] = h[i];
}

// pass 2: per bin-pair, exclusive prefix across chunks (in place) + total degree
__global__ __launch_bounds__(256) void merge_kernel(unsigned int* __restrict__ partial,
                                                    int* __restrict__ deg) {
    int w = blockIdx.x * 256 + threadIdx.x;
    if (w >= 25000) return;
    int hf = (w >= HWORDS) ? 1 : 0;
    int wi = w - hf * HWORDS;
    unsigned int run_lo = 0, run_hi = 0;
    for (int c = 0; c < NCHUNK; ++c) {
        size_t idx = ((size_t)(c * 2 + hf)) * HWORDS + wi;
        unsigned int u = partial[idx];
        partial[idx] = run_lo | (run_hi << 16);
        run_lo += u & 0xffffu;
        run_hi += u >> 16;
    }
    deg[2 * w]     = (int)run_lo;
    deg[2 * w + 1] = (int)run_hi;
}

// per-block sums of padded degrees
__global__ __launch_bounds__(256) void blocksum_kernel(const int* __restrict__ deg,
                                                       int* __restrict__ bsum) {
    int b = blockIdx.x, t = threadIdx.x;
    int i = b * 256 + t;
    int pd = (i < N_NODES) ? ((deg[i] + 7) & ~7) : 0;
    int lane = t & 63, w = t >> 6;
    int s = pd;
    #pragma unroll
    for (int o = 32; o >= 1; o >>= 1) s += __shfl_xor(s, o, 64);
    __shared__ int ws[4];
    if (lane == 0) ws[w] = s;
    __syncthreads();
    if (t == 0) bsum[b] = ws[0] + ws[1] + ws[2] + ws[3];
}

// single tiny block: exclusive scan bsum(196) -> bpre
__global__ __launch_bounds__(256) void scanb_kernel(const int* __restrict__ bsum,
                                                    int* __restrict__ bpre) {
    int t = threadIdx.x;
    int lane = t & 63, w = t >> 6;
    int x = (t < 196) ? bsum[t] : 0;
    int inc = x;
    #pragma unroll
    for (int o = 1; o < 64; o <<= 1) {
        int u = __shfl_up(inc, o, 64);
        if (lane >= o) inc += u;
    }
    __shared__ int wsA[4];
    if (lane == 63) wsA[w] = inc;
    __syncthreads();
    int base = 0;
    for (int k = 0; k < w; ++k) base += wsA[k];
    bpre[t] = base + inc - x;
}

// per-node padded offsets + dis
__global__ __launch_bounds__(256) void finalize_kernel(const int* __restrict__ deg,
                                                       const int* __restrict__ bpre,
                                                       int* __restrict__ offs,
                                                       float* __restrict__ dis) {
    int b = blockIdx.x, t = threadIdx.x;
    int i = b * 256 + t;
    int d = (i < N_NODES) ? deg[i] : 0;
    int pd = (d + 7) & ~7;
    int lane = t & 63, w = t >> 6;
    int inc = pd;
    #pragma unroll
    for (int o = 1; o < 64; o <<= 1) {
        int u = __shfl_up(inc, o, 64);
        if (lane >= o) inc += u;
    }
    __shared__ int ws[4];
    if (lane == 63) ws[w] = inc;
    __syncthreads();
    int base = 0;
    for (int k = 0; k < w; ++k) base += ws[k];
    int pre = base + inc - pd;
    if (i < N_NODES) {
        offs[i] = bpre[b] + pre;
        dis[i] = rsqrtf((float)d + 1.0f);
    }
    if (i == N_NODES - 1) offs[N_NODES] = bpre[b] + pre + pd;
}

// pass 3: counting-sort scatter (no global atomics): slot = offs[d] + rel[c][d] + local rank
__global__ __launch_bounds__(256) void scatter2_kernel(const void* __restrict__ ei,
                                                       const int* __restrict__ flag,
                                                       const int* __restrict__ offs,
                                                       const float* __restrict__ dis,
                                                       const unsigned int* __restrict__ partial,
                                                       int2* __restrict__ csr) {
    __shared__ unsigned int cur[HWORDS];
    int c = blockIdx.x >> 1, hf = blockIdx.x & 1;
    int t = threadIdx.x;
    for (int i = t; i < HWORDS; i += 256) cur[i] = 0u;
    __syncthreads();
    bool is32 = (*flag != 0);
    const unsigned int* rel = partial + (size_t)blockIdx.x * HWORDS;
    int e0 = c * CHUNK;
    for (int k = 0; k < 13; ++k) {
        int e = e0 + t + k * 256;
        if (e < e0 + CHUNK) {
            int s, d;
            if (is32) {
                const int* p = (const int*)ei;
                s = p[e]; d = p[N_EDGES + e];
            } else {
                const long long* p = (const long long*)ei;
                s = (int)p[e]; d = (int)p[N_EDGES + e];
            }
            if (((d >= 25000) ? 1 : 0) == hf) {
                int w = (d - hf * 25000) >> 1;
                unsigned int old = atomicAdd(&cur[w], (d & 1) ? 0x10000u : 1u);
                unsigned int p0 = (d & 1) ? (old >> 16) : (old & 0xffffu);
                unsigned int rp = rel[w];
                unsigned int r = (d & 1) ? (rp >> 16) : (rp & 0xffffu);
                int pos = offs[d] + (int)r + (int)p0;
                int2 rec;
                rec.x = s;
                rec.y = __float_as_int(dis[s] * dis[d]);
                csr[pos] = rec;
            }
        }
    }
}

// graph offsets from sorted batch via boundary detection (no atomics)
__global__ __launch_bounds__(256) void goffs_kernel(const void* __restrict__ bt,
                                                    const int* __restrict__ flag,
                                                    int* __restrict__ goffs) {
    int v = blockIdx.x * 256 + threadIdx.x;
    if (v >= N_NODES) return;
    bool is32 = (*flag != 0);
    int b = is32 ? ((const int*)bt)[v] : (int)((const long long*)bt)[v];
    if (v == 0) {
        for (int g = 0; g <= b; ++g) goffs[g] = 0;
    } else {
        int pb = is32 ? ((const int*)bt)[v - 1] : (int)((const long long*)bt)[v - 1];
        for (int g = pb + 1; g <= b; ++g) goffs[g] = v;
    }
    if (v == N_NODES - 1) {
        for (int g = b + 1; g <= NGRAPH; ++g) goffs[g] = N_NODES;
    }
}

// split x into bf16 hi/lo + transpose/split W1,W2,W3 into [N][K] bf16 pairs
#define XSPLIT_BLOCKS 6250
__global__ __launch_bounds__(256) void prep_w(const float* __restrict__ x,
                                              const float* __restrict__ W1,
                                              const float* __restrict__ W2,
                                              const float* __restrict__ W3,
                                              unsigned short* __restrict__ xh,
                                              unsigned short* __restrict__ xl,
                                              unsigned short* __restrict__ wt) {
    int b = blockIdx.x;
    int t = threadIdx.x;
    if (b < XSPLIT_BLOCKS) {
        int i = b * 256 + t;
        float4 v = ((const float4*)x)[i];
        ushort4 h, lo;
        h.x = f2b(v.x); lo.x = f2b(v.x - b2f(h.x));
        h.y = f2b(v.y); lo.y = f2b(v.y - b2f(h.y));
        h.z = f2b(v.z); lo.z = f2b(v.z - b2f(h.z));
        h.w = f2b(v.w); lo.w = f2b(v.w - b2f(h.w));
        ((ushort4*)xh)[i] = h;
        ((ushort4*)xl)[i] = lo;
    } else {
        int wb = b - XSPLIT_BLOCKS;
        const float* W; int K, k, bh, bl;
        if (wb < 128)      { W = W1; K = 128; k = wb;       bh = WT1H; bl = WT1L; }
        else if (wb < 384) { W = W2; K = 256; k = wb - 128; bh = WT2H; bl = WT2L; }
        else               { W = W3; K = 256; k = wb - 384; bh = WT3H; bl = WT3L; }
        int n = t;
        float val = W[k * HID + n];
        unsigned short hv = f2b(val);
        unsigned short lv = f2b(val - b2f(hv));
        wt[bh + n * K + k] = hv;
        wt[bl + n * K + k] = lv;
    }
}

// ---------------- bf16x2-split MFMA GEMM; C written as bf16 ----------------
__global__ __launch_bounds__(256) void gemm_bf16x2(const unsigned short* __restrict__ Ah,
                                                   const unsigned short* __restrict__ Al,
                                                   const unsigned short* __restrict__ Bh,
                                                   const unsigned short* __restrict__ Bl,
                                                   unsigned short* __restrict__ C,
                                                   int M, int K) {
    __shared__ char lds[4 * 128 * 80];
    int tid = threadIdx.x;
    int bm = blockIdx.x * 128;
    int bn = blockIdx.y * 128;
    int lane = tid & 63, wid = tid >> 6;
    int wm = wid >> 1, wn = wid & 1;
    int lr = lane & 15, lc = lane >> 4;
    f32x4 acc[4][4];
    #pragma unroll
    for (int i = 0; i < 4; ++i)
        #pragma unroll
        for (int j = 0; j < 4; ++j)
            acc[i][j] = (f32x4){0.f, 0.f, 0.f, 0.f};

    const unsigned short* gA[2] = {Ah, Al};
    const unsigned short* gB[2] = {Bh, Bl};

    for (int k0 = 0; k0 < K; k0 += 32) {
        #pragma unroll
        for (int c8 = 0; c8 < 8; ++c8) {
            int c = tid + c8 * 256;
            int tile = c >> 9;
            int rr = (c >> 2) & 127;
            int q = c & 3;
            u32x4 v = {0u, 0u, 0u, 0u};
            if (tile < 2) {
                int row = bm + rr;
                if (row < M) v = *(const u32x4*)(gA[tile] + (size_t)row * K + k0 + q * 8);
            } else {
                int row = bn + rr;
                v = *(const u32x4*)(gB[tile - 2] + (size_t)row * K + k0 + q * 8);
            }
            *(u32x4*)(lds + tile * 10240 + rr * 80 + q * 16) = v;
        }
        __syncthreads();
        bf16x8 af[2][4], bfr[2][4];
        #pragma unroll
        for (int p = 0; p < 2; ++p) {
            #pragma unroll
            for (int f = 0; f < 4; ++f) {
                af[p][f]  = *(const bf16x8*)(lds + p * 10240       + (wm * 64 + f * 16 + lr) * 80 + lc * 16);
                bfr[p][f] = *(const bf16x8*)(lds + (2 + p) * 10240 + (wn * 64 + f * 16 + lr) * 80 + lc * 16);
            }
        }
        #pragma unroll
        for (int fi = 0; fi < 4; ++fi) {
            #pragma unroll
            for (int fj = 0; fj < 4; ++fj) {
                acc[fi][fj] = __builtin_amdgcn_mfma_f32_16x16x32_bf16(af[0][fi], bfr[0][fj], acc[fi][fj], 0, 0, 0);
                acc[fi][fj] = __builtin_amdgcn_mfma_f32_16x16x32_bf16(af[0][fi], bfr[1][fj], acc[fi][fj], 0, 0, 0);
                acc[fi][fj] = __builtin_amdgcn_mfma_f32_16x16x32_bf16(af[1][fi], bfr[0][fj], acc[fi][fj], 0, 0, 0);
            }
        }
        __syncthreads();
    }
    #pragma unroll
    for (int fi = 0; fi < 4; ++fi) {
        int rbase = bm + wm * 64 + fi * 16 + lc * 4;
        #pragma unroll
        for (int fj = 0; fj < 4; ++fj) {
            int col = bn + wn * 64 + fj * 16 + lr;
            #pragma unroll
            for (int r = 0; r < 4; ++r) {
                int row = rbase + r;
                if (row < M) C[(size_t)row * HID + col] = f2b(acc[fi][fj][r]);
            }
        }
    }
}

// ---------------- fused aggregation: bf16 H gather, 1 node/wave, 8-edge chunks, 2-deep pipeline ----
#define DECL_CH(P) int4 P##c0, P##c1, P##c2, P##c3; \
                   ushort4 P##h0, P##h1, P##h2, P##h3, P##h4, P##h5, P##h6, P##h7;

#define LOAD8(P, idx) do { \
    const int4* _q = (const int4*)(csr + (idx)); \
    P##c0 = _q[0]; P##c1 = _q[1]; P##c2 = _q[2]; P##c3 = _q[3]; \
    P##h0 = ((const ushort4*)(H + (size_t)P##c0.x * HID))[l]; \
    P##h1 = ((const ushort4*)(H + (size_t)P##c0.z * HID))[l]; \
    P##h2 = ((const ushort4*)(H + (size_t)P##c1.x * HID))[l]; \
    P##h3 = ((const ushort4*)(H + (size_t)P##c1.z * HID))[l]; \
    P##h4 = ((const ushort4*)(H + (size_t)P##c2.x * HID))[l]; \
    P##h5 = ((const ushort4*)(H + (size_t)P##c2.z * HID))[l]; \
    P##h6 = ((const ushort4*)(H + (size_t)P##c3.x * HID))[l]; \
    P##h7 = ((const ushort4*)(H + (size_t)P##c3.z * HID))[l]; \
} while (0)

#define FMA4U(hv, wv, a) do { float _w = (wv); \
    a.x = fmaf(b2f(hv.x), _w, a.x); a.y = fmaf(b2f(hv.y), _w, a.y); \
    a.z = fmaf(b2f(hv.z), _w, a.z); a.w = fmaf(b2f(hv.w), _w, a.w); } while (0)

#define CONS8(P, a) do { \
    FMA4U(P##h0, __int_as_float(P##c0.y), a); \
    FMA4U(P##h1, __int_as_float(P##c0.w), a); \
    FMA4U(P##h2, __int_as_float(P##c1.y), a); \
    FMA4U(P##h3, __int_as_float(P##c1.w), a); \
    FMA4U(P##h4, __int_as_float(P##c2.y), a); \
    FMA4U(P##h5, __int_as_float(P##c2.w), a); \
    FMA4U(P##h6, __int_as_float(P##c3.y), a); \
    FMA4U(P##h7, __int_as_float(P##c3.w), a); \
} while (0)

// MODE 0: +bias, ReLU, LayerNorm, write bf16 hi/lo.  MODE 1: +bias, write f32 rows.
template <int MODE>
__global__ __launch_bounds__(256) void agg_kernel(const unsigned short* __restrict__ H,
                                                  const float* __restrict__ dis,
                                                  const int* __restrict__ offs,
                                                  const int2* __restrict__ csr,
                                                  const float* __restrict__ bias,
                                                  const float* __restrict__ gamma,
                                                  const float* __restrict__ beta,
                                                  unsigned short* __restrict__ Zh,
                                                  unsigned short* __restrict__ Zl,
                                                  float* __restrict__ O) {
    int v = blockIdx.x * 4 + (threadIdx.x >> 6);
    int l = threadIdx.x & 63;

    float dv = dis[v];
    ushort4 a0u = ((const ushort4*)(H + (size_t)v * HID))[l];
    float sl = dv * dv;
    float4 acc;
    acc.x = b2f(a0u.x) * sl; acc.y = b2f(a0u.y) * sl;
    acc.z = b2f(a0u.z) * sl; acc.w = b2f(a0u.w) * sl;

    int i = offs[v];
    int n = (offs[v + 1] - i) >> 3;   // padded chunk count
    DECL_CH(A)
    DECL_CH(B)
    if (n > 0) LOAD8(A, i);
    if (n > 1) LOAD8(B, i + 8);
    int c = 0;
    while (c + 2 < n) {
        if ((c & 1) == 0) { CONS8(A, acc); LOAD8(A, i + 16); }
        else              { CONS8(B, acc); LOAD8(B, i + 16); }
        i += 8; ++c;
    }
    if (c < n) {
        if ((c & 1) == 0) CONS8(A, acc); else CONS8(B, acc);
        ++c;
    }
    if (c < n) {
        if ((c & 1) == 0) CONS8(A, acc); else CONS8(B, acc);
    }

    float4 b4 = ((const float4*)bias)[l];
    if (MODE == 0) {
        acc.x = fmaxf(acc.x + b4.x, 0.f); acc.y = fmaxf(acc.y + b4.y, 0.f);
        acc.z = fmaxf(acc.z + b4.z, 0.f); acc.w = fmaxf(acc.w + b4.w, 0.f);
        float s = acc.x + acc.y + acc.z + acc.w;
        #pragma unroll
        for (int o = 32; o >= 1; o >>= 1) s += __shfl_xor(s, o, 64);
        float mu = s * (1.0f / HID);
        float4 d;
        d.x = acc.x - mu; d.y = acc.y - mu; d.z = acc.z - mu; d.w = acc.w - mu;
        float vs = d.x * d.x + d.y * d.y + d.z * d.z + d.w * d.w;
        #pragma unroll
        for (int o = 32; o >= 1; o >>= 1) vs += __shfl_xor(vs, o, 64);
        float inv = rsqrtf(vs * (1.0f / HID) + LN_EPS);
        float4 g4 = ((const float4*)gamma)[l];
        float4 be4 = ((const float4*)beta)[l];
        float z0 = d.x * inv * g4.x + be4.x;
        float z1 = d.y * inv * g4.y + be4.y;
        float z2 = d.z * inv * g4.z + be4.z;
        float z3 = d.w * inv * g4.w + be4.w;
        ushort4 zh, zl;
        zh.x = f2b(z0); zl.x = f2b(z0 - b2f(zh.x));
        zh.y = f2b(z1); zl.y = f2b(z1 - b2f(zh.y));
        zh.z = f2b(z2); zl.z = f2b(z2 - b2f(zh.z));
        zh.w = f2b(z3); zl.w = f2b(z3 - b2f(zh.w));
        *(ushort4*)(Zh + (size_t)v * HID + l * 4) = zh;
        *(ushort4*)(Zl + (size_t)v * HID + l * 4) = zl;
    } else {
        float4 o0;
        o0.x = acc.x + b4.x; o0.y = acc.y + b4.y;
        o0.z = acc.z + b4.z; o0.w = acc.w + b4.w;
        ((float4*)(O + (size_t)v * HID))[l] = o0;
    }
}

// ---------------- per-graph segment-mean pool (batch is sorted) ----------------
__global__ __launch_bounds__(256) void pool_kernel(const float* __restrict__ O,
                                                   const int* __restrict__ goffs,
                                                   float* __restrict__ out) {
    int g = blockIdx.x, t = threadIdx.x;
    int l = t & 63, w = t >> 6;
    int s = goffs[g], e = goffs[g + 1];
    float4 acc = make_float4(0.f, 0.f, 0.f, 0.f);
    for (int v = s + w; v < e; v += 4) {
        float4 r = ((const float4*)(O + (size_t)v * HID))[l];
        acc.x += r.x; acc.y += r.y; acc.z += r.z; acc.w += r.w;
    }
    __shared__ float4 red[4][64];
    red[w][l] = acc;
    __syncthreads();
    if (w == 0) {
        float4 r0 = red[0][l], r1 = red[1][l], r2 = red[2][l], r3 = red[3][l];
        float inv = 1.0f / (float)(e - s);
        float4 o;
        o.x = (r0.x + r1.x + r2.x + r3.x) * inv;
        o.y = (r0.y + r1.y + r2.y + r3.y) * inv;
        o.z = (r0.z + r1.z + r2.z + r3.z) * inv;
        o.w = (r0.w + r1.w + r2.w + r3.w) * inv;
        ((float4*)(out + (size_t)g * HID))[l] = o;
    }
}

// ---------------- launch ----------------
extern "C" void kernel_launch(void* const* d_in, const int* in_sizes, int n_in,
                              void* d_out, int out_size, void* d_ws, size_t ws_size,
                              hipStream_t stream) {
    const float* x   = (const float*)d_in[0];
    const float* W1  = (const float*)d_in[1];
    const float* b1  = (const float*)d_in[2];
    const float* g1  = (const float*)d_in[3];
    const float* be1 = (const float*)d_in[4];
    const float* W2  = (const float*)d_in[5];
    const float* b2  = (const float*)d_in[6];
    const float* g2  = (const float*)d_in[7];
    const float* be2 = (const float*)d_in[8];
    const float* W3  = (const float*)d_in[9];
    const float* b3  = (const float*)d_in[10];
    const void*  ei  = d_in[11];
    const void*  bt  = d_in[12];
    float* out = (float*)d_out;

    unsigned int* ws = (unsigned int*)d_ws;
    int*   deg    = (int*)(ws + W_DEG);
    int*   flag   = (int*)(ws + W_FLAG);
    int*   bsum   = (int*)(ws + W_BSUM);
    int*   bpre   = (int*)(ws + W_BPRE);
    int*   goffs  = (int*)(ws + W_GOFF);
    int*   offs   = (int*)(ws + W_OFFS);
    float* dis    = (float*)(ws + W_DIS);
    int2*  csr    = (int2*)(ws + W_CSR);
    unsigned short* wt = (unsigned short*)(ws + W_WT);
    unsigned short* Zh = (unsigned short*)(ws + W_ZH);
    unsigned short* Zl = (unsigned short*)(ws + W_ZL);
    unsigned short* xh = Zh;            // overlay: x-split dead after gemm1
    unsigned short* xl = Zl;
    unsigned short* Hbuf = (unsigned short*)(ws + W_H);       // bf16 H
    unsigned int*   partial = (unsigned int*)(ws + W_H);      // overlay: sort partials dead after scatter2
    float* Obuf = (float*)(ws + W_ZH);  // overlay: Zh/Zl dead after gemm3

    const int EB = (N_EDGES + 255) / 256;
    const int NB = (N_NODES + 255) / 256;  // 196

    zero_kernel<<<1, 256, 0, stream>>>(ws + W_FLAG, 16);
    zero_kernel<<<(2 * PAD_E + 255) / 256, 256, 0, stream>>>(ws + W_CSR, 2 * PAD_E);
    detect_kernel<<<EB, 256, 0, stream>>>((const unsigned int*)ei, flag);
    hist_kernel<<<2 * NCHUNK, 256, 0, stream>>>(ei, flag, partial);
    merge_kernel<<<(25000 + 255) / 256, 256, 0, stream>>>(partial, deg);
    blocksum_kernel<<<NB, 256, 0, stream>>>(deg, bsum);
    scanb_kernel<<<1, 256, 0, stream>>>(bsum, bpre);
    finalize_kernel<<<NB, 256, 0, stream>>>(deg, bpre, offs, dis);
    scatter2_kernel<<<2 * NCHUNK, 256, 0, stream>>>(ei, flag, offs, dis, partial, csr);
    goffs_kernel<<<NB, 256, 0, stream>>>(bt, flag, goffs);
    prep_w<<<XSPLIT_BLOCKS + 640, 256, 0, stream>>>(x, W1, W2, W3, xh, xl, wt);

    dim3 gg((N_NODES + 127) / 128, HID / 128);
    const int AB = N_NODES / 4;  // 12500 blocks = 50000 waves = 1 node/wave

    gemm_bf16x2<<<gg, 256, 0, stream>>>(xh, xl, wt + WT1H, wt + WT1L, Hbuf, N_NODES, IN_DIM);
    agg_kernel<0><<<AB, 256, 0, stream>>>(Hbuf, dis, offs, csr, b1, g1, be1, Zh, Zl, nullptr);
    gemm_bf16x2<<<gg, 256, 0, stream>>>(Zh, Zl, wt + WT2H, wt + WT2L, Hbuf, N_NODES, HID);
    agg_kernel<0><<<AB, 256, 0, stream>>>(Hbuf, dis, offs, csr, b2, g2, be2, Zh, Zl, nullptr);
    gemm_bf16x2<<<gg, 256, 0, stream>>>(Zh, Zl, wt + WT3H, wt + WT3L, Hbuf, N_NODES, HID);
    agg_kernel<1><<<AB, 256, 0, stream>>>(Hbuf, dis, offs, csr, b3, nullptr, nullptr, nullptr, nullptr, Obuf);
    pool_kernel<<<NGRAPH, 256, 0, stream>>>(Obuf, goffs, out);
}

// Round 7
// 438.634 us; speedup vs baseline: 2.4440x; 1.1281x over previous
//
#include <hip/hip_runtime.h>

#define N_NODES 50000
#define MROWS   50048   // N_NODES padded to 128 (391 * 128) - GEMM runs guard-free
#define N_EDGES 800000
#define IN_DIM  128
#define HID     256
#define NGRAPH  256
#define LN_EPS  1e-5f

typedef __attribute__((ext_vector_type(8))) short bf16x8;
typedef __attribute__((ext_vector_type(4))) float f32x4;
typedef __attribute__((ext_vector_type(4))) unsigned int u32x4;

// counting-sort geometry: 256 chunks x 3125 edges; bins split in 2 halves of 25000
#define NCHUNK  256
#define CHUNK   3125
#define HWORDS  12500   // packed u32 words per half (2 bins/word)

// padded CSR capacity (pad each node's edge list to a multiple of 8; max +7/node)
#define PAD_E (N_EDGES + 7 * N_NODES)

// ---------------- workspace layout (32-bit word offsets) ----------------
#define W_DEG      0
#define W_FLAG     (W_DEG + N_NODES)
#define W_BSUM     (W_FLAG + 16)
#define W_BPRE     (W_BSUM + 256)
#define W_GOFF     (W_BPRE + 256)
#define W_OFFS     (W_GOFF + NGRAPH + 8)
#define W_DIS      (W_OFFS + N_NODES + 8)
#define W_CSR      (((W_DIS + N_NODES) + 3) & ~3)
#define W_WT       (W_CSR + 2 * PAD_E)
#define W_ZH       (((W_WT + 163840) + 3) & ~3)
#define W_ZL       (W_ZH + (MROWS * HID / 2))
#define W_H        (W_ZL + (MROWS * HID / 2))   // bf16 H (overlaid by sort partials pre-gemm1)

// Wt sub-offsets in ushorts within W_WT
#define WT1H 0
#define WT1L 32768
#define WT2H 65536
#define WT2L 131072
#define WT3H 196608
#define WT3L 262144

__device__ __forceinline__ unsigned short f2b(float f) {
    unsigned int u = __float_as_uint(f);
    unsigned int r = (u + 0x7FFFu + ((u >> 16) & 1u)) >> 16;
    return (unsigned short)r;
}
__device__ __forceinline__ float b2f(unsigned short h) {
    return __uint_as_float(((unsigned int)h) << 16);
}
// 4 bf16 (packed in uint2) -> f32x4  (and/shl pair decode, 4 inst)
__device__ __forceinline__ f32x4 cvt4(uint2 u) {
    f32x4 r;
    r[0] = __uint_as_float(u.x << 16);
    r[1] = __uint_as_float(u.x & 0xffff0000u);
    r[2] = __uint_as_float(u.y << 16);
    r[3] = __uint_as_float(u.y & 0xffff0000u);
    return r;
}

// ---------------- prep kernels ----------------
__global__ __launch_bounds__(256) void zero_kernel(unsigned int* __restrict__ p, int n) {
    int i = blockIdx.x * 256 + threadIdx.x;
    if (i < n) p[i] = 0u;
}

__global__ __launch_bounds__(256) void detect_kernel(const unsigned int* __restrict__ ei,
                                                     int* __restrict__ flag) {
    int e = blockIdx.x * 256 + threadIdx.x;
    if (e >= N_EDGES) return;
    if (ei[2 * e + 1] != 0u) *flag = 1;
}

// pass 1: per-(chunk,half) LDS histogram, packed 2x16-bit counts per word
__global__ __launch_bounds__(256) void hist_kernel(const void* __restrict__ ei,
                                                   const int* __restrict__ flag,
                                                   unsigned int* __restrict__ partial) {
    __shared__ unsigned int h[HWORDS];
    int c = blockIdx.x >> 1, hf = blockIdx.x & 1;
    int t = threadIdx.x;
    for (int i = t; i < HWORDS; i += 256) h[i] = 0u;
    __syncthreads();
    bool is32 = (*flag != 0);
    int e0 = c * CHUNK;
    for (int k = 0; k < 13; ++k) {
        int e = e0 + t + k * 256;
        if (e < e0 + CHUNK) {
            int d = is32 ? ((const int*)ei)[N_EDGES + e]
                         : (int)((const long long*)ei)[N_EDGES + e];
            if (((d >= 25000) ? 1 : 0) == hf) {
                int w = (d - hf * 25000) >> 1;
                atomicAdd(&h[w], (d & 1) ? 0x10000u : 1u);
            }
        }
    }
    __syncthreads();
    unsigned int* dst = partial + (size_t)blockIdx.x * HWORDS;
    for (int i = t; i < HWORDS; i += 256) dst[i] = h[i];
}

// pass 2: per bin-pair, exclusive prefix across chunks (in place) + total degree
__global__ __launch_bounds__(256) void merge_kernel(unsigned int* __restrict__ partial,
                                                    int* __restrict__ deg) {
    int w = blockIdx.x * 256 + threadIdx.x;
    if (w >= 25000) return;
    int hf = (w >= HWORDS) ? 1 : 0;
    int wi = w - hf * HWORDS;
    unsigned int run_lo = 0, run_hi = 0;
    for (int c = 0; c < NCHUNK; ++c) {
        size_t idx = ((size_t)(c * 2 + hf)) * HWORDS + wi;
        unsigned int u = partial[idx];
        partial[idx] = run_lo | (run_hi << 16);
        run_lo += u & 0xffffu;
        run_hi += u >> 16;
    }
    deg[2 * w]     = (int)run_lo;
    deg[2 * w + 1] = (int)run_hi;
}

// per-block sums of padded degrees
__global__ __launch_bounds__(256) void blocksum_kernel(const int* __restrict__ deg,
                                                       int* __restrict__ bsum) {
    int b = blockIdx.x, t = threadIdx.x;
    int i = b * 256 + t;
    int pd = (i < N_NODES) ? ((deg[i] + 7) & ~7) : 0;
    int lane = t & 63, w = t >> 6;
    int s = pd;
    #pragma unroll
    for (int o = 32; o >= 1; o >>= 1) s += __shfl_xor(s, o, 64);
    __shared__ int ws[4];
    if (lane == 0) ws[w] = s;
    __syncthreads();
    if (t == 0) bsum[b] = ws[0] + ws[1] + ws[2] + ws[3];
}

// single tiny block: exclusive scan bsum(196) -> bpre
__global__ __launch_bounds__(256) void scanb_kernel(const int* __restrict__ bsum,
                                                    int* __restrict__ bpre) {
    int t = threadIdx.x;
    int lane = t & 63, w = t >> 6;
    int x = (t < 196) ? bsum[t] : 0;
    int inc = x;
    #pragma unroll
    for (int o = 1; o < 64; o <<= 1) {
        int u = __shfl_up(inc, o, 64);
        if (lane >= o) inc += u;
    }
    __shared__ int wsA[4];
    if (lane == 63) wsA[w] = inc;
    __syncthreads();
    int base = 0;
    for (int k = 0; k < w; ++k) base += wsA[k];
    bpre[t] = base + inc - x;
}

// per-node padded offsets + dis
__global__ __launch_bounds__(256) void finalize_kernel(const int* __restrict__ deg,
                                                       const int* __restrict__ bpre,
                                                       int* __restrict__ offs,
                                                       float* __restrict__ dis) {
    int b = blockIdx.x, t = threadIdx.x;
    int i = b * 256 + t;
    int d = (i < N_NODES) ? deg[i] : 0;
    int pd = (d + 7) & ~7;
    int lane = t & 63, w = t >> 6;
    int inc = pd;
    #pragma unroll
    for (int o = 1; o < 64; o <<= 1) {
        int u = __shfl_up(inc, o, 64);
        if (lane >= o) inc += u;
    }
    __shared__ int ws[4];
    if (lane == 63) ws[w] = inc;
    __syncthreads();
    int base = 0;
    for (int k = 0; k < w; ++k) base += ws[k];
    int pre = base + inc - pd;
    if (i < N_NODES) {
        offs[i] = bpre[b] + pre;
        dis[i] = rsqrtf((float)d + 1.0f);
    }
    if (i == N_NODES - 1) offs[N_NODES] = bpre[b] + pre + pd;
}

// pass 3: counting-sort scatter (no global atomics); rec.x = src byte-offset (src<<9)
__global__ __launch_bounds__(256) void scatter2_kernel(const void* __restrict__ ei,
                                                       const int* __restrict__ flag,
                                                       const int* __restrict__ offs,
                                                       const float* __restrict__ dis,
                                                       const unsigned int* __restrict__ partial,
                                                       int2* __restrict__ csr) {
    __shared__ unsigned int cur[HWORDS];
    int c = blockIdx.x >> 1, hf = blockIdx.x & 1;
    int t = threadIdx.x;
    for (int i = t; i < HWORDS; i += 256) cur[i] = 0u;
    __syncthreads();
    bool is32 = (*flag != 0);
    const unsigned int* rel = partial + (size_t)blockIdx.x * HWORDS;
    int e0 = c * CHUNK;
    for (int k = 0; k < 13; ++k) {
        int e = e0 + t + k * 256;
        if (e < e0 + CHUNK) {
            int s, d;
            if (is32) {
                const int* p = (const int*)ei;
                s = p[e]; d = p[N_EDGES + e];
            } else {
                const long long* p = (const long long*)ei;
                s = (int)p[e]; d = (int)p[N_EDGES + e];
            }
            if (((d >= 25000) ? 1 : 0) == hf) {
                int w = (d - hf * 25000) >> 1;
                unsigned int old = atomicAdd(&cur[w], (d & 1) ? 0x10000u : 1u);
                unsigned int p0 = (d & 1) ? (old >> 16) : (old & 0xffffu);
                unsigned int rp = rel[w];
                unsigned int r = (d & 1) ? (rp >> 16) : (rp & 0xffffu);
                int pos = offs[d] + (int)r + (int)p0;
                int2 rec;
                rec.x = s << 9;                       // pre-multiplied byte offset into bf16 H
                rec.y = __float_as_int(dis[s] * dis[d]);
                csr[pos] = rec;
            }
        }
    }
}

// graph offsets from sorted batch via boundary detection (no atomics)
__global__ __launch_bounds__(256) void goffs_kernel(const void* __restrict__ bt,
                                                    const int* __restrict__ flag,
                                                    int* __restrict__ goffs) {
    int v = blockIdx.x * 256 + threadIdx.x;
    if (v >= N_NODES) return;
    bool is32 = (*flag != 0);
    int b = is32 ? ((const int*)bt)[v] : (int)((const long long*)bt)[v];
    if (v == 0) {
        for (int g = 0; g <= b; ++g) goffs[g] = 0;
    } else {
        int pb = is32 ? ((const int*)bt)[v - 1] : (int)((const long long*)bt)[v - 1];
        for (int g = pb + 1; g <= b; ++g) goffs[g] = v;
    }
    if (v == N_NODES - 1) {
        for (int g = b + 1; g <= NGRAPH; ++g) goffs[g] = N_NODES;
    }
}

// split x into bf16 hi/lo + transpose/split W1,W2,W3 into [N][K] bf16 pairs
#define XSPLIT_BLOCKS 6250
__global__ __launch_bounds__(256) void prep_w(const float* __restrict__ x,
                                              const float* __restrict__ W1,
                                              const float* __restrict__ W2,
                                              const float* __restrict__ W3,
                                              unsigned short* __restrict__ xh,
                                              unsigned short* __restrict__ xl,
                                              unsigned short* __restrict__ wt) {
    int b = blockIdx.x;
    int t = threadIdx.x;
    if (b < XSPLIT_BLOCKS) {
        int i = b * 256 + t;
        float4 v = ((const float4*)x)[i];
        ushort4 h, lo;
        h.x = f2b(v.x); lo.x = f2b(v.x - b2f(h.x));
        h.y = f2b(v.y); lo.y = f2b(v.y - b2f(h.y));
        h.z = f2b(v.z); lo.z = f2b(v.z - b2f(h.z));
        h.w = f2b(v.w); lo.w = f2b(v.w - b2f(h.w));
        ((ushort4*)xh)[i] = h;
        ((ushort4*)xl)[i] = lo;
    } else {
        int wb = b - XSPLIT_BLOCKS;
        const float* W; int K, k, bh, bl;
        if (wb < 128)      { W = W1; K = 128; k = wb;       bh = WT1H; bl = WT1L; }
        else if (wb < 384) { W = W2; K = 256; k = wb - 128; bh = WT2H; bl = WT2L; }
        else               { W = W3; K = 256; k = wb - 384; bh = WT3H; bl = WT3L; }
        int n = t;
        float val = W[k * HID + n];
        unsigned short hv = f2b(val);
        unsigned short lv = f2b(val - b2f(hv));
        wt[bh + n * K + k] = hv;
        wt[bl + n * K + k] = lv;
    }
}

// ---------------- bf16x2-split MFMA GEMM; guard-free (M padded to MROWS); C as bf16 ----------------
__global__ __launch_bounds__(256) void gemm_bf16x2(const unsigned short* __restrict__ Ah,
                                                   const unsigned short* __restrict__ Al,
                                                   const unsigned short* __restrict__ Bh,
                                                   const unsigned short* __restrict__ Bl,
                                                   unsigned short* __restrict__ C,
                                                   int K) {
    __shared__ char lds[4 * 128 * 80];
    int tid = threadIdx.x;
    int bm = blockIdx.x * 128;
    int bn = blockIdx.y * 128;
    int lane = tid & 63, wid = tid >> 6;
    int wm = wid >> 1, wn = wid & 1;
    int lr = lane & 15, lc = lane >> 4;
    f32x4 acc[4][4];
    #pragma unroll
    for (int i = 0; i < 4; ++i)
        #pragma unroll
        for (int j = 0; j < 4; ++j)
            acc[i][j] = (f32x4){0.f, 0.f, 0.f, 0.f};

    for (int k0 = 0; k0 < K; k0 += 32) {
        // stage 4 tiles; tile index is compile-time constant per unrolled step
        #pragma unroll
        for (int c8 = 0; c8 < 8; ++c8) {
            const int tile = c8 >> 1;
            const unsigned short* __restrict__ src =
                (tile == 0) ? Ah : (tile == 1) ? Al : (tile == 2) ? Bh : Bl;
            int c = ((c8 & 1) << 8) + tid;
            int rr = c >> 2, q = c & 3;
            int row = ((tile < 2) ? bm : bn) + rr;
            u32x4 v = *(const u32x4*)(src + (size_t)row * K + k0 + q * 8);
            *(u32x4*)(lds + tile * 10240 + rr * 80 + q * 16) = v;
        }
        __syncthreads();
        bf16x8 af[2][4], bfr[2][4];
        #pragma unroll
        for (int p = 0; p < 2; ++p) {
            #pragma unroll
            for (int f = 0; f < 4; ++f) {
                af[p][f]  = *(const bf16x8*)(lds + p * 10240       + (wm * 64 + f * 16 + lr) * 80 + lc * 16);
                bfr[p][f] = *(const bf16x8*)(lds + (2 + p) * 10240 + (wn * 64 + f * 16 + lr) * 80 + lc * 16);
            }
        }
        #pragma unroll
        for (int fi = 0; fi < 4; ++fi) {
            #pragma unroll
            for (int fj = 0; fj < 4; ++fj) {
                acc[fi][fj] = __builtin_amdgcn_mfma_f32_16x16x32_bf16(af[0][fi], bfr[0][fj], acc[fi][fj], 0, 0, 0);
                acc[fi][fj] = __builtin_amdgcn_mfma_f32_16x16x32_bf16(af[0][fi], bfr[1][fj], acc[fi][fj], 0, 0, 0);
                acc[fi][fj] = __builtin_amdgcn_mfma_f32_16x16x32_bf16(af[1][fi], bfr[0][fj], acc[fi][fj], 0, 0, 0);
            }
        }
        __syncthreads();
    }
    #pragma unroll
    for (int fi = 0; fi < 4; ++fi) {
        int rbase = bm + wm * 64 + fi * 16 + lc * 4;
        #pragma unroll
        for (int fj = 0; fj < 4; ++fj) {
            int col = bn + wn * 64 + fj * 16 + lr;
            #pragma unroll
            for (int r = 0; r < 4; ++r) {
                C[(size_t)(rbase + r) * HID + col] = f2b(acc[fi][fj][r]);
            }
        }
    }
}

// ---------------- fused aggregation: bf16 H gather, 1 node/wave, 8-edge chunks, 2-deep pipeline ----
#define DECL_CH(P) int4 P##c0, P##c1, P##c2, P##c3; \
                   uint2 P##h0, P##h1, P##h2, P##h3, P##h4, P##h5, P##h6, P##h7;

#define LOAD8(P, idx) do { \
    const int4* _q = (const int4*)(csr + (idx)); \
    P##c0 = _q[0]; P##c1 = _q[1]; P##c2 = _q[2]; P##c3 = _q[3]; \
    P##h0 = *(const uint2*)(Hl + P##c0.x); \
    P##h1 = *(const uint2*)(Hl + P##c0.z); \
    P##h2 = *(const uint2*)(Hl + P##c1.x); \
    P##h3 = *(const uint2*)(Hl + P##c1.z); \
    P##h4 = *(const uint2*)(Hl + P##c2.x); \
    P##h5 = *(const uint2*)(Hl + P##c2.z); \
    P##h6 = *(const uint2*)(Hl + P##c3.x); \
    P##h7 = *(const uint2*)(Hl + P##c3.z); \
} while (0)

#define FMA4U(hv, wv, a) do { a += cvt4(hv) * (wv); } while (0)

#define CONS8(P, a) do { \
    FMA4U(P##h0, __int_as_float(P##c0.y), a); \
    FMA4U(P##h1, __int_as_float(P##c0.w), a); \
    FMA4U(P##h2, __int_as_float(P##c1.y), a); \
    FMA4U(P##h3, __int_as_float(P##c1.w), a); \
    FMA4U(P##h4, __int_as_float(P##c2.y), a); \
    FMA4U(P##h5, __int_as_float(P##c2.w), a); \
    FMA4U(P##h6, __int_as_float(P##c3.y), a); \
    FMA4U(P##h7, __int_as_float(P##c3.w), a); \
} while (0)

// MODE 0: +bias, ReLU, LayerNorm, write bf16 hi/lo.  MODE 1: +bias, write f32 rows.
template <int MODE>
__global__ __launch_bounds__(256) void agg_kernel(const unsigned short* __restrict__ H,
                                                  const float* __restrict__ dis,
                                                  const int* __restrict__ offs,
                                                  const int2* __restrict__ csr,
                                                  const float* __restrict__ bias,
                                                  const float* __restrict__ gamma,
                                                  const float* __restrict__ beta,
                                                  unsigned short* __restrict__ Zh,
                                                  unsigned short* __restrict__ Zl,
                                                  float* __restrict__ O) {
    int v = blockIdx.x * 4 + (threadIdx.x >> 6);
    int l = threadIdx.x & 63;
    const char* Hl = (const char*)H + l * 8;   // lane-fixed byte base

    float dv = dis[v];
    uint2 a0u = ((const uint2*)(H + (size_t)v * HID))[l];
    f32x4 acc = cvt4(a0u) * (dv * dv);

    int i = offs[v];
    int n = (offs[v + 1] - i) >> 3;   // padded chunk count
    DECL_CH(A)
    DECL_CH(B)
    if (n > 0) LOAD8(A, i);
    if (n > 1) LOAD8(B, i + 8);
    int c = 0;
    // steady state: consume chunk c, prefetch chunk c+2 into the freed register set
    while (c + 2 < n) {
        if ((c & 1) == 0) { CONS8(A, acc); LOAD8(A, i + 16); }
        else              { CONS8(B, acc); LOAD8(B, i + 16); }
        i += 8; ++c;
    }
    if (c < n) {
        if ((c & 1) == 0) CONS8(A, acc); else CONS8(B, acc);
        ++c;
    }
    if (c < n) {
        if ((c & 1) == 0) CONS8(A, acc); else CONS8(B, acc);
    }

    f32x4 b4 = *(const f32x4*)(bias + l * 4);
    if (MODE == 0) {
        acc += b4;
        acc[0] = fmaxf(acc[0], 0.f); acc[1] = fmaxf(acc[1], 0.f);
        acc[2] = fmaxf(acc[2], 0.f); acc[3] = fmaxf(acc[3], 0.f);
        float s = acc[0] + acc[1] + acc[2] + acc[3];
        #pragma unroll
        for (int o = 32; o >= 1; o >>= 1) s += __shfl_xor(s, o, 64);
        float mu = s * (1.0f / HID);
        f32x4 d = acc - mu;
        float vs = d[0] * d[0] + d[1] * d[1] + d[2] * d[2] + d[3] * d[3];
        #pragma unroll
        for (int o = 32; o >= 1; o >>= 1) vs += __shfl_xor(vs, o, 64);
        float inv = rsqrtf(vs * (1.0f / HID) + LN_EPS);
        f32x4 g4 = *(const f32x4*)(gamma + l * 4);
        f32x4 be4 = *(const f32x4*)(beta + l * 4);
        float z0 = d[0] * inv * g4[0] + be4[0];
        float z1 = d[1] * inv * g4[1] + be4[1];
        float z2 = d[2] * inv * g4[2] + be4[2];
        float z3 = d[3] * inv * g4[3] + be4[3];
        ushort4 zh, zl;
        zh.x = f2b(z0); zl.x = f2b(z0 - b2f(zh.x));
        zh.y = f2b(z1); zl.y = f2b(z1 - b2f(zh.y));
        zh.z = f2b(z2); zl.z = f2b(z2 - b2f(zh.z));
        zh.w = f2b(z3); zl.w = f2b(z3 - b2f(zh.w));
        *(ushort4*)(Zh + (size_t)v * HID + l * 4) = zh;
        *(ushort4*)(Zl + (size_t)v * HID + l * 4) = zl;
    } else {
        acc += b4;
        *(f32x4*)(O + (size_t)v * HID + l * 4) = acc;
    }
}

// ---------------- per-graph segment-mean pool (batch is sorted) ----------------
__global__ __launch_bounds__(256) void pool_kernel(const float* __restrict__ O,
                                                   const int* __restrict__ goffs,
                                                   float* __restrict__ out) {
    int g = blockIdx.x, t = threadIdx.x;
    int l = t & 63, w = t >> 6;
    int s = goffs[g], e = goffs[g + 1];
    float4 acc = make_float4(0.f, 0.f, 0.f, 0.f);
    for (int v = s + w; v < e; v += 4) {
        float4 r = ((const float4*)(O + (size_t)v * HID))[l];
        acc.x += r.x; acc.y += r.y; acc.z += r.z; acc.w += r.w;
    }
    __shared__ float4 red[4][64];
    red[w][l] = acc;
    __syncthreads();
    if (w == 0) {
        float4 r0 = red[0][l], r1 = red[1][l], r2 = red[2][l], r3 = red[3][l];
        float inv = 1.0f / (float)(e - s);
        float4 o;
        o.x = (r0.x + r1.x + r2.x + r3.x) * inv;
        o.y = (r0.y + r1.y + r2.y + r3.y) * inv;
        o.z = (r0.z + r1.z + r2.z + r3.z) * inv;
        o.w = (r0.w + r1.w + r2.w + r3.w) * inv;
        ((float4*)(out + (size_t)g * HID))[l] = o;
    }
}

// ---------------- launch ----------------
extern "C" void kernel_launch(void* const* d_in, const int* in_sizes, int n_in,
                              void* d_out, int out_size, void* d_ws, size_t ws_size,
                              hipStream_t stream) {
    const float* x   = (const float*)d_in[0];
    const float* W1  = (const float*)d_in[1];
    const float* b1  = (const float*)d_in[2];
    const float* g1  = (const float*)d_in[3];
    const float* be1 = (const float*)d_in[4];
    const float* W2  = (const float*)d_in[5];
    const float* b2  = (const float*)d_in[6];
    const float* g2  = (const float*)d_in[7];
    const float* be2 = (const float*)d_in[8];
    const float* W3  = (const float*)d_in[9];
    const float* b3  = (const float*)d_in[10];
    const void*  ei  = d_in[11];
    const void*  bt  = d_in[12];
    float* out = (float*)d_out;

    unsigned int* ws = (unsigned int*)d_ws;
    int*   deg    = (int*)(ws + W_DEG);
    int*   flag   = (int*)(ws + W_FLAG);
    int*   bsum   = (int*)(ws + W_BSUM);
    int*   bpre   = (int*)(ws + W_BPRE);
    int*   goffs  = (int*)(ws + W_GOFF);
    int*   offs   = (int*)(ws + W_OFFS);
    float* dis    = (float*)(ws + W_DIS);
    int2*  csr    = (int2*)(ws + W_CSR);
    unsigned short* wt = (unsigned short*)(ws + W_WT);
    unsigned short* Zh = (unsigned short*)(ws + W_ZH);
    unsigned short* Zl = (unsigned short*)(ws + W_ZL);
    unsigned short* xh = Zh;            // overlay: x-split dead after gemm1
    unsigned short* xl = Zl;
    unsigned short* Hbuf = (unsigned short*)(ws + W_H);       // bf16 H (MROWS rows)
    unsigned int*   partial = (unsigned int*)(ws + W_H);      // overlay: sort partials dead after scatter2
    float* Obuf = (float*)(ws + W_ZH);  // overlay: Zh/Zl dead after gemm3

    const int EB = (N_EDGES + 255) / 256;
    const int NB = (N_NODES + 255) / 256;  // 196

    zero_kernel<<<1, 256, 0, stream>>>(ws + W_FLAG, 16);
    zero_kernel<<<(2 * PAD_E + 255) / 256, 256, 0, stream>>>(ws + W_CSR, 2 * PAD_E);
    detect_kernel<<<EB, 256, 0, stream>>>((const unsigned int*)ei, flag);
    hist_kernel<<<2 * NCHUNK, 256, 0, stream>>>(ei, flag, partial);
    merge_kernel<<<(25000 + 255) / 256, 256, 0, stream>>>(partial, deg);
    blocksum_kernel<<<NB, 256, 0, stream>>>(deg, bsum);
    scanb_kernel<<<1, 256, 0, stream>>>(bsum, bpre);
    finalize_kernel<<<NB, 256, 0, stream>>>(deg, bpre, offs, dis);
    scatter2_kernel<<<2 * NCHUNK, 256, 0, stream>>>(ei, flag, offs, dis, partial, csr);
    goffs_kernel<<<NB, 256, 0, stream>>>(bt, flag, goffs);
    prep_w<<<XSPLIT_BLOCKS + 640, 256, 0, stream>>>(x, W1, W2, W3, xh, xl, wt);

    dim3 gg(MROWS / 128, HID / 128);     // (391, 2), guard-free
    const int AB = N_NODES / 4;          // 12500 blocks = 50000 waves = 1 node/wave

    gemm_bf16x2<<<gg, 256, 0, stream>>>(xh, xl, wt + WT1H, wt + WT1L, Hbuf, IN_DIM);
    agg_kernel<0><<<AB, 256, 0, stream>>>(Hbuf, dis, offs, csr, b1, g1, be1, Zh, Zl, nullptr);
    gemm_bf16x2<<<gg, 256, 0, stream>>>(Zh, Zl, wt + WT2H, wt + WT2L, Hbuf, HID);
    agg_kernel<0><<<AB, 256, 0, stream>>>(Hbuf, dis, offs, csr, b2, g2, be2, Zh, Zl, nullptr);
    gemm_bf16x2<<<gg, 256, 0, stream>>>(Zh, Zl, wt + WT3H, wt + WT3L, Hbuf, HID);
    agg_kernel<1><<<AB, 256, 0, stream>>>(Hbuf, dis, offs, csr, b3, nullptr, nullptr, nullptr, nullptr, Obuf);
    pool_kernel<<<NGRAPH, 256, 0, stream>>>(Obuf, goffs, out);
}

// Round 8
// 403.328 us; speedup vs baseline: 2.6579x; 1.0875x over previous
//
#include <hip/hip_runtime.h>

#define N_NODES 50000
#define MROWS   50048   // N_NODES padded to 128 (391 * 128) - GEMM runs guard-free
#define N_EDGES 800000
#define IN_DIM  128
#define HID     256
#define NGRAPH  256
#define LN_EPS  1e-5f

typedef __attribute__((ext_vector_type(8))) short bf16x8;
typedef __attribute__((ext_vector_type(4))) float f32x4;
typedef __attribute__((ext_vector_type(4))) unsigned int u32x4;

// counting-sort geometry: 128 chunks x 6250 edges; bins split in 2 halves of 25000
#define NCHUNK  128
#define CHUNK   6250
#define HWORDS  12500   // packed u32 words per half (2 bins/word)

// padded CSR capacity (pad each node's edge list to a multiple of 8; max +7/node)
#define PAD_E (N_EDGES + 7 * N_NODES)

// ---------------- workspace layout (32-bit word offsets) ----------------
#define W_DEG      0
#define W_FLAG     (W_DEG + N_NODES)
#define W_BSUM     (W_FLAG + 16)
#define W_BPRE     (W_BSUM + 256)
#define W_GOFF     (W_BPRE + 256)
#define W_OFFS     (W_GOFF + NGRAPH + 8)
#define W_DIS      (W_OFFS + N_NODES + 8)
#define W_CSR      (((W_DIS + N_NODES) + 3) & ~3)
#define W_WT       (W_CSR + 2 * PAD_E)
#define W_ZH       (((W_WT + 163840) + 3) & ~3)
#define W_ZL       (W_ZH + (MROWS * HID / 2))       // spill space for f32 Obuf overlay
#define W_H        (W_ZL + (MROWS * HID / 2))       // bf16 H (overlaid by sort partials pre-gemm1)

// Wt sub-offsets in ushorts within W_WT
#define WT1H 0
#define WT1L 32768
#define WT2H 65536
#define WT2L 131072
#define WT3H 196608
#define WT3L 262144

__device__ __forceinline__ unsigned short f2b(float f) {
    unsigned int u = __float_as_uint(f);
    unsigned int r = (u + 0x7FFFu + ((u >> 16) & 1u)) >> 16;
    return (unsigned short)r;
}
__device__ __forceinline__ float b2f(unsigned short h) {
    return __uint_as_float(((unsigned int)h) << 16);
}
// 4 bf16 (packed in uint2) -> f32x4  (and/shl pair decode, 4 inst)
__device__ __forceinline__ f32x4 cvt4(uint2 u) {
    f32x4 r;
    r[0] = __uint_as_float(u.x << 16);
    r[1] = __uint_as_float(u.x & 0xffff0000u);
    r[2] = __uint_as_float(u.y << 16);
    r[3] = __uint_as_float(u.y & 0xffff0000u);
    return r;
}

// ---------------- prep kernels ----------------
__global__ __launch_bounds__(256) void zero_kernel(unsigned int* __restrict__ p, int n) {
    int i = blockIdx.x * 256 + threadIdx.x;
    if (i < n) p[i] = 0u;
}

__global__ __launch_bounds__(256) void detect_kernel(const unsigned int* __restrict__ ei,
                                                     int* __restrict__ flag) {
    int e = blockIdx.x * 256 + threadIdx.x;
    if (e >= N_EDGES) return;
    if (ei[2 * e + 1] != 0u) *flag = 1;
}

// pass 1: per-(chunk,half) LDS histogram, packed 2x16-bit counts per word
__global__ __launch_bounds__(256) void hist_kernel(const void* __restrict__ ei,
                                                   const int* __restrict__ flag,
                                                   unsigned int* __restrict__ partial) {
    __shared__ unsigned int h[HWORDS];
    int c = blockIdx.x >> 1, hf = blockIdx.x & 1;
    int t = threadIdx.x;
    for (int i = t; i < HWORDS; i += 256) h[i] = 0u;
    __syncthreads();
    bool is32 = (*flag != 0);
    int e0 = c * CHUNK;
    for (int k = 0; k < 25; ++k) {
        int e = e0 + t + k * 256;
        if (e < e0 + CHUNK) {
            int d = is32 ? ((const int*)ei)[N_EDGES + e]
                         : (int)((const long long*)ei)[N_EDGES + e];
            if (((d >= 25000) ? 1 : 0) == hf) {
                int w = (d - hf * 25000) >> 1;
                atomicAdd(&h[w], (d & 1) ? 0x10000u : 1u);
            }
        }
    }
    __syncthreads();
    unsigned int* dst = partial + (size_t)blockIdx.x * HWORDS;
    for (int i = t; i < HWORDS; i += 256) dst[i] = h[i];
}

// pass 2: per bin-pair, exclusive prefix across chunks (in place) + total degree
__global__ __launch_bounds__(256) void merge_kernel(unsigned int* __restrict__ partial,
                                                    int* __restrict__ deg) {
    int w = blockIdx.x * 256 + threadIdx.x;
    if (w >= 25000) return;
    int hf = (w >= HWORDS) ? 1 : 0;
    int wi = w - hf * HWORDS;
    unsigned int run_lo = 0, run_hi = 0;
    for (int c = 0; c < NCHUNK; ++c) {
        size_t idx = ((size_t)(c * 2 + hf)) * HWORDS + wi;
        unsigned int u = partial[idx];
        partial[idx] = run_lo | (run_hi << 16);
        run_lo += u & 0xffffu;
        run_hi += u >> 16;
    }
    deg[2 * w]     = (int)run_lo;
    deg[2 * w + 1] = (int)run_hi;
}

// per-block sums of padded degrees
__global__ __launch_bounds__(256) void blocksum_kernel(const int* __restrict__ deg,
                                                       int* __restrict__ bsum) {
    int b = blockIdx.x, t = threadIdx.x;
    int i = b * 256 + t;
    int pd = (i < N_NODES) ? ((deg[i] + 7) & ~7) : 0;
    int lane = t & 63, w = t >> 6;
    int s = pd;
    #pragma unroll
    for (int o = 32; o >= 1; o >>= 1) s += __shfl_xor(s, o, 64);
    __shared__ int ws[4];
    if (lane == 0) ws[w] = s;
    __syncthreads();
    if (t == 0) bsum[b] = ws[0] + ws[1] + ws[2] + ws[3];
}

// single tiny block: exclusive scan bsum(196) -> bpre
__global__ __launch_bounds__(256) void scanb_kernel(const int* __restrict__ bsum,
                                                    int* __restrict__ bpre) {
    int t = threadIdx.x;
    int lane = t & 63, w = t >> 6;
    int x = (t < 196) ? bsum[t] : 0;
    int inc = x;
    #pragma unroll
    for (int o = 1; o < 64; o <<= 1) {
        int u = __shfl_up(inc, o, 64);
        if (lane >= o) inc += u;
    }
    __shared__ int wsA[4];
    if (lane == 63) wsA[w] = inc;
    __syncthreads();
    int base = 0;
    for (int k = 0; k < w; ++k) base += wsA[k];
    bpre[t] = base + inc - x;
}

// per-node padded offsets + dis
__global__ __launch_bounds__(256) void finalize_kernel(const int* __restrict__ deg,
                                                       const int* __restrict__ bpre,
                                                       int* __restrict__ offs,
                                                       float* __restrict__ dis) {
    int b = blockIdx.x, t = threadIdx.x;
    int i = b * 256 + t;
    int d = (i < N_NODES) ? deg[i] : 0;
    int pd = (d + 7) & ~7;
    int lane = t & 63, w = t >> 6;
    int inc = pd;
    #pragma unroll
    for (int o = 1; o < 64; o <<= 1) {
        int u = __shfl_up(inc, o, 64);
        if (lane >= o) inc += u;
    }
    __shared__ int ws[4];
    if (lane == 63) ws[w] = inc;
    __syncthreads();
    int base = 0;
    for (int k = 0; k < w; ++k) base += ws[k];
    int pre = base + inc - pd;
    if (i < N_NODES) {
        offs[i] = bpre[b] + pre;
        dis[i] = rsqrtf((float)d + 1.0f);
    }
    if (i == N_NODES - 1) offs[N_NODES] = bpre[b] + pre + pd;
}

// pass 3: counting-sort scatter (no global atomics); rec.x = src byte-offset (src<<9)
__global__ __launch_bounds__(256) void scatter2_kernel(const void* __restrict__ ei,
                                                       const int* __restrict__ flag,
                                                       const int* __restrict__ offs,
                                                       const float* __restrict__ dis,
                                                       const unsigned int* __restrict__ partial,
                                                       int2* __restrict__ csr) {
    __shared__ unsigned int cur[HWORDS];
    int c = blockIdx.x >> 1, hf = blockIdx.x & 1;
    int t = threadIdx.x;
    for (int i = t; i < HWORDS; i += 256) cur[i] = 0u;
    __syncthreads();
    bool is32 = (*flag != 0);
    const unsigned int* rel = partial + (size_t)blockIdx.x * HWORDS;
    int e0 = c * CHUNK;
    for (int k = 0; k < 25; ++k) {
        int e = e0 + t + k * 256;
        if (e < e0 + CHUNK) {
            int s, d;
            if (is32) {
                const int* p = (const int*)ei;
                s = p[e]; d = p[N_EDGES + e];
            } else {
                const long long* p = (const long long*)ei;
                s = (int)p[e]; d = (int)p[N_EDGES + e];
            }
            if (((d >= 25000) ? 1 : 0) == hf) {
                int w = (d - hf * 25000) >> 1;
                unsigned int old = atomicAdd(&cur[w], (d & 1) ? 0x10000u : 1u);
                unsigned int p0 = (d & 1) ? (old >> 16) : (old & 0xffffu);
                unsigned int rp = rel[w];
                unsigned int r = (d & 1) ? (rp >> 16) : (rp & 0xffffu);
                int pos = offs[d] + (int)r + (int)p0;
                int2 rec;
                rec.x = s << 9;                       // pre-multiplied byte offset into bf16 H
                rec.y = __float_as_int(dis[s] * dis[d]);
                csr[pos] = rec;
            }
        }
    }
}

// graph offsets from sorted batch via boundary detection (no atomics)
__global__ __launch_bounds__(256) void goffs_kernel(const void* __restrict__ bt,
                                                    const int* __restrict__ flag,
                                                    int* __restrict__ goffs) {
    int v = blockIdx.x * 256 + threadIdx.x;
    if (v >= N_NODES) return;
    bool is32 = (*flag != 0);
    int b = is32 ? ((const int*)bt)[v] : (int)((const long long*)bt)[v];
    if (v == 0) {
        for (int g = 0; g <= b; ++g) goffs[g] = 0;
    } else {
        int pb = is32 ? ((const int*)bt)[v - 1] : (int)((const long long*)bt)[v - 1];
        for (int g = pb + 1; g <= b; ++g) goffs[g] = v;
    }
    if (v == N_NODES - 1) {
        for (int g = b + 1; g <= NGRAPH; ++g) goffs[g] = N_NODES;
    }
}

// x -> bf16 (hi only) + transpose/split W1,W2,W3 into [N][K] bf16 pairs
#define XSPLIT_BLOCKS 6250
__global__ __launch_bounds__(256) void prep_w(const float* __restrict__ x,
                                              const float* __restrict__ W1,
                                              const float* __restrict__ W2,
                                              const float* __restrict__ W3,
                                              unsigned short* __restrict__ xh,
                                              unsigned short* __restrict__ wt) {
    int b = blockIdx.x;
    int t = threadIdx.x;
    if (b < XSPLIT_BLOCKS) {
        int i = b * 256 + t;
        float4 v = ((const float4*)x)[i];
        ushort4 h;
        h.x = f2b(v.x); h.y = f2b(v.y); h.z = f2b(v.z); h.w = f2b(v.w);
        ((ushort4*)xh)[i] = h;
    } else {
        int wb = b - XSPLIT_BLOCKS;
        const float* W; int K, k, bh, bl;
        if (wb < 128)      { W = W1; K = 128; k = wb;       bh = WT1H; bl = WT1L; }
        else if (wb < 384) { W = W2; K = 256; k = wb - 128; bh = WT2H; bl = WT2L; }
        else               { W = W3; K = 256; k = wb - 384; bh = WT3H; bl = WT3L; }
        int n = t;
        float val = W[k * HID + n];
        unsigned short hv = f2b(val);
        unsigned short lv = f2b(val - b2f(hv));
        wt[bh + n * K + k] = hv;
        wt[bl + n * K + k] = lv;
    }
}

// ---------------- bf16 MFMA GEMM: C = A @ (Bh+Bl)^T-stored; guard-free; C as bf16 ----------------
__global__ __launch_bounds__(256) void gemm_bf16(const unsigned short* __restrict__ A,
                                                 const unsigned short* __restrict__ Bh,
                                                 const unsigned short* __restrict__ Bl,
                                                 unsigned short* __restrict__ C,
                                                 int K) {
    __shared__ char lds[3 * 128 * 80];   // 30720 B: A, Bh, Bl tiles (128 rows x 64B, 80B pitch)
    int tid = threadIdx.x;
    int bm = blockIdx.x * 128;
    int bn = blockIdx.y * 128;
    int lane = tid & 63, wid = tid >> 6;
    int wm = wid >> 1, wn = wid & 1;
    int lr = lane & 15, lc = lane >> 4;
    f32x4 acc[4][4];
    #pragma unroll
    for (int i = 0; i < 4; ++i)
        #pragma unroll
        for (int j = 0; j < 4; ++j)
            acc[i][j] = (f32x4){0.f, 0.f, 0.f, 0.f};

    for (int k0 = 0; k0 < K; k0 += 32) {
        // stage 3 tiles; tile index compile-time per unrolled step
        #pragma unroll
        for (int c8 = 0; c8 < 6; ++c8) {
            const int tile = c8 >> 1;
            const unsigned short* __restrict__ src =
                (tile == 0) ? A : (tile == 1) ? Bh : Bl;
            int c = ((c8 & 1) << 8) + tid;
            int rr = c >> 2, q = c & 3;
            int row = ((tile == 0) ? bm : bn) + rr;
            u32x4 v = *(const u32x4*)(src + (size_t)row * K + k0 + q * 8);
            *(u32x4*)(lds + tile * 10240 + rr * 80 + q * 16) = v;
        }
        __syncthreads();
        bf16x8 af[4], bh[4], bl[4];
        #pragma unroll
        for (int f = 0; f < 4; ++f) {
            af[f] = *(const bf16x8*)(lds +             (wm * 64 + f * 16 + lr) * 80 + lc * 16);
            bh[f] = *(const bf16x8*)(lds + 10240     + (wn * 64 + f * 16 + lr) * 80 + lc * 16);
            bl[f] = *(const bf16x8*)(lds + 2 * 10240 + (wn * 64 + f * 16 + lr) * 80 + lc * 16);
        }
        #pragma unroll
        for (int fi = 0; fi < 4; ++fi) {
            #pragma unroll
            for (int fj = 0; fj < 4; ++fj) {
                acc[fi][fj] = __builtin_amdgcn_mfma_f32_16x16x32_bf16(af[fi], bh[fj], acc[fi][fj], 0, 0, 0);
                acc[fi][fj] = __builtin_amdgcn_mfma_f32_16x16x32_bf16(af[fi], bl[fj], acc[fi][fj], 0, 0, 0);
            }
        }
        __syncthreads();
    }
    #pragma unroll
    for (int fi = 0; fi < 4; ++fi) {
        int rbase = bm + wm * 64 + fi * 16 + lc * 4;
        #pragma unroll
        for (int fj = 0; fj < 4; ++fj) {
            int col = bn + wn * 64 + fj * 16 + lr;
            #pragma unroll
            for (int r = 0; r < 4; ++r) {
                C[(size_t)(rbase + r) * HID + col] = f2b(acc[fi][fj][r]);
            }
        }
    }
}

// ---------------- fused aggregation: bf16 H gather, 1 node/wave, 8-edge chunks, 2-deep pipeline ----
#define DECL_CH(P) int4 P##c0, P##c1, P##c2, P##c3; \
                   uint2 P##h0, P##h1, P##h2, P##h3, P##h4, P##h5, P##h6, P##h7;

#define LOAD8(P, idx) do { \
    const int4* _q = (const int4*)(csr + (idx)); \
    P##c0 = _q[0]; P##c1 = _q[1]; P##c2 = _q[2]; P##c3 = _q[3]; \
    P##h0 = *(const uint2*)(Hl + P##c0.x); \
    P##h1 = *(const uint2*)(Hl + P##c0.z); \
    P##h2 = *(const uint2*)(Hl + P##c1.x); \
    P##h3 = *(const uint2*)(Hl + P##c1.z); \
    P##h4 = *(const uint2*)(Hl + P##c2.x); \
    P##h5 = *(const uint2*)(Hl + P##c2.z); \
    P##h6 = *(const uint2*)(Hl + P##c3.x); \
    P##h7 = *(const uint2*)(Hl + P##c3.z); \
} while (0)

#define FMA4U(hv, wv, a) do { a += cvt4(hv) * (wv); } while (0)

#define CONS8(P, a) do { \
    FMA4U(P##h0, __int_as_float(P##c0.y), a); \
    FMA4U(P##h1, __int_as_float(P##c0.w), a); \
    FMA4U(P##h2, __int_as_float(P##c1.y), a); \
    FMA4U(P##h3, __int_as_float(P##c1.w), a); \
    FMA4U(P##h4, __int_as_float(P##c2.y), a); \
    FMA4U(P##h5, __int_as_float(P##c2.w), a); \
    FMA4U(P##h6, __int_as_float(P##c3.y), a); \
    FMA4U(P##h7, __int_as_float(P##c3.w), a); \
} while (0)

// MODE 0: +bias, ReLU, LayerNorm, write bf16 Z.  MODE 1: +bias, write f32 rows.
template <int MODE>
__global__ __launch_bounds__(256) void agg_kernel(const unsigned short* __restrict__ H,
                                                  const float* __restrict__ dis,
                                                  const int* __restrict__ offs,
                                                  const int2* __restrict__ csr,
                                                  const float* __restrict__ bias,
                                                  const float* __restrict__ gamma,
                                                  const float* __restrict__ beta,
                                                  unsigned short* __restrict__ Z,
                                                  float* __restrict__ O) {
    int v = blockIdx.x * 4 + (threadIdx.x >> 6);
    int l = threadIdx.x & 63;
    const char* Hl = (const char*)H + l * 8;   // lane-fixed byte base

    float dv = dis[v];
    uint2 a0u = ((const uint2*)(H + (size_t)v * HID))[l];
    f32x4 acc = cvt4(a0u) * (dv * dv);

    int i = offs[v];
    int n = (offs[v + 1] - i) >> 3;   // padded chunk count
    DECL_CH(A)
    DECL_CH(B)
    if (n > 0) LOAD8(A, i);
    if (n > 1) LOAD8(B, i + 8);
    int c = 0;
    // steady state: consume chunk c, prefetch chunk c+2 into the freed register set
    while (c + 2 < n) {
        if ((c & 1) == 0) { CONS8(A, acc); LOAD8(A, i + 16); }
        else              { CONS8(B, acc); LOAD8(B, i + 16); }
        i += 8; ++c;
    }
    if (c < n) {
        if ((c & 1) == 0) CONS8(A, acc); else CONS8(B, acc);
        ++c;
    }
    if (c < n) {
        if ((c & 1) == 0) CONS8(A, acc); else CONS8(B, acc);
    }

    f32x4 b4 = *(const f32x4*)(bias + l * 4);
    if (MODE == 0) {
        acc += b4;
        acc[0] = fmaxf(acc[0], 0.f); acc[1] = fmaxf(acc[1], 0.f);
        acc[2] = fmaxf(acc[2], 0.f); acc[3] = fmaxf(acc[3], 0.f);
        float s = acc[0] + acc[1] + acc[2] + acc[3];
        #pragma unroll
        for (int o = 32; o >= 1; o >>= 1) s += __shfl_xor(s, o, 64);
        float mu = s * (1.0f / HID);
        f32x4 d = acc - mu;
        float vs = d[0] * d[0] + d[1] * d[1] + d[2] * d[2] + d[3] * d[3];
        #pragma unroll
        for (int o = 32; o >= 1; o >>= 1) vs += __shfl_xor(vs, o, 64);
        float inv = rsqrtf(vs * (1.0f / HID) + LN_EPS);
        f32x4 g4 = *(const f32x4*)(gamma + l * 4);
        f32x4 be4 = *(const f32x4*)(beta + l * 4);
        ushort4 zh;
        zh.x = f2b(d[0] * inv * g4[0] + be4[0]);
        zh.y = f2b(d[1] * inv * g4[1] + be4[1]);
        zh.z = f2b(d[2] * inv * g4[2] + be4[2]);
        zh.w = f2b(d[3] * inv * g4[3] + be4[3]);
        *(ushort4*)(Z + (size_t)v * HID + l * 4) = zh;
    } else {
        acc += b4;
        *(f32x4*)(O + (size_t)v * HID + l * 4) = acc;
    }
}

// ---------------- per-graph segment-mean pool (batch is sorted) ----------------
__global__ __launch_bounds__(256) void pool_kernel(const float* __restrict__ O,
                                                   const int* __restrict__ goffs,
                                                   float* __restrict__ out) {
    int g = blockIdx.x, t = threadIdx.x;
    int l = t & 63, w = t >> 6;
    int s = goffs[g], e = goffs[g + 1];
    float4 acc = make_float4(0.f, 0.f, 0.f, 0.f);
    for (int v = s + w; v < e; v += 4) {
        float4 r = ((const float4*)(O + (size_t)v * HID))[l];
        acc.x += r.x; acc.y += r.y; acc.z += r.z; acc.w += r.w;
    }
    __shared__ float4 red[4][64];
    red[w][l] = acc;
    __syncthreads();
    if (w == 0) {
        float4 r0 = red[0][l], r1 = red[1][l], r2 = red[2][l], r3 = red[3][l];
        float inv = 1.0f / (float)(e - s);
        float4 o;
        o.x = (r0.x + r1.x + r2.x + r3.x) * inv;
        o.y = (r0.y + r1.y + r2.y + r3.y) * inv;
        o.z = (r0.z + r1.z + r2.z + r3.z) * inv;
        o.w = (r0.w + r1.w + r2.w + r3.w) * inv;
        ((float4*)(out + (size_t)g * HID))[l] = o;
    }
}

// ---------------- launch ----------------
extern "C" void kernel_launch(void* const* d_in, const int* in_sizes, int n_in,
                              void* d_out, int out_size, void* d_ws, size_t ws_size,
                              hipStream_t stream) {
    const float* x   = (const float*)d_in[0];
    const float* W1  = (const float*)d_in[1];
    const float* b1  = (const float*)d_in[2];
    const float* g1  = (const float*)d_in[3];
    const float* be1 = (const float*)d_in[4];
    const float* W2  = (const float*)d_in[5];
    const float* b2  = (const float*)d_in[6];
    const float* g2  = (const float*)d_in[7];
    const float* be2 = (const float*)d_in[8];
    const float* W3  = (const float*)d_in[9];
    const float* b3  = (const float*)d_in[10];
    const void*  ei  = d_in[11];
    const void*  bt  = d_in[12];
    float* out = (float*)d_out;

    unsigned int* ws = (unsigned int*)d_ws;
    int*   deg    = (int*)(ws + W_DEG);
    int*   flag   = (int*)(ws + W_FLAG);
    int*   bsum   = (int*)(ws + W_BSUM);
    int*   bpre   = (int*)(ws + W_BPRE);
    int*   goffs  = (int*)(ws + W_GOFF);
    int*   offs   = (int*)(ws + W_OFFS);
    float* dis    = (float*)(ws + W_DIS);
    int2*  csr    = (int2*)(ws + W_CSR);
    unsigned short* wt = (unsigned short*)(ws + W_WT);
    unsigned short* Zbuf = (unsigned short*)(ws + W_ZH);
    unsigned short* xh = Zbuf;          // overlay: x-bf16 dead after gemm1
    unsigned short* Hbuf = (unsigned short*)(ws + W_H);       // bf16 H (MROWS rows)
    unsigned int*   partial = (unsigned int*)(ws + W_H);      // overlay: sort partials dead after scatter2
    float* Obuf = (float*)(ws + W_ZH);  // overlay: Z dead after gemm3 (spans W_ZH+W_ZL)

    const int EB = (N_EDGES + 255) / 256;
    const int NB = (N_NODES + 255) / 256;  // 196

    zero_kernel<<<1, 256, 0, stream>>>(ws + W_FLAG, 16);
    zero_kernel<<<(2 * PAD_E + 255) / 256, 256, 0, stream>>>(ws + W_CSR, 2 * PAD_E);
    detect_kernel<<<EB, 256, 0, stream>>>((const unsigned int*)ei, flag);
    hist_kernel<<<2 * NCHUNK, 256, 0, stream>>>(ei, flag, partial);
    merge_kernel<<<(25000 + 255) / 256, 256, 0, stream>>>(partial, deg);
    blocksum_kernel<<<NB, 256, 0, stream>>>(deg, bsum);
    scanb_kernel<<<1, 256, 0, stream>>>(bsum, bpre);
    finalize_kernel<<<NB, 256, 0, stream>>>(deg, bpre, offs, dis);
    scatter2_kernel<<<2 * NCHUNK, 256, 0, stream>>>(ei, flag, offs, dis, partial, csr);
    goffs_kernel<<<NB, 256, 0, stream>>>(bt, flag, goffs);
    prep_w<<<XSPLIT_BLOCKS + 640, 256, 0, stream>>>(x, W1, W2, W3, xh, wt);

    dim3 gg(MROWS / 128, HID / 128);     // (391, 2), guard-free
    const int AB = N_NODES / 4;          // 12500 blocks = 50000 waves = 1 node/wave

    gemm_bf16<<<gg, 256, 0, stream>>>(xh, wt + WT1H, wt + WT1L, Hbuf, IN_DIM);
    agg_kernel<0><<<AB, 256, 0, stream>>>(Hbuf, dis, offs, csr, b1, g1, be1, Zbuf, nullptr);
    gemm_bf16<<<gg, 256, 0, stream>>>(Zbuf, wt + WT2H, wt + WT2L, Hbuf, HID);
    agg_kernel<0><<<AB, 256, 0, stream>>>(Hbuf, dis, offs, csr, b2, g2, be2, Zbuf, nullptr);
    gemm_bf16<<<gg, 256, 0, stream>>>(Zbuf, wt + WT3H, wt + WT3L, Hbuf, HID);
    agg_kernel<1><<<AB, 256, 0, stream>>>(Hbuf, dis, offs, csr, b3, nullptr, nullptr, nullptr, Obuf);
    pool_kernel<<<NGRAPH, 256, 0, stream>>>(Obuf, goffs, out);
}

// Round 9
// 384.515 us; speedup vs baseline: 2.7879x; 1.0489x over previous
//
#include <hip/hip_runtime.h>

#define N_NODES 50000
#define MROWS   50048   // N_NODES padded to 128 (391 * 128) - GEMM runs guard-free
#define N_EDGES 800000
#define IN_DIM  128
#define HID     256
#define NGRAPH  256
#define LN_EPS  1e-5f

typedef __attribute__((ext_vector_type(8))) short bf16x8;
typedef __attribute__((ext_vector_type(4))) float f32x4;
typedef __attribute__((ext_vector_type(4))) unsigned int u32x4;

// counting-sort geometry: 128 chunks x 6250 edges; bins split in 2 halves of 25000
#define NCHUNK  128
#define CHUNK   6250
#define HWORDS  12500   // packed u32 words per half (2 bins/word)

// padded CSR capacity (pad each node's edge list to a multiple of 4; max +3/node)
#define PAD_E (N_EDGES + 3 * N_NODES)

// ---------------- workspace layout (32-bit word offsets) ----------------
#define W_DEG      0
#define W_FLAG     (W_DEG + N_NODES)
#define W_BSUM     (W_FLAG + 16)
#define W_BPRE     (W_BSUM + 256)
#define W_GOFF     (W_BPRE + 256)
#define W_OFFS     (W_GOFF + NGRAPH + 8)
#define W_DIS      (W_OFFS + N_NODES + 8)
#define W_CSR      (((W_DIS + N_NODES) + 3) & ~3)
#define W_WT       (W_CSR + 2 * PAD_E)
#define W_ZH       (((W_WT + 163840) + 3) & ~3)
#define W_ZL       (W_ZH + (MROWS * HID / 2))       // spill space for f32 Obuf overlay
#define W_H        (W_ZL + (MROWS * HID / 2))       // bf16 H (overlaid by sort partials pre-gemm1)

// Wt sub-offsets in ushorts within W_WT
#define WT1H 0
#define WT1L 32768
#define WT2H 65536
#define WT2L 131072
#define WT3H 196608
#define WT3L 262144

__device__ __forceinline__ unsigned short f2b(float f) {
    unsigned int u = __float_as_uint(f);
    unsigned int r = (u + 0x7FFFu + ((u >> 16) & 1u)) >> 16;
    return (unsigned short)r;
}
__device__ __forceinline__ float b2f(unsigned short h) {
    return __uint_as_float(((unsigned int)h) << 16);
}
// 4 bf16 (packed in uint2) -> f32x4  (and/shl pair decode, 4 inst)
__device__ __forceinline__ f32x4 cvt4(uint2 u) {
    f32x4 r;
    r[0] = __uint_as_float(u.x << 16);
    r[1] = __uint_as_float(u.x & 0xffff0000u);
    r[2] = __uint_as_float(u.y << 16);
    r[3] = __uint_as_float(u.y & 0xffff0000u);
    return r;
}

// ---------------- prep kernels ----------------
__global__ __launch_bounds__(256) void zero_kernel(unsigned int* __restrict__ p, int n) {
    int i = blockIdx.x * 256 + threadIdx.x;
    if (i < n) p[i] = 0u;
}

__global__ __launch_bounds__(256) void detect_kernel(const unsigned int* __restrict__ ei,
                                                     int* __restrict__ flag) {
    int e = blockIdx.x * 256 + threadIdx.x;
    if (e >= N_EDGES) return;
    if (ei[2 * e + 1] != 0u) *flag = 1;
}

// pass 1: per-(chunk,half) LDS histogram, packed 2x16-bit counts per word
__global__ __launch_bounds__(256) void hist_kernel(const void* __restrict__ ei,
                                                   const int* __restrict__ flag,
                                                   unsigned int* __restrict__ partial) {
    __shared__ unsigned int h[HWORDS];
    int c = blockIdx.x >> 1, hf = blockIdx.x & 1;
    int t = threadIdx.x;
    for (int i = t; i < HWORDS; i += 256) h[i] = 0u;
    __syncthreads();
    bool is32 = (*flag != 0);
    int e0 = c * CHUNK;
    for (int k = 0; k < 25; ++k) {
        int e = e0 + t + k * 256;
        if (e < e0 + CHUNK) {
            int d = is32 ? ((const int*)ei)[N_EDGES + e]
                         : (int)((const long long*)ei)[N_EDGES + e];
            if (((d >= 25000) ? 1 : 0) == hf) {
                int w = (d - hf * 25000) >> 1;
                atomicAdd(&h[w], (d & 1) ? 0x10000u : 1u);
            }
        }
    }
    __syncthreads();
    unsigned int* dst = partial + (size_t)blockIdx.x * HWORDS;
    for (int i = t; i < HWORDS; i += 256) dst[i] = h[i];
}

// pass 2: per bin-pair, exclusive prefix across chunks (in place) + total degree
__global__ __launch_bounds__(256) void merge_kernel(unsigned int* __restrict__ partial,
                                                    int* __restrict__ deg) {
    int w = blockIdx.x * 256 + threadIdx.x;
    if (w >= 25000) return;
    int hf = (w >= HWORDS) ? 1 : 0;
    int wi = w - hf * HWORDS;
    unsigned int run_lo = 0, run_hi = 0;
    for (int c = 0; c < NCHUNK; ++c) {
        size_t idx = ((size_t)(c * 2 + hf)) * HWORDS + wi;
        unsigned int u = partial[idx];
        partial[idx] = run_lo | (run_hi << 16);
        run_lo += u & 0xffffu;
        run_hi += u >> 16;
    }
    deg[2 * w]     = (int)run_lo;
    deg[2 * w + 1] = (int)run_hi;
}

// per-block sums of padded degrees (pad to 4)
__global__ __launch_bounds__(256) void blocksum_kernel(const int* __restrict__ deg,
                                                       int* __restrict__ bsum) {
    int b = blockIdx.x, t = threadIdx.x;
    int i = b * 256 + t;
    int pd = (i < N_NODES) ? ((deg[i] + 3) & ~3) : 0;
    int lane = t & 63, w = t >> 6;
    int s = pd;
    #pragma unroll
    for (int o = 32; o >= 1; o >>= 1) s += __shfl_xor(s, o, 64);
    __shared__ int ws[4];
    if (lane == 0) ws[w] = s;
    __syncthreads();
    if (t == 0) bsum[b] = ws[0] + ws[1] + ws[2] + ws[3];
}

// single tiny block: exclusive scan bsum(196) -> bpre
__global__ __launch_bounds__(256) void scanb_kernel(const int* __restrict__ bsum,
                                                    int* __restrict__ bpre) {
    int t = threadIdx.x;
    int lane = t & 63, w = t >> 6;
    int x = (t < 196) ? bsum[t] : 0;
    int inc = x;
    #pragma unroll
    for (int o = 1; o < 64; o <<= 1) {
        int u = __shfl_up(inc, o, 64);
        if (lane >= o) inc += u;
    }
    __shared__ int wsA[4];
    if (lane == 63) wsA[w] = inc;
    __syncthreads();
    int base = 0;
    for (int k = 0; k < w; ++k) base += wsA[k];
    bpre[t] = base + inc - x;
}

// per-node padded offsets + dis (pad to 4)
__global__ __launch_bounds__(256) void finalize_kernel(const int* __restrict__ deg,
                                                       const int* __restrict__ bpre,
                                                       int* __restrict__ offs,
                                                       float* __restrict__ dis) {
    int b = blockIdx.x, t = threadIdx.x;
    int i = b * 256 + t;
    int d = (i < N_NODES) ? deg[i] : 0;
    int pd = (d + 3) & ~3;
    int lane = t & 63, w = t >> 6;
    int inc = pd;
    #pragma unroll
    for (int o = 1; o < 64; o <<= 1) {
        int u = __shfl_up(inc, o, 64);
        if (lane >= o) inc += u;
    }
    __shared__ int ws[4];
    if (lane == 63) ws[w] = inc;
    __syncthreads();
    int base = 0;
    for (int k = 0; k < w; ++k) base += ws[k];
    int pre = base + inc - pd;
    if (i < N_NODES) {
        offs[i] = bpre[b] + pre;
        dis[i] = rsqrtf((float)d + 1.0f);
    }
    if (i == N_NODES - 1) offs[N_NODES] = bpre[b] + pre + pd;
}

// zero only the pad slots [offs+deg, offs+paddeg) - replaces the 26 MB full-CSR zero
__global__ __launch_bounds__(256) void padzero_kernel(const int* __restrict__ deg,
                                                      const int* __restrict__ offs,
                                                      int2* __restrict__ csr) {
    int v = blockIdx.x * 256 + threadIdx.x;
    if (v >= N_NODES) return;
    int d = deg[v];
    int e = offs[v] + d;
    int pe = offs[v] + ((d + 3) & ~3);
    int2 z; z.x = 0; z.y = 0;
    for (; e < pe; ++e) csr[e] = z;
}

// pass 3: counting-sort scatter (no global atomics); rec.x = src byte-offset (src<<9)
__global__ __launch_bounds__(256) void scatter2_kernel(const void* __restrict__ ei,
                                                       const int* __restrict__ flag,
                                                       const int* __restrict__ offs,
                                                       const float* __restrict__ dis,
                                                       const unsigned int* __restrict__ partial,
                                                       int2* __restrict__ csr) {
    __shared__ unsigned int cur[HWORDS];
    int c = blockIdx.x >> 1, hf = blockIdx.x & 1;
    int t = threadIdx.x;
    for (int i = t; i < HWORDS; i += 256) cur[i] = 0u;
    __syncthreads();
    bool is32 = (*flag != 0);
    const unsigned int* rel = partial + (size_t)blockIdx.x * HWORDS;
    int e0 = c * CHUNK;
    for (int k = 0; k < 25; ++k) {
        int e = e0 + t + k * 256;
        if (e < e0 + CHUNK) {
            int s, d;
            if (is32) {
                const int* p = (const int*)ei;
                s = p[e]; d = p[N_EDGES + e];
            } else {
                const long long* p = (const long long*)ei;
                s = (int)p[e]; d = (int)p[N_EDGES + e];
            }
            if (((d >= 25000) ? 1 : 0) == hf) {
                int w = (d - hf * 25000) >> 1;
                unsigned int old = atomicAdd(&cur[w], (d & 1) ? 0x10000u : 1u);
                unsigned int p0 = (d & 1) ? (old >> 16) : (old & 0xffffu);
                unsigned int rp = rel[w];
                unsigned int r = (d & 1) ? (rp >> 16) : (rp & 0xffffu);
                int pos = offs[d] + (int)r + (int)p0;
                int2 rec;
                rec.x = s << 9;                       // pre-multiplied byte offset into bf16 H
                rec.y = __float_as_int(dis[s] * dis[d]);
                csr[pos] = rec;
            }
        }
    }
}

// graph offsets from sorted batch via boundary detection (no atomics)
__global__ __launch_bounds__(256) void goffs_kernel(const void* __restrict__ bt,
                                                    const int* __restrict__ flag,
                                                    int* __restrict__ goffs) {
    int v = blockIdx.x * 256 + threadIdx.x;
    if (v >= N_NODES) return;
    bool is32 = (*flag != 0);
    int b = is32 ? ((const int*)bt)[v] : (int)((const long long*)bt)[v];
    if (v == 0) {
        for (int g = 0; g <= b; ++g) goffs[g] = 0;
    } else {
        int pb = is32 ? ((const int*)bt)[v - 1] : (int)((const long long*)bt)[v - 1];
        for (int g = pb + 1; g <= b; ++g) goffs[g] = v;
    }
    if (v == N_NODES - 1) {
        for (int g = b + 1; g <= NGRAPH; ++g) goffs[g] = N_NODES;
    }
}

// x -> bf16 (hi only) + transpose/split W1,W2,W3 into [N][K] bf16 pairs
#define XSPLIT_BLOCKS 6250
__global__ __launch_bounds__(256) void prep_w(const float* __restrict__ x,
                                              const float* __restrict__ W1,
                                              const float* __restrict__ W2,
                                              const float* __restrict__ W3,
                                              unsigned short* __restrict__ xh,
                                              unsigned short* __restrict__ wt) {
    int b = blockIdx.x;
    int t = threadIdx.x;
    if (b < XSPLIT_BLOCKS) {
        int i = b * 256 + t;
        float4 v = ((const float4*)x)[i];
        ushort4 h;
        h.x = f2b(v.x); h.y = f2b(v.y); h.z = f2b(v.z); h.w = f2b(v.w);
        ((ushort4*)xh)[i] = h;
    } else {
        int wb = b - XSPLIT_BLOCKS;
        const float* W; int K, k, bh, bl;
        if (wb < 128)      { W = W1; K = 128; k = wb;       bh = WT1H; bl = WT1L; }
        else if (wb < 384) { W = W2; K = 256; k = wb - 128; bh = WT2H; bl = WT2L; }
        else               { W = W3; K = 256; k = wb - 384; bh = WT3H; bl = WT3L; }
        int n = t;
        float val = W[k * HID + n];
        unsigned short hv = f2b(val);
        unsigned short lv = f2b(val - b2f(hv));
        wt[bh + n * K + k] = hv;
        wt[bl + n * K + k] = lv;
    }
}

// ---------------- bf16 MFMA GEMM: C = A @ (Bh+Bl)^T-stored; guard-free; C as bf16 ----------------
__global__ __launch_bounds__(256) void gemm_bf16(const unsigned short* __restrict__ A,
                                                 const unsigned short* __restrict__ Bh,
                                                 const unsigned short* __restrict__ Bl,
                                                 unsigned short* __restrict__ C,
                                                 int K) {
    __shared__ char lds[3 * 128 * 80];   // 30720 B: A, Bh, Bl tiles (128 rows x 64B, 80B pitch)
    int tid = threadIdx.x;
    int bm = blockIdx.x * 128;
    int bn = blockIdx.y * 128;
    int lane = tid & 63, wid = tid >> 6;
    int wm = wid >> 1, wn = wid & 1;
    int lr = lane & 15, lc = lane >> 4;
    f32x4 acc[4][4];
    #pragma unroll
    for (int i = 0; i < 4; ++i)
        #pragma unroll
        for (int j = 0; j < 4; ++j)
            acc[i][j] = (f32x4){0.f, 0.f, 0.f, 0.f};

    for (int k0 = 0; k0 < K; k0 += 32) {
        // stage 3 tiles; tile index compile-time per unrolled step
        #pragma unroll
        for (int c8 = 0; c8 < 6; ++c8) {
            const int tile = c8 >> 1;
            const unsigned short* __restrict__ src =
                (tile == 0) ? A : (tile == 1) ? Bh : Bl;
            int c = ((c8 & 1) << 8) + tid;
            int rr = c >> 2, q = c & 3;
            int row = ((tile == 0) ? bm : bn) + rr;
            u32x4 v = *(const u32x4*)(src + (size_t)row * K + k0 + q * 8);
            *(u32x4*)(lds + tile * 10240 + rr * 80 + q * 16) = v;
        }
        __syncthreads();
        bf16x8 af[4], bh[4], bl[4];
        #pragma unroll
        for (int f = 0; f < 4; ++f) {
            af[f] = *(const bf16x8*)(lds +             (wm * 64 + f * 16 + lr) * 80 + lc * 16);
            bh[f] = *(const bf16x8*)(lds + 10240     + (wn * 64 + f * 16 + lr) * 80 + lc * 16);
            bl[f] = *(const bf16x8*)(lds + 2 * 10240 + (wn * 64 + f * 16 + lr) * 80 + lc * 16);
        }
        #pragma unroll
        for (int fi = 0; fi < 4; ++fi) {
            #pragma unroll
            for (int fj = 0; fj < 4; ++fj) {
                acc[fi][fj] = __builtin_amdgcn_mfma_f32_16x16x32_bf16(af[fi], bh[fj], acc[fi][fj], 0, 0, 0);
                acc[fi][fj] = __builtin_amdgcn_mfma_f32_16x16x32_bf16(af[fi], bl[fj], acc[fi][fj], 0, 0, 0);
            }
        }
        __syncthreads();
    }
    #pragma unroll
    for (int fi = 0; fi < 4; ++fi) {
        int rbase = bm + wm * 64 + fi * 16 + lc * 4;
        #pragma unroll
        for (int fj = 0; fj < 4; ++fj) {
            int col = bn + wn * 64 + fj * 16 + lr;
            #pragma unroll
            for (int r = 0; r < 4; ++r) {
                C[(size_t)(rbase + r) * HID + col] = f2b(acc[fi][fj][r]);
            }
        }
    }
}

// ---------------- fused aggregation: 1 node/wave, 4-edge chunks, 3-deep pipeline ----------------
#define DECL_C4(P) int4 P##c0, P##c1; uint2 P##h0, P##h1, P##h2, P##h3;

#define LOAD4(P, idx) do { \
    const int4* _q = (const int4*)(csr + (idx)); \
    P##c0 = _q[0]; P##c1 = _q[1]; \
    P##h0 = *(const uint2*)(Hl + P##c0.x); \
    P##h1 = *(const uint2*)(Hl + P##c0.z); \
    P##h2 = *(const uint2*)(Hl + P##c1.x); \
    P##h3 = *(const uint2*)(Hl + P##c1.z); \
} while (0)

#define FMA4U(hv, wv, a) do { a += cvt4(hv) * (wv); } while (0)

#define CONS4(P, a) do { \
    FMA4U(P##h0, __int_as_float(P##c0.y), a); \
    FMA4U(P##h1, __int_as_float(P##c0.w), a); \
    FMA4U(P##h2, __int_as_float(P##c1.y), a); \
    FMA4U(P##h3, __int_as_float(P##c1.w), a); \
} while (0)

// MODE 0: +bias, ReLU, LayerNorm, write bf16 Z.  MODE 1: +bias, write f32 rows.
template <int MODE>
__global__ __launch_bounds__(256) void agg_kernel(const unsigned short* __restrict__ H,
                                                  const float* __restrict__ dis,
                                                  const int* __restrict__ offs,
                                                  const int2* __restrict__ csr,
                                                  const float* __restrict__ bias,
                                                  const float* __restrict__ gamma,
                                                  const float* __restrict__ beta,
                                                  unsigned short* __restrict__ Z,
                                                  float* __restrict__ O) {
    int v = blockIdx.x * 4 + (threadIdx.x >> 6);
    int l = threadIdx.x & 63;
    const char* Hl = (const char*)H + l * 8;   // lane-fixed byte base

    float dv = dis[v];
    uint2 a0u = ((const uint2*)(H + (size_t)v * HID))[l];
    f32x4 acc = cvt4(a0u) * (dv * dv);

    int i = offs[v];
    int n = (offs[v + 1] - i) >> 2;   // padded 4-edge chunk count
    DECL_C4(A)
    DECL_C4(B)
    DECL_C4(C)
    if (n > 0) LOAD4(A, i);
    if (n > 1) LOAD4(B, i + 4);
    if (n > 2) LOAD4(C, i + 8);
    int c = 0;
    // steady state: always 2 chunks in flight behind the one being consumed
    while (c + 6 <= n) {
        CONS4(A, acc); LOAD4(A, i + 12);
        CONS4(B, acc); LOAD4(B, i + 16);
        CONS4(C, acc); LOAD4(C, i + 20);
        i += 12; c += 3;
    }
    // tail: r in [0..5]; buffers hold chunks c, c+1, c+2 (those < n)
    int r = n - c;
    if (r >= 1) { CONS4(A, acc); if (r >= 4) LOAD4(A, i + 12); }
    if (r >= 2) { CONS4(B, acc); if (r >= 5) LOAD4(B, i + 16); }
    if (r >= 3) CONS4(C, acc);
    if (r >= 4) CONS4(A, acc);
    if (r >= 5) CONS4(B, acc);

    f32x4 b4 = *(const f32x4*)(bias + l * 4);
    if (MODE == 0) {
        acc += b4;
        acc[0] = fmaxf(acc[0], 0.f); acc[1] = fmaxf(acc[1], 0.f);
        acc[2] = fmaxf(acc[2], 0.f); acc[3] = fmaxf(acc[3], 0.f);
        float s = acc[0] + acc[1] + acc[2] + acc[3];
        #pragma unroll
        for (int o = 32; o >= 1; o >>= 1) s += __shfl_xor(s, o, 64);
        float mu = s * (1.0f / HID);
        f32x4 d = acc - mu;
        float vs = d[0] * d[0] + d[1] * d[1] + d[2] * d[2] + d[3] * d[3];
        #pragma unroll
        for (int o = 32; o >= 1; o >>= 1) vs += __shfl_xor(vs, o, 64);
        float inv = rsqrtf(vs * (1.0f / HID) + LN_EPS);
        f32x4 g4 = *(const f32x4*)(gamma + l * 4);
        f32x4 be4 = *(const f32x4*)(beta + l * 4);
        ushort4 zh;
        zh.x = f2b(d[0] * inv * g4[0] + be4[0]);
        zh.y = f2b(d[1] * inv * g4[1] + be4[1]);
        zh.z = f2b(d[2] * inv * g4[2] + be4[2]);
        zh.w = f2b(d[3] * inv * g4[3] + be4[3]);
        *(ushort4*)(Z + (size_t)v * HID + l * 4) = zh;
    } else {
        acc += b4;
        *(f32x4*)(O + (size_t)v * HID + l * 4) = acc;
    }
}

// ---------------- per-graph segment-mean pool (batch is sorted) ----------------
__global__ __launch_bounds__(256) void pool_kernel(const float* __restrict__ O,
                                                   const int* __restrict__ goffs,
                                                   float* __restrict__ out) {
    int g = blockIdx.x, t = threadIdx.x;
    int l = t & 63, w = t >> 6;
    int s = goffs[g], e = goffs[g + 1];
    float4 acc = make_float4(0.f, 0.f, 0.f, 0.f);
    for (int v = s + w; v < e; v += 4) {
        float4 r = ((const float4*)(O + (size_t)v * HID))[l];
        acc.x += r.x; acc.y += r.y; acc.z += r.z; acc.w += r.w;
    }
    __shared__ float4 red[4][64];
    red[w][l] = acc;
    __syncthreads();
    if (w == 0) {
        float4 r0 = red[0][l], r1 = red[1][l], r2 = red[2][l], r3 = red[3][l];
        float inv = 1.0f / (float)(e - s);
        float4 o;
        o.x = (r0.x + r1.x + r2.x + r3.x) * inv;
        o.y = (r0.y + r1.y + r2.y + r3.y) * inv;
        o.z = (r0.z + r1.z + r2.z + r3.z) * inv;
        o.w = (r0.w + r1.w + r2.w + r3.w) * inv;
        ((float4*)(out + (size_t)g * HID))[l] = o;
    }
}

// ---------------- launch ----------------
extern "C" void kernel_launch(void* const* d_in, const int* in_sizes, int n_in,
                              void* d_out, int out_size, void* d_ws, size_t ws_size,
                              hipStream_t stream) {
    const float* x   = (const float*)d_in[0];
    const float* W1  = (const float*)d_in[1];
    const float* b1  = (const float*)d_in[2];
    const float* g1  = (const float*)d_in[3];
    const float* be1 = (const float*)d_in[4];
    const float* W2  = (const float*)d_in[5];
    const float* b2  = (const float*)d_in[6];
    const float* g2  = (const float*)d_in[7];
    const float* be2 = (const float*)d_in[8];
    const float* W3  = (const float*)d_in[9];
    const float* b3  = (const float*)d_in[10];
    const void*  ei  = d_in[11];
    const void*  bt  = d_in[12];
    float* out = (float*)d_out;

    unsigned int* ws = (unsigned int*)d_ws;
    int*   deg    = (int*)(ws + W_DEG);
    int*   flag   = (int*)(ws + W_FLAG);
    int*   bsum   = (int*)(ws + W_BSUM);
    int*   bpre   = (int*)(ws + W_BPRE);
    int*   goffs  = (int*)(ws + W_GOFF);
    int*   offs   = (int*)(ws + W_OFFS);
    float* dis    = (float*)(ws + W_DIS);
    int2*  csr    = (int2*)(ws + W_CSR);
    unsigned short* wt = (unsigned short*)(ws + W_WT);
    unsigned short* Zbuf = (unsigned short*)(ws + W_ZH);
    unsigned short* xh = Zbuf;          // overlay: x-bf16 dead after gemm1
    unsigned short* Hbuf = (unsigned short*)(ws + W_H);       // bf16 H (MROWS rows)
    unsigned int*   partial = (unsigned int*)(ws + W_H);      // overlay: sort partials dead after scatter2
    float* Obuf = (float*)(ws + W_ZH);  // overlay: Z dead after gemm3 (spans W_ZH+W_ZL)

    const int EB = (N_EDGES + 255) / 256;
    const int NB = (N_NODES + 255) / 256;  // 196

    zero_kernel<<<1, 256, 0, stream>>>(ws + W_FLAG, 16);
    detect_kernel<<<EB, 256, 0, stream>>>((const unsigned int*)ei, flag);
    hist_kernel<<<2 * NCHUNK, 256, 0, stream>>>(ei, flag, partial);
    merge_kernel<<<(25000 + 255) / 256, 256, 0, stream>>>(partial, deg);
    blocksum_kernel<<<NB, 256, 0, stream>>>(deg, bsum);
    scanb_kernel<<<1, 256, 0, stream>>>(bsum, bpre);
    finalize_kernel<<<NB, 256, 0, stream>>>(deg, bpre, offs, dis);
    padzero_kernel<<<NB, 256, 0, stream>>>(deg, offs, csr);
    scatter2_kernel<<<2 * NCHUNK, 256, 0, stream>>>(ei, flag, offs, dis, partial, csr);
    goffs_kernel<<<NB, 256, 0, stream>>>(bt, flag, goffs);
    prep_w<<<XSPLIT_BLOCKS + 640, 256, 0, stream>>>(x, W1, W2, W3, xh, wt);

    dim3 gg(MROWS / 128, HID / 128);     // (391, 2), guard-free
    const int AB = N_NODES / 4;          // 12500 blocks = 50000 waves = 1 node/wave

    gemm_bf16<<<gg, 256, 0, stream>>>(xh, wt + WT1H, wt + WT1L, Hbuf, IN_DIM);
    agg_kernel<0><<<AB, 256, 0, stream>>>(Hbuf, dis, offs, csr, b1, g1, be1, Zbuf, nullptr);
    gemm_bf16<<<gg, 256, 0, stream>>>(Zbuf, wt + WT2H, wt + WT2L, Hbuf, HID);
    agg_kernel<0><<<AB, 256, 0, stream>>>(Hbuf, dis, offs, csr, b2, g2, be2, Zbuf, nullptr);
    gemm_bf16<<<gg, 256, 0, stream>>>(Zbuf, wt + WT3H, wt + WT3L, Hbuf, HID);
    agg_kernel<1><<<AB, 256, 0, stream>>>(Hbuf, dis, offs, csr, b3, nullptr, nullptr, nullptr, Obuf);
    pool_kernel<<<NGRAPH, 256, 0, stream>>>(Obuf, goffs, out);
}

// Round 10
// 366.891 us; speedup vs baseline: 2.9219x; 1.0480x over previous
//
#include <hip/hip_runtime.h>

#define N_NODES 50000
#define MROWS   50048   // N_NODES padded to 128 (391 * 128) - GEMM runs guard-free
#define N_EDGES 800000
#define IN_DIM  128
#define HID     256
#define NGRAPH  256
#define LN_EPS  1e-5f

typedef __attribute__((ext_vector_type(8))) short bf16x8;
typedef __attribute__((ext_vector_type(4))) float f32x4;
typedef __attribute__((ext_vector_type(4))) unsigned int u32x4;

// counting-sort geometry: 128 chunks x 6250 edges; bins split in 2 halves of 25000
#define NCHUNK  128
#define CHUNK   6250
#define HWORDS  12500   // packed u32 words per half (2 bins/word)

// padded CSR capacity (pad each node's edge list to a multiple of 4; max +3/node)
#define PAD_E (N_EDGES + 3 * N_NODES)

// ---------------- workspace layout (32-bit word offsets) ----------------
#define W_DEG      0
#define W_FLAG     (W_DEG + N_NODES)
#define W_BSUM     (W_FLAG + 16)
#define W_BPRE     (W_BSUM + 256)
#define W_GOFF     (W_BPRE + 256)
#define W_OFFS     (W_GOFF + NGRAPH + 8)
#define W_DIS      (W_OFFS + N_NODES + 8)
#define W_CSR      (((W_DIS + N_NODES) + 3) & ~3)
#define W_WT       (W_CSR + 2 * PAD_E)
#define W_ZH       (((W_WT + 81920) + 3) & ~3)
#define W_H        (W_ZH + (MROWS * HID / 2))       // bf16 H (overlaid by sort partials pre-gemm1)

// Wt sub-offsets in ushorts within W_WT (transposed bf16, hi only)
#define WT1 0
#define WT2 32768
#define WT3 98304

__device__ __forceinline__ unsigned short f2b(float f) {
    unsigned int u = __float_as_uint(f);
    unsigned int r = (u + 0x7FFFu + ((u >> 16) & 1u)) >> 16;
    return (unsigned short)r;
}
__device__ __forceinline__ float b2f(unsigned short h) {
    return __uint_as_float(((unsigned int)h) << 16);
}
// 4 bf16 (packed in uint2) -> f32x4  (and/shl pair decode, 4 inst)
__device__ __forceinline__ f32x4 cvt4(uint2 u) {
    f32x4 r;
    r[0] = __uint_as_float(u.x << 16);
    r[1] = __uint_as_float(u.x & 0xffff0000u);
    r[2] = __uint_as_float(u.y << 16);
    r[3] = __uint_as_float(u.y & 0xffff0000u);
    return r;
}

// ---------------- prep kernels ----------------
__global__ __launch_bounds__(256) void zero_kernel(unsigned int* __restrict__ p, int n) {
    int i = blockIdx.x * 256 + threadIdx.x;
    if (i < n) p[i] = 0u;
}

__global__ __launch_bounds__(256) void detect_kernel(const unsigned int* __restrict__ ei,
                                                     int* __restrict__ flag) {
    int e = blockIdx.x * 256 + threadIdx.x;
    if (e >= N_EDGES) return;
    if (ei[2 * e + 1] != 0u) *flag = 1;
}

// pass 1: per-(chunk,half) LDS histogram, packed 2x16-bit counts per word
__global__ __launch_bounds__(256) void hist_kernel(const void* __restrict__ ei,
                                                   const int* __restrict__ flag,
                                                   unsigned int* __restrict__ partial) {
    __shared__ unsigned int h[HWORDS];
    int c = blockIdx.x >> 1, hf = blockIdx.x & 1;
    int t = threadIdx.x;
    for (int i = t; i < HWORDS; i += 256) h[i] = 0u;
    __syncthreads();
    bool is32 = (*flag != 0);
    int e0 = c * CHUNK;
    for (int k = 0; k < 25; ++k) {
        int e = e0 + t + k * 256;
        if (e < e0 + CHUNK) {
            int d = is32 ? ((const int*)ei)[N_EDGES + e]
                         : (int)((const long long*)ei)[N_EDGES + e];
            if (((d >= 25000) ? 1 : 0) == hf) {
                int w = (d - hf * 25000) >> 1;
                atomicAdd(&h[w], (d & 1) ? 0x10000u : 1u);
            }
        }
    }
    __syncthreads();
    unsigned int* dst = partial + (size_t)blockIdx.x * HWORDS;
    for (int i = t; i < HWORDS; i += 256) dst[i] = h[i];
}

// pass 2: per bin-pair, exclusive prefix across chunks (in place) + total degree
__global__ __launch_bounds__(256) void merge_kernel(unsigned int* __restrict__ partial,
                                                    int* __restrict__ deg) {
    int w = blockIdx.x * 256 + threadIdx.x;
    if (w >= 25000) return;
    int hf = (w >= HWORDS) ? 1 : 0;
    int wi = w - hf * HWORDS;
    unsigned int run_lo = 0, run_hi = 0;
    for (int c = 0; c < NCHUNK; ++c) {
        size_t idx = ((size_t)(c * 2 + hf)) * HWORDS + wi;
        unsigned int u = partial[idx];
        partial[idx] = run_lo | (run_hi << 16);
        run_lo += u & 0xffffu;
        run_hi += u >> 16;
    }
    deg[2 * w]     = (int)run_lo;
    deg[2 * w + 1] = (int)run_hi;
}

// per-block sums of padded degrees (pad to 4)
__global__ __launch_bounds__(256) void blocksum_kernel(const int* __restrict__ deg,
                                                       int* __restrict__ bsum) {
    int b = blockIdx.x, t = threadIdx.x;
    int i = b * 256 + t;
    int pd = (i < N_NODES) ? ((deg[i] + 3) & ~3) : 0;
    int lane = t & 63, w = t >> 6;
    int s = pd;
    #pragma unroll
    for (int o = 32; o >= 1; o >>= 1) s += __shfl_xor(s, o, 64);
    __shared__ int ws[4];
    if (lane == 0) ws[w] = s;
    __syncthreads();
    if (t == 0) bsum[b] = ws[0] + ws[1] + ws[2] + ws[3];
}

// single tiny block: exclusive scan bsum(196) -> bpre
__global__ __launch_bounds__(256) void scanb_kernel(const int* __restrict__ bsum,
                                                    int* __restrict__ bpre) {
    int t = threadIdx.x;
    int lane = t & 63, w = t >> 6;
    int x = (t < 196) ? bsum[t] : 0;
    int inc = x;
    #pragma unroll
    for (int o = 1; o < 64; o <<= 1) {
        int u = __shfl_up(inc, o, 64);
        if (lane >= o) inc += u;
    }
    __shared__ int wsA[4];
    if (lane == 63) wsA[w] = inc;
    __syncthreads();
    int base = 0;
    for (int k = 0; k < w; ++k) base += wsA[k];
    bpre[t] = base + inc - x;
}

// per-node padded offsets + dis (pad to 4)
__global__ __launch_bounds__(256) void finalize_kernel(const int* __restrict__ deg,
                                                       const int* __restrict__ bpre,
                                                       int* __restrict__ offs,
                                                       float* __restrict__ dis) {
    int b = blockIdx.x, t = threadIdx.x;
    int i = b * 256 + t;
    int d = (i < N_NODES) ? deg[i] : 0;
    int pd = (d + 3) & ~3;
    int lane = t & 63, w = t >> 6;
    int inc = pd;
    #pragma unroll
    for (int o = 1; o < 64; o <<= 1) {
        int u = __shfl_up(inc, o, 64);
        if (lane >= o) inc += u;
    }
    __shared__ int ws[4];
    if (lane == 63) ws[w] = inc;
    __syncthreads();
    int base = 0;
    for (int k = 0; k < w; ++k) base += ws[k];
    int pre = base + inc - pd;
    if (i < N_NODES) {
        offs[i] = bpre[b] + pre;
        dis[i] = rsqrtf((float)d + 1.0f);
    }
    if (i == N_NODES - 1) offs[N_NODES] = bpre[b] + pre + pd;
}

// zero only the pad slots [offs+deg, offs+paddeg)
__global__ __launch_bounds__(256) void padzero_kernel(const int* __restrict__ deg,
                                                      const int* __restrict__ offs,
                                                      int2* __restrict__ csr) {
    int v = blockIdx.x * 256 + threadIdx.x;
    if (v >= N_NODES) return;
    int d = deg[v];
    int e = offs[v] + d;
    int pe = offs[v] + ((d + 3) & ~3);
    int2 z; z.x = 0; z.y = 0;
    for (; e < pe; ++e) csr[e] = z;
}

// pass 3: counting-sort scatter (no global atomics); rec.x = src byte-offset (src<<9)
__global__ __launch_bounds__(256) void scatter2_kernel(const void* __restrict__ ei,
                                                       const int* __restrict__ flag,
                                                       const int* __restrict__ offs,
                                                       const float* __restrict__ dis,
                                                       const unsigned int* __restrict__ partial,
                                                       int2* __restrict__ csr) {
    __shared__ unsigned int cur[HWORDS];
    int c = blockIdx.x >> 1, hf = blockIdx.x & 1;
    int t = threadIdx.x;
    for (int i = t; i < HWORDS; i += 256) cur[i] = 0u;
    __syncthreads();
    bool is32 = (*flag != 0);
    const unsigned int* rel = partial + (size_t)blockIdx.x * HWORDS;
    int e0 = c * CHUNK;
    for (int k = 0; k < 25; ++k) {
        int e = e0 + t + k * 256;
        if (e < e0 + CHUNK) {
            int s, d;
            if (is32) {
                const int* p = (const int*)ei;
                s = p[e]; d = p[N_EDGES + e];
            } else {
                const long long* p = (const long long*)ei;
                s = (int)p[e]; d = (int)p[N_EDGES + e];
            }
            if (((d >= 25000) ? 1 : 0) == hf) {
                int w = (d - hf * 25000) >> 1;
                unsigned int old = atomicAdd(&cur[w], (d & 1) ? 0x10000u : 1u);
                unsigned int p0 = (d & 1) ? (old >> 16) : (old & 0xffffu);
                unsigned int rp = rel[w];
                unsigned int r = (d & 1) ? (rp >> 16) : (rp & 0xffffu);
                int pos = offs[d] + (int)r + (int)p0;
                int2 rec;
                rec.x = s << 9;                       // pre-multiplied byte offset into bf16 H
                rec.y = __float_as_int(dis[s] * dis[d]);
                csr[pos] = rec;
            }
        }
    }
}

// graph offsets from sorted batch via boundary detection (no atomics)
__global__ __launch_bounds__(256) void goffs_kernel(const void* __restrict__ bt,
                                                    const int* __restrict__ flag,
                                                    int* __restrict__ goffs) {
    int v = blockIdx.x * 256 + threadIdx.x;
    if (v >= N_NODES) return;
    bool is32 = (*flag != 0);
    int b = is32 ? ((const int*)bt)[v] : (int)((const long long*)bt)[v];
    if (v == 0) {
        for (int g = 0; g <= b; ++g) goffs[g] = 0;
    } else {
        int pb = is32 ? ((const int*)bt)[v - 1] : (int)((const long long*)bt)[v - 1];
        for (int g = pb + 1; g <= b; ++g) goffs[g] = v;
    }
    if (v == N_NODES - 1) {
        for (int g = b + 1; g <= NGRAPH; ++g) goffs[g] = N_NODES;
    }
}

// x -> bf16 + transpose W1,W2,W3 into [N][K] bf16 (hi only)
#define XSPLIT_BLOCKS 6250
__global__ __launch_bounds__(256) void prep_w(const float* __restrict__ x,
                                              const float* __restrict__ W1,
                                              const float* __restrict__ W2,
                                              const float* __restrict__ W3,
                                              unsigned short* __restrict__ xh,
                                              unsigned short* __restrict__ wt) {
    int b = blockIdx.x;
    int t = threadIdx.x;
    if (b < XSPLIT_BLOCKS) {
        int i = b * 256 + t;
        float4 v = ((const float4*)x)[i];
        ushort4 h;
        h.x = f2b(v.x); h.y = f2b(v.y); h.z = f2b(v.z); h.w = f2b(v.w);
        ((ushort4*)xh)[i] = h;
    } else {
        int wb = b - XSPLIT_BLOCKS;
        const float* W; int K, k, bh;
        if (wb < 128)      { W = W1; K = 128; k = wb;       bh = WT1; }
        else if (wb < 384) { W = W2; K = 256; k = wb - 128; bh = WT2; }
        else               { W = W3; K = 256; k = wb - 384; bh = WT3; }
        int n = t;
        wt[bh + n * K + k] = f2b(W[k * HID + n]);
    }
}

// ---------------- bf16 MFMA GEMM: C = A @ B^T-stored; guard-free; C as bf16 ----------------
__global__ __launch_bounds__(256) void gemm_bf16(const unsigned short* __restrict__ A,
                                                 const unsigned short* __restrict__ B,
                                                 unsigned short* __restrict__ C,
                                                 int K) {
    __shared__ char lds[2 * 128 * 80];   // 20480 B: A, B tiles (128 rows x 64B, 80B pitch)
    int tid = threadIdx.x;
    int bm = blockIdx.x * 128;
    int bn = blockIdx.y * 128;
    int lane = tid & 63, wid = tid >> 6;
    int wm = wid >> 1, wn = wid & 1;
    int lr = lane & 15, lc = lane >> 4;
    f32x4 acc[4][4];
    #pragma unroll
    for (int i = 0; i < 4; ++i)
        #pragma unroll
        for (int j = 0; j < 4; ++j)
            acc[i][j] = (f32x4){0.f, 0.f, 0.f, 0.f};

    for (int k0 = 0; k0 < K; k0 += 32) {
        // stage 2 tiles; tile index compile-time per unrolled step
        #pragma unroll
        for (int c8 = 0; c8 < 4; ++c8) {
            const int tile = c8 >> 1;
            const unsigned short* __restrict__ src = (tile == 0) ? A : B;
            int c = ((c8 & 1) << 8) + tid;
            int rr = c >> 2, q = c & 3;
            int row = ((tile == 0) ? bm : bn) + rr;
            u32x4 v = *(const u32x4*)(src + (size_t)row * K + k0 + q * 8);
            *(u32x4*)(lds + tile * 10240 + rr * 80 + q * 16) = v;
        }
        __syncthreads();
        bf16x8 af[4], bf[4];
        #pragma unroll
        for (int f = 0; f < 4; ++f) {
            af[f] = *(const bf16x8*)(lds +         (wm * 64 + f * 16 + lr) * 80 + lc * 16);
            bf[f] = *(const bf16x8*)(lds + 10240 + (wn * 64 + f * 16 + lr) * 80 + lc * 16);
        }
        #pragma unroll
        for (int fi = 0; fi < 4; ++fi) {
            #pragma unroll
            for (int fj = 0; fj < 4; ++fj) {
                acc[fi][fj] = __builtin_amdgcn_mfma_f32_16x16x32_bf16(af[fi], bf[fj], acc[fi][fj], 0, 0, 0);
            }
        }
        __syncthreads();
    }
    #pragma unroll
    for (int fi = 0; fi < 4; ++fi) {
        int rbase = bm + wm * 64 + fi * 16 + lc * 4;
        #pragma unroll
        for (int fj = 0; fj < 4; ++fj) {
            int col = bn + wn * 64 + fj * 16 + lr;
            #pragma unroll
            for (int r = 0; r < 4; ++r) {
                C[(size_t)(rbase + r) * HID + col] = f2b(acc[fi][fj][r]);
            }
        }
    }
}

// ---------------- fused aggregation: 1 node/wave, 4-edge chunks, 3-deep pipeline ----------------
#define DECL_C4(P) int4 P##c0, P##c1; uint2 P##h0, P##h1, P##h2, P##h3;

#define LOAD4(P, idx) do { \
    const int4* _q = (const int4*)(csr + (idx)); \
    P##c0 = _q[0]; P##c1 = _q[1]; \
    P##h0 = *(const uint2*)(Hl + P##c0.x); \
    P##h1 = *(const uint2*)(Hl + P##c0.z); \
    P##h2 = *(const uint2*)(Hl + P##c1.x); \
    P##h3 = *(const uint2*)(Hl + P##c1.z); \
} while (0)

#define FMA4U(hv, wv, a) do { a += cvt4(hv) * (wv); } while (0)

#define CONS4(P, a) do { \
    FMA4U(P##h0, __int_as_float(P##c0.y), a); \
    FMA4U(P##h1, __int_as_float(P##c0.w), a); \
    FMA4U(P##h2, __int_as_float(P##c1.y), a); \
    FMA4U(P##h3, __int_as_float(P##c1.w), a); \
} while (0)

// MODE 0: +bias, ReLU, LayerNorm, write bf16 Z.  MODE 1: +bias, write bf16 rows (for pool).
template <int MODE>
__global__ __launch_bounds__(256) void agg_kernel(const unsigned short* __restrict__ H,
                                                  const float* __restrict__ dis,
                                                  const int* __restrict__ offs,
                                                  const int2* __restrict__ csr,
                                                  const float* __restrict__ bias,
                                                  const float* __restrict__ gamma,
                                                  const float* __restrict__ beta,
                                                  unsigned short* __restrict__ Z) {
    int v = blockIdx.x * 4 + (threadIdx.x >> 6);
    int l = threadIdx.x & 63;
    const char* Hl = (const char*)H + l * 8;   // lane-fixed byte base

    float dv = dis[v];
    uint2 a0u = ((const uint2*)(H + (size_t)v * HID))[l];
    f32x4 acc = cvt4(a0u) * (dv * dv);

    int i = offs[v];
    int n = (offs[v + 1] - i) >> 2;   // padded 4-edge chunk count
    DECL_C4(A)
    DECL_C4(B)
    DECL_C4(C)
    if (n > 0) LOAD4(A, i);
    if (n > 1) LOAD4(B, i + 4);
    if (n > 2) LOAD4(C, i + 8);
    int c = 0;
    // steady state: always 2 chunks in flight behind the one being consumed
    while (c + 6 <= n) {
        CONS4(A, acc); LOAD4(A, i + 12);
        CONS4(B, acc); LOAD4(B, i + 16);
        CONS4(C, acc); LOAD4(C, i + 20);
        i += 12; c += 3;
    }
    // tail: r in [0..5]; buffers hold chunks c, c+1, c+2 (those < n)
    int r = n - c;
    if (r >= 1) { CONS4(A, acc); if (r >= 4) LOAD4(A, i + 12); }
    if (r >= 2) { CONS4(B, acc); if (r >= 5) LOAD4(B, i + 16); }
    if (r >= 3) CONS4(C, acc);
    if (r >= 4) CONS4(A, acc);
    if (r >= 5) CONS4(B, acc);

    f32x4 b4 = *(const f32x4*)(bias + l * 4);
    acc += b4;
    if (MODE == 0) {
        acc[0] = fmaxf(acc[0], 0.f); acc[1] = fmaxf(acc[1], 0.f);
        acc[2] = fmaxf(acc[2], 0.f); acc[3] = fmaxf(acc[3], 0.f);
        float s = acc[0] + acc[1] + acc[2] + acc[3];
        #pragma unroll
        for (int o = 32; o >= 1; o >>= 1) s += __shfl_xor(s, o, 64);
        float mu = s * (1.0f / HID);
        f32x4 d = acc - mu;
        float vs = d[0] * d[0] + d[1] * d[1] + d[2] * d[2] + d[3] * d[3];
        #pragma unroll
        for (int o = 32; o >= 1; o >>= 1) vs += __shfl_xor(vs, o, 64);
        float inv = rsqrtf(vs * (1.0f / HID) + LN_EPS);
        f32x4 g4 = *(const f32x4*)(gamma + l * 4);
        f32x4 be4 = *(const f32x4*)(beta + l * 4);
        ushort4 zh;
        zh.x = f2b(d[0] * inv * g4[0] + be4[0]);
        zh.y = f2b(d[1] * inv * g4[1] + be4[1]);
        zh.z = f2b(d[2] * inv * g4[2] + be4[2]);
        zh.w = f2b(d[3] * inv * g4[3] + be4[3]);
        *(ushort4*)(Z + (size_t)v * HID + l * 4) = zh;
    } else {
        ushort4 zh;
        zh.x = f2b(acc[0]); zh.y = f2b(acc[1]);
        zh.z = f2b(acc[2]); zh.w = f2b(acc[3]);
        *(ushort4*)(Z + (size_t)v * HID + l * 4) = zh;
    }
}

// ---------------- per-graph segment-mean pool over bf16 rows (batch is sorted) ----------------
__global__ __launch_bounds__(256) void pool_kernel(const unsigned short* __restrict__ O,
                                                   const int* __restrict__ goffs,
                                                   float* __restrict__ out) {
    int g = blockIdx.x, t = threadIdx.x;
    int l = t & 63, w = t >> 6;
    int s = goffs[g], e = goffs[g + 1];
    f32x4 acc = (f32x4){0.f, 0.f, 0.f, 0.f};
    for (int v = s + w; v < e; v += 4) {
        uint2 r = ((const uint2*)(O + (size_t)v * HID))[l];
        acc += cvt4(r);
    }
    __shared__ f32x4 red[4][64];
    red[w][l] = acc;
    __syncthreads();
    if (w == 0) {
        f32x4 r0 = red[0][l], r1 = red[1][l], r2 = red[2][l], r3 = red[3][l];
        float inv = 1.0f / (float)(e - s);
        f32x4 o = (r0 + r1 + r2 + r3) * inv;
        *(f32x4*)(out + (size_t)g * HID + l * 4) = o;
    }
}

// ---------------- launch ----------------
extern "C" void kernel_launch(void* const* d_in, const int* in_sizes, int n_in,
                              void* d_out, int out_size, void* d_ws, size_t ws_size,
                              hipStream_t stream) {
    const float* x   = (const float*)d_in[0];
    const float* W1  = (const float*)d_in[1];
    const float* b1  = (const float*)d_in[2];
    const float* g1  = (const float*)d_in[3];
    const float* be1 = (const float*)d_in[4];
    const float* W2  = (const float*)d_in[5];
    const float* b2  = (const float*)d_in[6];
    const float* g2  = (const float*)d_in[7];
    const float* be2 = (const float*)d_in[8];
    const float* W3  = (const float*)d_in[9];
    const float* b3  = (const float*)d_in[10];
    const void*  ei  = d_in[11];
    const void*  bt  = d_in[12];
    float* out = (float*)d_out;

    unsigned int* ws = (unsigned int*)d_ws;
    int*   deg    = (int*)(ws + W_DEG);
    int*   flag   = (int*)(ws + W_FLAG);
    int*   bsum   = (int*)(ws + W_BSUM);
    int*   bpre   = (int*)(ws + W_BPRE);
    int*   goffs  = (int*)(ws + W_GOFF);
    int*   offs   = (int*)(ws + W_OFFS);
    float* dis    = (float*)(ws + W_DIS);
    int2*  csr    = (int2*)(ws + W_CSR);
    unsigned short* wt = (unsigned short*)(ws + W_WT);
    unsigned short* Zbuf = (unsigned short*)(ws + W_ZH);
    unsigned short* xh = Zbuf;          // overlay: x-bf16 dead after gemm1
    unsigned short* Hbuf = (unsigned short*)(ws + W_H);       // bf16 H (MROWS rows)
    unsigned int*   partial = (unsigned int*)(ws + W_H);      // overlay: dead after scatter2

    const int EB = (N_EDGES + 255) / 256;
    const int NB = (N_NODES + 255) / 256;  // 196

    zero_kernel<<<1, 256, 0, stream>>>(ws + W_FLAG, 16);
    detect_kernel<<<EB, 256, 0, stream>>>((const unsigned int*)ei, flag);
    hist_kernel<<<2 * NCHUNK, 256, 0, stream>>>(ei, flag, partial);
    merge_kernel<<<(25000 + 255) / 256, 256, 0, stream>>>(partial, deg);
    blocksum_kernel<<<NB, 256, 0, stream>>>(deg, bsum);
    scanb_kernel<<<1, 256, 0, stream>>>(bsum, bpre);
    finalize_kernel<<<NB, 256, 0, stream>>>(deg, bpre, offs, dis);
    padzero_kernel<<<NB, 256, 0, stream>>>(deg, offs, csr);
    scatter2_kernel<<<2 * NCHUNK, 256, 0, stream>>>(ei, flag, offs, dis, partial, csr);
    goffs_kernel<<<NB, 256, 0, stream>>>(bt, flag, goffs);
    prep_w<<<XSPLIT_BLOCKS + 640, 256, 0, stream>>>(x, W1, W2, W3, xh, wt);

    dim3 gg(MROWS / 128, HID / 128);     // (391, 2), guard-free
    const int AB = N_NODES / 4;          // 12500 blocks = 50000 waves = 1 node/wave

    gemm_bf16<<<gg, 256, 0, stream>>>(xh, wt + WT1, Hbuf, IN_DIM);
    agg_kernel<0><<<AB, 256, 0, stream>>>(Hbuf, dis, offs, csr, b1, g1, be1, Zbuf);
    gemm_bf16<<<gg, 256, 0, stream>>>(Zbuf, wt + WT2, Hbuf, HID);
    agg_kernel<0><<<AB, 256, 0, stream>>>(Hbuf, dis, offs, csr, b2, g2, be2, Zbuf);
    gemm_bf16<<<gg, 256, 0, stream>>>(Zbuf, wt + WT3, Hbuf, HID);
    agg_kernel<1><<<AB, 256, 0, stream>>>(Hbuf, dis, offs, csr, b3, nullptr, nullptr, Zbuf);
    pool_kernel<<<NGRAPH, 256, 0, stream>>>(Zbuf, goffs, out);
}